// Round 1
// baseline (3820.395 us; speedup 1.0000x reference)
//
#include <hip/hip_runtime.h>
#include <math.h>

#define SEQN 1536
#define NH 8
#define MROWS 6144      // BATCH*SEQ
#define NDIST 3071      // 2*SEQ-1

// ---------------- positional embedding table: pos[3071][192] ----------------
__global__ __launch_bounds__(64) void pos_embed_kernel(float* __restrict__ pos) {
  int row = blockIdx.x;
  int j = threadIdx.x;
  if (j >= 32) return;
  float dist = (float)(row - (SEQN - 1));
  float adist = fabsf(dist);
  float sgn = (dist > 0.f) ? 1.f : (dist < 0.f ? -1.f : 0.f);

  const float max_range = 10.58496250072116f;  // log2(1536)
  float hl = exp2f(3.0f + ((max_range - 3.0f) / 31.0f) * (float)j);
  float e_exp = expf(-0.6931471805599453f / hl * adist);

  float cw = exp2f((float)(j + 1)) - 1.0f;
  float e_cm = (cw > adist) ? 1.0f : 0.0f;

  float mean = 48.0f * (float)(j + 1);          // linspace(48,1536,32), exact
  float tt = mean / 24.0f;
  float conc = tt * tt;
  float rate = mean / 576.0f;
  float log_unnorm = (conc - 1.0f) * logf(fmaxf(adist, 1e-20f)) - rate * adist;
  float log_norm = lgammaf(conc) - conc * logf(rate);
  float prob = expf(log_unnorm - log_norm) + 1e-8f;
  float mx = prob;
  #pragma unroll
  for (int off = 16; off >= 1; off >>= 1)
    mx = fmaxf(mx, __shfl_xor(mx, off, 32));
  float e_g = prob / mx;

  float* o = pos + (size_t)row * 192;
  o[j] = e_exp;        o[32 + j] = e_cm;        o[64 + j] = e_g;
  o[96 + j] = sgn * e_exp; o[128 + j] = sgn * e_cm; o[160 + j] = sgn * e_g;
}

// ------------- rel_k = pos @ Wrk  -> relk[3071][512]; PR[h][d] = pb_h . relk -------------
__global__ __launch_bounds__(512) void relk_kernel(
    const float* __restrict__ pos, const float* __restrict__ Wrk,
    const float* __restrict__ pb, float* __restrict__ relk, float* __restrict__ PR) {
  const int d = blockIdx.x;
  const int t = threadIdx.x;
  __shared__ float prow[192];
  if (t < 192) prow[t] = pos[(size_t)d * 192 + t];
  __syncthreads();
  float acc = 0.f;
  #pragma unroll 8
  for (int kk = 0; kk < 192; ++kk)
    acc = fmaf(prow[kk], Wrk[(size_t)kk * 512 + t], acc);
  relk[(size_t)d * 512 + t] = acc;
  float pv = pb[t] * acc;                        // wave w == head w (512 = 8 waves)
  #pragma unroll
  for (int off = 32; off >= 1; off >>= 1) pv += __shfl_xor(pv, off);
  if ((t & 63) == 0) PR[(size_t)(t >> 6) * NDIST + d] = pv;
}

// ------------- CK[row][h] = cb_h . k[row,h,:] -------------
__global__ __launch_bounds__(256) void ck_kernel(
    const float* __restrict__ k, const float* __restrict__ cb, float* __restrict__ CK) {
  const int gid = blockIdx.x * 4 + (threadIdx.x >> 6);
  const int lane = threadIdx.x & 63;
  const int row = gid >> 3;
  const int h = gid & 7;
  float pv = cb[h * 64 + lane] * k[(size_t)row * 512 + h * 64 + lane];
  #pragma unroll
  for (int off = 32; off >= 1; off >>= 1) pv += __shfl_xor(pv, off);
  if (lane == 0) CK[(size_t)row * 8 + h] = pv;
}

// ------------- layernorm: one block per row of 1536 -------------
__global__ __launch_bounds__(256) void ln_kernel(
    const float* __restrict__ x, const float* __restrict__ g,
    const float* __restrict__ bta, float* __restrict__ out) {
  const int row = blockIdx.x;
  const int t = threadIdx.x;
  __shared__ float red[4];
  __shared__ float bc[2];
  const float4* xr = (const float4*)(x + (size_t)row * 1536);
  float4 v0 = xr[t];
  float4 v1 = make_float4(0.f, 0.f, 0.f, 0.f);
  if (t < 128) v1 = xr[256 + t];
  float s = v0.x + v0.y + v0.z + v0.w;
  if (t < 128) s += v1.x + v1.y + v1.z + v1.w;
  #pragma unroll
  for (int off = 32; off >= 1; off >>= 1) s += __shfl_xor(s, off);
  if ((t & 63) == 0) red[t >> 6] = s;
  __syncthreads();
  if (t == 0) bc[0] = (red[0] + red[1] + red[2] + red[3]) * (1.f / 1536.f);
  __syncthreads();
  const float mu = bc[0];
  float d, s2 = 0.f;
  d = v0.x - mu; s2 += d * d; d = v0.y - mu; s2 += d * d;
  d = v0.z - mu; s2 += d * d; d = v0.w - mu; s2 += d * d;
  if (t < 128) {
    d = v1.x - mu; s2 += d * d; d = v1.y - mu; s2 += d * d;
    d = v1.z - mu; s2 += d * d; d = v1.w - mu; s2 += d * d;
  }
  #pragma unroll
  for (int off = 32; off >= 1; off >>= 1) s2 += __shfl_xor(s2, off);
  if ((t & 63) == 0) red[t >> 6] = s2;
  __syncthreads();
  if (t == 0) bc[1] = (red[0] + red[1] + red[2] + red[3]) * (1.f / 1536.f);
  __syncthreads();
  const float inv = rsqrtf(bc[1] + 1e-5f);
  const float4* g4 = (const float4*)g;
  const float4* b4 = (const float4*)bta;
  float4* o4 = (float4*)(out + (size_t)row * 1536);
  float4 gg = g4[t], bb = b4[t], o;
  o.x = (v0.x - mu) * inv * gg.x + bb.x;
  o.y = (v0.y - mu) * inv * gg.y + bb.y;
  o.z = (v0.z - mu) * inv * gg.z + bb.z;
  o.w = (v0.w - mu) * inv * gg.w + bb.w;
  o4[t] = o;
  if (t < 128) {
    gg = g4[256 + t]; bb = b4[256 + t];
    o.x = (v1.x - mu) * inv * gg.x + bb.x;
    o.y = (v1.y - mu) * inv * gg.y + bb.y;
    o.z = (v1.z - mu) * inv * gg.z + bb.z;
    o.w = (v1.w - mu) * inv * gg.w + bb.w;
    o4[256 + t] = o;
  }
}

// ------------- fp32 GEMM: C = alpha*(A@B) [+bias] [+relu] [+res] -------------
#define BM 128
#define BN 64
#define BK 16

template <int EPI>  // 0 = alpha only, 2 = bias+relu, 3 = bias+residual
__global__ __launch_bounds__(256) void gemm_kernel(
    const float* __restrict__ A, const float* __restrict__ B,
    float* __restrict__ C, const float* __restrict__ bias,
    const float* __restrict__ res, int M, int N, int K, float alpha) {
  __shared__ float As[BK][BM + 4];
  __shared__ float Bs[BK][BN + 4];
  const int t = threadIdx.x;
  const int m0 = blockIdx.y * BM;
  const int n0 = blockIdx.x * BN;
  const int ty = t >> 4;   // 0..15
  const int tx = t & 15;   // 0..15

  float acc[8][4];
  #pragma unroll
  for (int r = 0; r < 8; ++r)
    #pragma unroll
    for (int c = 0; c < 4; ++c) acc[r][c] = 0.f;

  for (int k0 = 0; k0 < K; k0 += BK) {
    #pragma unroll
    for (int p = 0; p < 2; ++p) {
      int id = t + p * 256;
      int row = id >> 2, q4 = id & 3;
      float4 av = *(const float4*)(A + (size_t)(m0 + row) * K + k0 + q4 * 4);
      As[q4 * 4 + 0][row] = av.x;
      As[q4 * 4 + 1][row] = av.y;
      As[q4 * 4 + 2][row] = av.z;
      As[q4 * 4 + 3][row] = av.w;
    }
    {
      int krow = t >> 4, c4 = t & 15;
      *(float4*)(&Bs[krow][c4 * 4]) =
          *(const float4*)(B + (size_t)(k0 + krow) * N + n0 + c4 * 4);
    }
    __syncthreads();
    #pragma unroll
    for (int kk = 0; kk < BK; ++kk) {
      float a[8], b[4];
      *(float4*)(&a[0]) = *(const float4*)(&As[kk][ty * 8]);
      *(float4*)(&a[4]) = *(const float4*)(&As[kk][ty * 8 + 4]);
      *(float4*)(&b[0]) = *(const float4*)(&Bs[kk][tx * 4]);
      #pragma unroll
      for (int r = 0; r < 8; ++r)
        #pragma unroll
        for (int c = 0; c < 4; ++c) acc[r][c] = fmaf(a[r], b[c], acc[r][c]);
    }
    __syncthreads();
  }

  #pragma unroll
  for (int r = 0; r < 8; ++r) {
    size_t row = m0 + ty * 8 + r;
    size_t col = n0 + tx * 4;
    float vv[4];
    #pragma unroll
    for (int c = 0; c < 4; ++c) {
      float xv = acc[r][c] * alpha;
      if (EPI >= 2) xv += bias[col + c];
      if (EPI == 2) xv = fmaxf(xv, 0.f);
      if (EPI == 3) xv += res[row * (size_t)N + col + c];
      vv[c] = xv;
    }
    float4 o; o.x = vv[0]; o.y = vv[1]; o.z = vv[2]; o.w = vv[3];
    *(float4*)(C + row * (size_t)N + col) = o;
  }
}

// ------------- flash attention with relative positions -------------
// S[i,j] = q_i.k_j + q_i.relk[d] + CK[b,h,j] + PR[h,d],  d = n-1 + j - i
__global__ __launch_bounds__(256) void attn_kernel(
    const float* __restrict__ q, const float* __restrict__ k,
    const float* __restrict__ v, const float* __restrict__ relk,
    const float* __restrict__ PR, const float* __restrict__ CK,
    float* __restrict__ out) {
  const int n = SEQN;
  const int i0 = blockIdx.x * 32;
  const int h = blockIdx.y;
  const int b = blockIdx.z;
  const int t = threadIdx.x;

  __shared__ float Qs[32][68];
  __shared__ float Ks[32][68];
  __shared__ float Rs[63][68];
  __shared__ float Vs[32][192];
  __shared__ float Ss[32][33];
  __shared__ float mS[32], lS[32], aS[32];

  {
    const float* qb = q + ((size_t)(b * n + i0)) * 512 + h * 64;
    #pragma unroll
    for (int p = 0; p < 2; ++p) {
      int id = t + p * 256;
      int row = id >> 4, c4 = id & 15;
      *(float4*)(&Qs[row][c4 * 4]) = *(const float4*)(qb + (size_t)row * 512 + c4 * 4);
    }
  }
  if (t < 32) { mS[t] = -1e30f; lS[t] = 0.f; }

  float acc[4][6];
  #pragma unroll
  for (int r = 0; r < 4; ++r)
    #pragma unroll
    for (int c = 0; c < 6; ++c) acc[r][c] = 0.f;

  const int ti = t >> 4, tj = t & 15;   // S-phase: 2x2 per thread
  const int ci = t >> 5, cc = t & 31;   // PV-phase: 4 rows x 6 cols
  const int il0 = 2 * ti, jl0 = 2 * tj;

  for (int j0 = 0; j0 < n; j0 += 32) {
    __syncthreads();
    const float* kb = k + ((size_t)(b * n + j0)) * 512 + h * 64;
    #pragma unroll
    for (int p = 0; p < 2; ++p) {
      int id = t + p * 256;
      int row = id >> 4, c4 = id & 15;
      *(float4*)(&Ks[row][c4 * 4]) = *(const float4*)(kb + (size_t)row * 512 + c4 * 4);
    }
    const float* vb = v + ((size_t)(b * n + j0)) * 1536 + h * 192;
    #pragma unroll
    for (int p = 0; p < 6; ++p) {
      int id = t + p * 256;
      int row = id / 48, c4 = id % 48;
      *(float4*)(&Vs[row][c4 * 4]) = *(const float4*)(vb + (size_t)row * 1536 + c4 * 4);
    }
    const int d0 = (n - 1) + j0 - i0 - 31;
    const float* rb = relk + (size_t)d0 * 512 + h * 64;
    #pragma unroll
    for (int p = 0; p < 4; ++p) {
      int id = t + p * 256;
      if (id < 63 * 16) {
        int row = id >> 4, c4 = id & 15;
        *(float4*)(&Rs[row][c4 * 4]) = *(const float4*)(rb + (size_t)row * 512 + c4 * 4);
      }
    }
    __syncthreads();

    float s00 = 0.f, s01 = 0.f, s10 = 0.f, s11 = 0.f;
    const int dm = jl0 + 31 - il0;   // d-index (local) for (il0, jl0); in [1,61]
    #pragma unroll 4
    for (int kc = 0; kc < 64; kc += 4) {
      float4 q0 = *(const float4*)(&Qs[il0][kc]);
      float4 q1 = *(const float4*)(&Qs[il0 + 1][kc]);
      float4 k0 = *(const float4*)(&Ks[jl0][kc]);
      float4 k1 = *(const float4*)(&Ks[jl0 + 1][kc]);
      float4 rm = *(const float4*)(&Rs[dm - 1][kc]);
      float4 r0 = *(const float4*)(&Rs[dm][kc]);
      float4 rp = *(const float4*)(&Rs[dm + 1][kc]);
      s00 = fmaf(q0.x, k0.x + r0.x, s00); s00 = fmaf(q0.y, k0.y + r0.y, s00);
      s00 = fmaf(q0.z, k0.z + r0.z, s00); s00 = fmaf(q0.w, k0.w + r0.w, s00);
      s01 = fmaf(q0.x, k1.x + rp.x, s01); s01 = fmaf(q0.y, k1.y + rp.y, s01);
      s01 = fmaf(q0.z, k1.z + rp.z, s01); s01 = fmaf(q0.w, k1.w + rp.w, s01);
      s10 = fmaf(q1.x, k0.x + rm.x, s10); s10 = fmaf(q1.y, k0.y + rm.y, s10);
      s10 = fmaf(q1.z, k0.z + rm.z, s10); s10 = fmaf(q1.w, k0.w + rm.w, s10);
      s11 = fmaf(q1.x, k1.x + r0.x, s11); s11 = fmaf(q1.y, k1.y + r0.y, s11);
      s11 = fmaf(q1.z, k1.z + r0.z, s11); s11 = fmaf(q1.w, k1.w + r0.w, s11);
    }
    float ck0 = CK[((size_t)(b * n + j0 + jl0)) * 8 + h];
    float ck1 = CK[((size_t)(b * n + j0 + jl0 + 1)) * 8 + h];
    const float* prh = PR + (size_t)h * NDIST + (n - 1) + j0 - i0;
    float pr00 = prh[jl0 - il0];
    Ss[il0][jl0]         = s00 + ck0 + pr00;
    Ss[il0][jl0 + 1]     = s01 + ck1 + prh[jl0 + 1 - il0];
    Ss[il0 + 1][jl0]     = s10 + ck0 + prh[jl0 - il0 - 1];
    Ss[il0 + 1][jl0 + 1] = s11 + ck1 + pr00;
    __syncthreads();

    if (t < 32) {   // online softmax for row t
      float m_old = mS[t];
      float mx = m_old;
      #pragma unroll
      for (int jj = 0; jj < 32; ++jj) mx = fmaxf(mx, Ss[t][jj]);
      float sum = 0.f;
      #pragma unroll
      for (int jj = 0; jj < 32; ++jj) {
        float p = __expf(Ss[t][jj] - mx);
        Ss[t][jj] = p;
        sum += p;
      }
      float al = __expf(m_old - mx);
      lS[t] = lS[t] * al + sum;
      mS[t] = mx;
      aS[t] = al;
    }
    __syncthreads();

    #pragma unroll
    for (int r = 0; r < 4; ++r) {
      float al = aS[ci * 4 + r];
      #pragma unroll
      for (int c = 0; c < 6; ++c) acc[r][c] *= al;
    }
    #pragma unroll 4
    for (int jj = 0; jj < 32; ++jj) {
      float p0 = Ss[ci * 4 + 0][jj];
      float p1 = Ss[ci * 4 + 1][jj];
      float p2 = Ss[ci * 4 + 2][jj];
      float p3 = Ss[ci * 4 + 3][jj];
      float2 va = *(const float2*)(&Vs[jj][cc * 6 + 0]);
      float2 vb2 = *(const float2*)(&Vs[jj][cc * 6 + 2]);
      float2 vc = *(const float2*)(&Vs[jj][cc * 6 + 4]);
      acc[0][0] = fmaf(p0, va.x, acc[0][0]); acc[0][1] = fmaf(p0, va.y, acc[0][1]);
      acc[0][2] = fmaf(p0, vb2.x, acc[0][2]); acc[0][3] = fmaf(p0, vb2.y, acc[0][3]);
      acc[0][4] = fmaf(p0, vc.x, acc[0][4]); acc[0][5] = fmaf(p0, vc.y, acc[0][5]);
      acc[1][0] = fmaf(p1, va.x, acc[1][0]); acc[1][1] = fmaf(p1, va.y, acc[1][1]);
      acc[1][2] = fmaf(p1, vb2.x, acc[1][2]); acc[1][3] = fmaf(p1, vb2.y, acc[1][3]);
      acc[1][4] = fmaf(p1, vc.x, acc[1][4]); acc[1][5] = fmaf(p1, vc.y, acc[1][5]);
      acc[2][0] = fmaf(p2, va.x, acc[2][0]); acc[2][1] = fmaf(p2, va.y, acc[2][1]);
      acc[2][2] = fmaf(p2, vb2.x, acc[2][2]); acc[2][3] = fmaf(p2, vb2.y, acc[2][3]);
      acc[2][4] = fmaf(p2, vc.x, acc[2][4]); acc[2][5] = fmaf(p2, vc.y, acc[2][5]);
      acc[3][0] = fmaf(p3, va.x, acc[3][0]); acc[3][1] = fmaf(p3, va.y, acc[3][1]);
      acc[3][2] = fmaf(p3, vb2.x, acc[3][2]); acc[3][3] = fmaf(p3, vb2.y, acc[3][3]);
      acc[3][4] = fmaf(p3, vc.x, acc[3][4]); acc[3][5] = fmaf(p3, vc.y, acc[3][5]);
    }
  }

  #pragma unroll
  for (int r = 0; r < 4; ++r) {
    int ig = i0 + ci * 4 + r;
    float linv = 1.0f / lS[ci * 4 + r];
    float* ob = out + ((size_t)(b * n + ig)) * 1536 + h * 192 + cc * 6;
    float2 o0; o0.x = acc[r][0] * linv; o0.y = acc[r][1] * linv;
    float2 o1; o1.x = acc[r][2] * linv; o1.y = acc[r][3] * linv;
    float2 o2; o2.x = acc[r][4] * linv; o2.y = acc[r][5] * linv;
    *(float2*)(ob + 0) = o0;
    *(float2*)(ob + 2) = o1;
    *(float2*)(ob + 4) = o2;
  }
}

extern "C" void kernel_launch(void* const* d_in, const int* in_sizes, int n_in,
                              void* d_out, int out_size, void* d_ws, size_t ws_size,
                              hipStream_t stream) {
  (void)in_sizes; (void)n_in; (void)out_size; (void)ws_size;
  const float* x   = (const float*)d_in[0];
  const float* g1  = (const float*)d_in[1];
  const float* be1 = (const float*)d_in[2];
  const float* Wq  = (const float*)d_in[3];
  const float* Wk  = (const float*)d_in[4];
  const float* Wv  = (const float*)d_in[5];
  const float* Wo  = (const float*)d_in[6];
  const float* bo  = (const float*)d_in[7];
  const float* Wrk = (const float*)d_in[8];
  const float* cb  = (const float*)d_in[9];
  const float* pb  = (const float*)d_in[10];
  const float* g2  = (const float*)d_in[11];
  const float* be2 = (const float*)d_in[12];
  const float* W1  = (const float*)d_in[13];
  const float* b1  = (const float*)d_in[14];
  const float* W2  = (const float*)d_in[15];
  const float* b2  = (const float*)d_in[16];
  float* out = (float*)d_out;

  float* ws  = (float*)d_ws;
  float* xn  = ws;                  // 6144*1536
  float* qb  = xn + 9437184;        // 6144*512
  float* kb  = qb + 3145728;        // 6144*512
  float* vb  = kb + 3145728;        // 6144*1536
  float* ao  = vb + 9437184;        // 6144*1536 (attention out)
  float* x2  = ao + 9437184;        // 6144*1536 (post-attn residual)
  float* pos = x2 + 9437184;        // 3071*192
  float* rk  = pos + 589632;        // 3071*512
  float* PRb = rk + 1572352;        // 8*3071
  float* CKb = PRb + 24568;         // 6144*8
  float* h1  = qb;                  // reuse q..ao region (needs 18.9M <= 25.2M floats)

  pos_embed_kernel<<<NDIST, 64, 0, stream>>>(pos);
  relk_kernel<<<NDIST, 512, 0, stream>>>(pos, Wrk, pb, rk, PRb);
  ln_kernel<<<MROWS, 256, 0, stream>>>(x, g1, be1, xn);
  gemm_kernel<0><<<dim3(512 / BN, MROWS / BM), 256, 0, stream>>>(
      xn, Wq, qb, nullptr, nullptr, MROWS, 512, 1536, 0.125f);
  gemm_kernel<0><<<dim3(512 / BN, MROWS / BM), 256, 0, stream>>>(
      xn, Wk, kb, nullptr, nullptr, MROWS, 512, 1536, 1.0f);
  gemm_kernel<0><<<dim3(1536 / BN, MROWS / BM), 256, 0, stream>>>(
      xn, Wv, vb, nullptr, nullptr, MROWS, 1536, 1536, 1.0f);
  ck_kernel<<<MROWS * 8 / 4, 256, 0, stream>>>(kb, cb, CKb);
  attn_kernel<<<dim3(SEQN / 32, NH, 4), 256, 0, stream>>>(qb, kb, vb, rk, PRb, CKb, ao);
  gemm_kernel<3><<<dim3(1536 / BN, MROWS / BM), 256, 0, stream>>>(
      ao, Wo, x2, bo, x, MROWS, 1536, 1536, 1.0f);
  ln_kernel<<<MROWS, 256, 0, stream>>>(x2, g2, be2, xn);
  gemm_kernel<2><<<dim3(3072 / BN, MROWS / BM), 256, 0, stream>>>(
      xn, W1, h1, b1, nullptr, MROWS, 3072, 1536, 1.0f);
  gemm_kernel<3><<<dim3(1536 / BN, MROWS / BM), 256, 0, stream>>>(
      h1, W2, out, b2, x2, MROWS, 1536, 3072, 1.0f);
}

// Round 3
// 1950.527 us; speedup vs baseline: 1.9586x; 1.9586x over previous
//
#include <hip/hip_runtime.h>
#include <hip/hip_bf16.h>
#include <math.h>

#define SEQN 1536
#define NH 8
#define MROWS 6144      // BATCH*SEQ
#define NDIST 3071      // 2*SEQ-1

typedef __attribute__((ext_vector_type(8))) short bf16x8;
typedef __attribute__((ext_vector_type(4))) float f32x4;

__device__ __forceinline__ unsigned short f2bu(float x) {
  __hip_bfloat16 h = __float2bfloat16(x);
  return *reinterpret_cast<unsigned short*>(&h);
}
__device__ __forceinline__ float b2f(unsigned short u) {
  __hip_bfloat16 h;
  *reinterpret_cast<unsigned short*>(&h) = u;
  return __bfloat162float(h);
}

__device__ __forceinline__ void gl_lds16(const void* g, void* l) {
  __builtin_amdgcn_global_load_lds(
      (const __attribute__((address_space(1))) void*)g,
      (__attribute__((address_space(3))) void*)l, 16, 0, 0);
}

// ---------------- positional embedding table: pos[3071][192] ----------------
__global__ __launch_bounds__(64) void pos_embed_kernel(float* __restrict__ pos) {
  int row = blockIdx.x;
  int j = threadIdx.x;
  if (j >= 32) return;
  float dist = (float)(row - (SEQN - 1));
  float adist = fabsf(dist);
  float sgn = (dist > 0.f) ? 1.f : (dist < 0.f ? -1.f : 0.f);

  const float max_range = 10.58496250072116f;  // log2(1536)
  float hl = exp2f(3.0f + ((max_range - 3.0f) / 31.0f) * (float)j);
  float e_exp = expf(-0.6931471805599453f / hl * adist);

  float cw = exp2f((float)(j + 1)) - 1.0f;
  float e_cm = (cw > adist) ? 1.0f : 0.0f;

  float mean = 48.0f * (float)(j + 1);
  float tt = mean / 24.0f;
  float conc = tt * tt;
  float rate = mean / 576.0f;
  float log_unnorm = (conc - 1.0f) * logf(fmaxf(adist, 1e-20f)) - rate * adist;
  float log_norm = lgammaf(conc) - conc * logf(rate);
  float prob = expf(log_unnorm - log_norm) + 1e-8f;
  float mx = prob;
  #pragma unroll
  for (int off = 16; off >= 1; off >>= 1)
    mx = fmaxf(mx, __shfl_xor(mx, off, 32));
  float e_g = prob / mx;

  float* o = pos + (size_t)row * 192;
  o[j] = e_exp;        o[32 + j] = e_cm;        o[64 + j] = e_g;
  o[96 + j] = sgn * e_exp; o[128 + j] = sgn * e_cm; o[160 + j] = sgn * e_g;
}

// ------------- rel_k = pos @ Wrk -> relk[3071][512]; PR[h][d] -------------
__global__ __launch_bounds__(512) void relk_kernel(
    const float* __restrict__ pos, const float* __restrict__ Wrk,
    const float* __restrict__ pb, float* __restrict__ relk, float* __restrict__ PR) {
  const int d = blockIdx.x;
  const int t = threadIdx.x;
  __shared__ float prow[192];
  if (t < 192) prow[t] = pos[(size_t)d * 192 + t];
  __syncthreads();
  float acc = 0.f;
  #pragma unroll 8
  for (int kk = 0; kk < 192; ++kk)
    acc = fmaf(prow[kk], Wrk[(size_t)kk * 512 + t], acc);
  relk[(size_t)d * 512 + t] = acc;
  float pv = pb[t] * acc;
  #pragma unroll
  for (int off = 32; off >= 1; off >>= 1) pv += __shfl_xor(pv, off);
  if ((t & 63) == 0) PR[(size_t)(t >> 6) * NDIST + d] = pv;
}

// ------------- CK[row][h] = cb_h . k[row,h,:]  (k inside fused qkv) -------------
__global__ __launch_bounds__(256) void ck_kernel(
    const float* __restrict__ qkv, const float* __restrict__ cb, float* __restrict__ CK) {
  const int gid = blockIdx.x * 4 + (threadIdx.x >> 6);
  const int lane = threadIdx.x & 63;
  const int row = gid >> 3;
  const int h = gid & 7;
  float pv = cb[h * 64 + lane] * qkv[(size_t)row * 2560 + 512 + h * 64 + lane];
  #pragma unroll
  for (int off = 32; off >= 1; off >>= 1) pv += __shfl_xor(pv, off);
  if (lane == 0) CK[(size_t)row * 8 + h] = pv;
}

// ------------- layernorm: fp32 in -> bf16 hi/lo planes out -------------
__global__ __launch_bounds__(256) void ln_kernel(
    const float* __restrict__ x, const float* __restrict__ g,
    const float* __restrict__ bta, unsigned short* __restrict__ oh,
    unsigned short* __restrict__ ol) {
  const int row = blockIdx.x;
  const int t = threadIdx.x;
  __shared__ float red[4];
  __shared__ float bc[2];
  const float4* xr = (const float4*)(x + (size_t)row * 1536);
  float4 v0 = xr[t];
  float4 v1 = make_float4(0.f, 0.f, 0.f, 0.f);
  if (t < 128) v1 = xr[256 + t];
  float s = v0.x + v0.y + v0.z + v0.w;
  if (t < 128) s += v1.x + v1.y + v1.z + v1.w;
  #pragma unroll
  for (int off = 32; off >= 1; off >>= 1) s += __shfl_xor(s, off);
  if ((t & 63) == 0) red[t >> 6] = s;
  __syncthreads();
  if (t == 0) bc[0] = (red[0] + red[1] + red[2] + red[3]) * (1.f / 1536.f);
  __syncthreads();
  const float mu = bc[0];
  float d, s2 = 0.f;
  d = v0.x - mu; s2 += d * d; d = v0.y - mu; s2 += d * d;
  d = v0.z - mu; s2 += d * d; d = v0.w - mu; s2 += d * d;
  if (t < 128) {
    d = v1.x - mu; s2 += d * d; d = v1.y - mu; s2 += d * d;
    d = v1.z - mu; s2 += d * d; d = v1.w - mu; s2 += d * d;
  }
  #pragma unroll
  for (int off = 32; off >= 1; off >>= 1) s2 += __shfl_xor(s2, off);
  if ((t & 63) == 0) red[t >> 6] = s2;
  __syncthreads();
  if (t == 0) bc[1] = (red[0] + red[1] + red[2] + red[3]) * (1.f / 1536.f);
  __syncthreads();
  const float inv = rsqrtf(bc[1] + 1e-5f);
  const float4* g4 = (const float4*)g;
  const float4* b4 = (const float4*)bta;
  float4 gg = g4[t], bb = b4[t];
  float o0 = (v0.x - mu) * inv * gg.x + bb.x;
  float o1 = (v0.y - mu) * inv * gg.y + bb.y;
  float o2 = (v0.z - mu) * inv * gg.z + bb.z;
  float o3 = (v0.w - mu) * inv * gg.w + bb.w;
  ushort4 hv, lv;
  hv.x = f2bu(o0); lv.x = f2bu(o0 - b2f(hv.x));
  hv.y = f2bu(o1); lv.y = f2bu(o1 - b2f(hv.y));
  hv.z = f2bu(o2); lv.z = f2bu(o2 - b2f(hv.z));
  hv.w = f2bu(o3); lv.w = f2bu(o3 - b2f(hv.w));
  *(ushort4*)(oh + (size_t)row * 1536 + t * 4) = hv;
  *(ushort4*)(ol + (size_t)row * 1536 + t * 4) = lv;
  if (t < 128) {
    gg = g4[256 + t]; bb = b4[256 + t];
    o0 = (v1.x - mu) * inv * gg.x + bb.x;
    o1 = (v1.y - mu) * inv * gg.y + bb.y;
    o2 = (v1.z - mu) * inv * gg.z + bb.z;
    o3 = (v1.w - mu) * inv * gg.w + bb.w;
    hv.x = f2bu(o0); lv.x = f2bu(o0 - b2f(hv.x));
    hv.y = f2bu(o1); lv.y = f2bu(o1 - b2f(hv.y));
    hv.z = f2bu(o2); lv.z = f2bu(o2 - b2f(hv.z));
    hv.w = f2bu(o3); lv.w = f2bu(o3 - b2f(hv.w));
    *(ushort4*)(oh + (size_t)row * 1536 + 1024 + t * 4) = hv;
    *(ushort4*)(ol + (size_t)row * 1536 + 1024 + t * 4) = lv;
  }
}

// ------------- weight convert + transpose: W[K][N] fp32 -> T{h,l}[roff+N][KD] -------------
__global__ __launch_bounds__(256) void convw_kernel(
    const float* __restrict__ W, unsigned short* __restrict__ Th,
    unsigned short* __restrict__ Tl, int N, int K, int KD, int roff, float scale) {
  __shared__ float tile[32][33];
  const int n0 = blockIdx.x * 32, k0 = blockIdx.y * 32;
  const int t = threadIdx.x;
  const int cr = t >> 5;
  const int cc = t & 31;
  #pragma unroll
  for (int p = 0; p < 4; ++p) {
    int r = cr + p * 8;
    tile[r][cc] = W[(size_t)(k0 + r) * N + n0 + cc];
  }
  __syncthreads();
  #pragma unroll
  for (int p = 0; p < 4; ++p) {
    int r = cr + p * 8;                    // local n
    float v = tile[cc][r] * scale;         // W[k0+cc][n0+r]
    unsigned short hh = f2bu(v);
    size_t o = (size_t)(roff + n0 + r) * KD + k0 + cc;
    Th[o] = hh;
    Tl[o] = f2bu(v - b2f(hh));
  }
}

// ------------- bf16x3 MFMA GEMM: C = (Ah+Al)@(Bh+Bl)^T(+bias)(+relu)(+res) -------------
// A planes [M][K], B planes [N][K] (pre-transposed), 128x128 tile, BK=32.
template <int EPI>  // 0 = plain fp32 out, 2 = bias+relu -> bf16 hi/lo planes, 3 = bias+res -> fp32
__global__ __launch_bounds__(256, 2) void mgemm_kernel(
    const unsigned short* __restrict__ Ah, const unsigned short* __restrict__ Al,
    const unsigned short* __restrict__ Bh, const unsigned short* __restrict__ Bl,
    float* __restrict__ C, unsigned short* __restrict__ Ch, unsigned short* __restrict__ Cl,
    const float* __restrict__ bias, const float* __restrict__ res,
    int M, int N, int K) {
  __shared__ unsigned short sm[16384];  // Ah[128][32] Al Bh Bl planes, 8KB each
  const int t = threadIdx.x;
  const int lane = t & 63;
  const int w = t >> 6;
  const int wm = w >> 1, wn = w & 1;
  const int m0 = blockIdx.y * 128, n0 = blockIdx.x * 128;

  f32x4 acc[4][4];
  #pragma unroll
  for (int i = 0; i < 4; ++i)
    #pragma unroll
    for (int j = 0; j < 4; ++j) acc[i][j] = (f32x4){0.f, 0.f, 0.f, 0.f};

  // staging geometry: chunk c (0..511) -> row c>>2, kslot c&3 ; this wave: c = w*128 + j*64 + lane
  const int r0 = w * 32 + (lane >> 2);
  const int ks = lane & 3;
  const int lr = lane & 15;
  const int ko = (lane >> 4) * 8;
  char* smb = (char*)&sm[0];

  for (int k0 = 0; k0 < K; k0 += 32) {
    #pragma unroll
    for (int j = 0; j < 2; ++j) {
      int r = r0 + j * 16;
      size_t ga = (size_t)(m0 + r) * K + k0 + ks * 8;
      size_t gb = (size_t)(n0 + r) * K + k0 + ks * 8;
      int lo = (w * 2 + j) * 1024;
      gl_lds16(Ah + ga, smb + lo);
      gl_lds16(Al + ga, smb + 8192 + lo);
      gl_lds16(Bh + gb, smb + 16384 + lo);
      gl_lds16(Bl + gb, smb + 24576 + lo);
    }
    __syncthreads();
    bf16x8 ah[4], al[4], bh[4], bl[4];
    const unsigned short* pa = sm + (wm * 64 + lr) * 32 + ko;
    const unsigned short* pb2 = sm + 8192 + (wn * 64 + lr) * 32 + ko;
    #pragma unroll
    for (int i = 0; i < 4; ++i) {
      ah[i] = *(const bf16x8*)(pa + i * 512);
      al[i] = *(const bf16x8*)(pa + 4096 + i * 512);
      bh[i] = *(const bf16x8*)(pb2 + i * 512);
      bl[i] = *(const bf16x8*)(pb2 + 4096 + i * 512);
    }
    #pragma unroll
    for (int i = 0; i < 4; ++i)
      #pragma unroll
      for (int j = 0; j < 4; ++j) {
        acc[i][j] = __builtin_amdgcn_mfma_f32_16x16x32_bf16(ah[i], bh[j], acc[i][j], 0, 0, 0);
        acc[i][j] = __builtin_amdgcn_mfma_f32_16x16x32_bf16(ah[i], bl[j], acc[i][j], 0, 0, 0);
        acc[i][j] = __builtin_amdgcn_mfma_f32_16x16x32_bf16(al[i], bh[j], acc[i][j], 0, 0, 0);
      }
    __syncthreads();
  }

  const int lq = lane >> 4;
  #pragma unroll
  for (int i = 0; i < 4; ++i) {
    #pragma unroll
    for (int j = 0; j < 4; ++j) {
      int col = n0 + wn * 64 + j * 16 + lr;
      #pragma unroll
      for (int q = 0; q < 4; ++q) {
        int row = m0 + wm * 64 + i * 16 + lq * 4 + q;
        size_t o = (size_t)row * N + col;
        float v = acc[i][j][q];
        if (EPI == 0) {
          C[o] = v;
        } else if (EPI == 3) {
          C[o] = v + bias[col] + res[o];
        } else {  // EPI == 2
          v = fmaxf(v + bias[col], 0.f);
          unsigned short hh = f2bu(v);
          Ch[o] = hh;
          Cl[o] = f2bu(v - b2f(hh));
        }
      }
    }
  }
}

// ------------- flash attention with relative positions (fused qkv input) -------------
__global__ __launch_bounds__(256) void attn_kernel(
    const float* __restrict__ qkv, const float* __restrict__ relk,
    const float* __restrict__ PR, const float* __restrict__ CK,
    unsigned short* __restrict__ aoh, unsigned short* __restrict__ aol) {
  const int n = SEQN;
  const int i0 = blockIdx.x * 32;
  const int h = blockIdx.y;
  const int b = blockIdx.z;
  const int t = threadIdx.x;

  __shared__ float Qs[32][68];
  __shared__ float Ks[32][68];
  __shared__ float Rs[63][68];
  __shared__ float Vs[32][192];
  __shared__ float Ss[32][33];
  __shared__ float mS[32], lS[32], aS[32];

  {
    const float* qb = qkv + ((size_t)(b * n + i0)) * 2560 + h * 64;
    #pragma unroll
    for (int p = 0; p < 2; ++p) {
      int id = t + p * 256;
      int row = id >> 4, c4 = id & 15;
      *(float4*)(&Qs[row][c4 * 4]) = *(const float4*)(qb + (size_t)row * 2560 + c4 * 4);
    }
  }
  if (t < 32) { mS[t] = -1e30f; lS[t] = 0.f; }

  float acc[4][6];
  #pragma unroll
  for (int r = 0; r < 4; ++r)
    #pragma unroll
    for (int c = 0; c < 6; ++c) acc[r][c] = 0.f;

  const int ti = t >> 4, tj = t & 15;
  const int ci = t >> 5, cc = t & 31;
  const int il0 = 2 * ti, jl0 = 2 * tj;

  for (int j0 = 0; j0 < n; j0 += 32) {
    __syncthreads();
    const float* kb = qkv + ((size_t)(b * n + j0)) * 2560 + 512 + h * 64;
    #pragma unroll
    for (int p = 0; p < 2; ++p) {
      int id = t + p * 256;
      int row = id >> 4, c4 = id & 15;
      *(float4*)(&Ks[row][c4 * 4]) = *(const float4*)(kb + (size_t)row * 2560 + c4 * 4);
    }
    const float* vb = qkv + ((size_t)(b * n + j0)) * 2560 + 1024 + h * 192;
    #pragma unroll
    for (int p = 0; p < 6; ++p) {
      int id = t + p * 256;
      int row = id / 48, c4 = id % 48;
      *(float4*)(&Vs[row][c4 * 4]) = *(const float4*)(vb + (size_t)row * 2560 + c4 * 4);
    }
    const int d0 = (n - 1) + j0 - i0 - 31;
    const float* rb = relk + (size_t)d0 * 512 + h * 64;
    #pragma unroll
    for (int p = 0; p < 4; ++p) {
      int id = t + p * 256;
      if (id < 63 * 16) {
        int row = id >> 4, c4 = id & 15;
        *(float4*)(&Rs[row][c4 * 4]) = *(const float4*)(rb + (size_t)row * 512 + c4 * 4);
      }
    }
    __syncthreads();

    float s00 = 0.f, s01 = 0.f, s10 = 0.f, s11 = 0.f;
    const int dm = jl0 + 31 - il0;
    #pragma unroll 4
    for (int kc = 0; kc < 64; kc += 4) {
      float4 q0 = *(const float4*)(&Qs[il0][kc]);
      float4 q1 = *(const float4*)(&Qs[il0 + 1][kc]);
      float4 k0 = *(const float4*)(&Ks[jl0][kc]);
      float4 k1 = *(const float4*)(&Ks[jl0 + 1][kc]);
      float4 rm = *(const float4*)(&Rs[dm - 1][kc]);
      float4 r0 = *(const float4*)(&Rs[dm][kc]);
      float4 rp = *(const float4*)(&Rs[dm + 1][kc]);
      s00 = fmaf(q0.x, k0.x + r0.x, s00); s00 = fmaf(q0.y, k0.y + r0.y, s00);
      s00 = fmaf(q0.z, k0.z + r0.z, s00); s00 = fmaf(q0.w, k0.w + r0.w, s00);
      s01 = fmaf(q0.x, k1.x + rp.x, s01); s01 = fmaf(q0.y, k1.y + rp.y, s01);
      s01 = fmaf(q0.z, k1.z + rp.z, s01); s01 = fmaf(q0.w, k1.w + rp.w, s01);
      s10 = fmaf(q1.x, k0.x + rm.x, s10); s10 = fmaf(q1.y, k0.y + rm.y, s10);
      s10 = fmaf(q1.z, k0.z + rm.z, s10); s10 = fmaf(q1.w, k0.w + rm.w, s10);
      s11 = fmaf(q1.x, k1.x + r0.x, s11); s11 = fmaf(q1.y, k1.y + r0.y, s11);
      s11 = fmaf(q1.z, k1.z + r0.z, s11); s11 = fmaf(q1.w, k1.w + r0.w, s11);
    }
    float ck0 = CK[((size_t)(b * n + j0 + jl0)) * 8 + h];
    float ck1 = CK[((size_t)(b * n + j0 + jl0 + 1)) * 8 + h];
    const float* prh = PR + (size_t)h * NDIST + (n - 1) + j0 - i0;
    float pr00 = prh[jl0 - il0];
    Ss[il0][jl0]         = s00 + ck0 + pr00;
    Ss[il0][jl0 + 1]     = s01 + ck1 + prh[jl0 + 1 - il0];
    Ss[il0 + 1][jl0]     = s10 + ck0 + prh[jl0 - il0 - 1];
    Ss[il0 + 1][jl0 + 1] = s11 + ck1 + pr00;
    __syncthreads();

    if (t < 32) {
      float m_old = mS[t];
      float mx = m_old;
      #pragma unroll
      for (int jj = 0; jj < 32; ++jj) mx = fmaxf(mx, Ss[t][jj]);
      float sum = 0.f;
      #pragma unroll
      for (int jj = 0; jj < 32; ++jj) {
        float p = __expf(Ss[t][jj] - mx);
        Ss[t][jj] = p;
        sum += p;
      }
      float al = __expf(m_old - mx);
      lS[t] = lS[t] * al + sum;
      mS[t] = mx;
      aS[t] = al;
    }
    __syncthreads();

    #pragma unroll
    for (int r = 0; r < 4; ++r) {
      float al = aS[ci * 4 + r];
      #pragma unroll
      for (int c = 0; c < 6; ++c) acc[r][c] *= al;
    }
    #pragma unroll 4
    for (int jj = 0; jj < 32; ++jj) {
      float p0 = Ss[ci * 4 + 0][jj];
      float p1 = Ss[ci * 4 + 1][jj];
      float p2 = Ss[ci * 4 + 2][jj];
      float p3 = Ss[ci * 4 + 3][jj];
      float2 va = *(const float2*)(&Vs[jj][cc * 6 + 0]);
      float2 vb2 = *(const float2*)(&Vs[jj][cc * 6 + 2]);
      float2 vc = *(const float2*)(&Vs[jj][cc * 6 + 4]);
      acc[0][0] = fmaf(p0, va.x, acc[0][0]); acc[0][1] = fmaf(p0, va.y, acc[0][1]);
      acc[0][2] = fmaf(p0, vb2.x, acc[0][2]); acc[0][3] = fmaf(p0, vb2.y, acc[0][3]);
      acc[0][4] = fmaf(p0, vc.x, acc[0][4]); acc[0][5] = fmaf(p0, vc.y, acc[0][5]);
      acc[1][0] = fmaf(p1, va.x, acc[1][0]); acc[1][1] = fmaf(p1, va.y, acc[1][1]);
      acc[1][2] = fmaf(p1, vb2.x, acc[1][2]); acc[1][3] = fmaf(p1, vb2.y, acc[1][3]);
      acc[1][4] = fmaf(p1, vc.x, acc[1][4]); acc[1][5] = fmaf(p1, vc.y, acc[1][5]);
      acc[2][0] = fmaf(p2, va.x, acc[2][0]); acc[2][1] = fmaf(p2, va.y, acc[2][1]);
      acc[2][2] = fmaf(p2, vb2.x, acc[2][2]); acc[2][3] = fmaf(p2, vb2.y, acc[2][3]);
      acc[2][4] = fmaf(p2, vc.x, acc[2][4]); acc[2][5] = fmaf(p2, vc.y, acc[2][5]);
      acc[3][0] = fmaf(p3, va.x, acc[3][0]); acc[3][1] = fmaf(p3, va.y, acc[3][1]);
      acc[3][2] = fmaf(p3, vb2.x, acc[3][2]); acc[3][3] = fmaf(p3, vb2.y, acc[3][3]);
      acc[3][4] = fmaf(p3, vc.x, acc[3][4]); acc[3][5] = fmaf(p3, vc.y, acc[3][5]);
    }
  }

  #pragma unroll
  for (int r = 0; r < 4; ++r) {
    int ig = i0 + ci * 4 + r;
    float linv = 1.0f / lS[ci * 4 + r];
    size_t ob = ((size_t)(b * n + ig)) * 1536 + h * 192 + cc * 6;
    ushort2 hv, lv;
    #pragma unroll
    for (int c = 0; c < 3; ++c) {
      float v0 = acc[r][2 * c] * linv;
      float v1 = acc[r][2 * c + 1] * linv;
      hv.x = f2bu(v0); lv.x = f2bu(v0 - b2f(hv.x));
      hv.y = f2bu(v1); lv.y = f2bu(v1 - b2f(hv.y));
      *(ushort2*)(aoh + ob + 2 * c) = hv;
      *(ushort2*)(aol + ob + 2 * c) = lv;
    }
  }
}

extern "C" void kernel_launch(void* const* d_in, const int* in_sizes, int n_in,
                              void* d_out, int out_size, void* d_ws, size_t ws_size,
                              hipStream_t stream) {
  (void)in_sizes; (void)n_in; (void)out_size; (void)ws_size;
  const float* x   = (const float*)d_in[0];
  const float* g1  = (const float*)d_in[1];
  const float* be1 = (const float*)d_in[2];
  const float* Wq  = (const float*)d_in[3];
  const float* Wk  = (const float*)d_in[4];
  const float* Wv  = (const float*)d_in[5];
  const float* Wo  = (const float*)d_in[6];
  const float* bo  = (const float*)d_in[7];
  const float* Wrk = (const float*)d_in[8];
  const float* cb  = (const float*)d_in[9];
  const float* pb  = (const float*)d_in[10];
  const float* g2  = (const float*)d_in[11];
  const float* be2 = (const float*)d_in[12];
  const float* W1  = (const float*)d_in[13];
  const float* b1  = (const float*)d_in[14];
  const float* W2  = (const float*)d_in[15];
  const float* b2  = (const float*)d_in[16];
  float* out = (float*)d_out;

  char* B = (char*)d_ws;
  float* pos = (float*)(B + 0);                        // 2,358,528 B
  float* rk  = (float*)(B + 2359296);                  // 6,289,408 B
  float* PRb = (float*)(B + 8650752);                  // 98,272 B
  float* CKb = (float*)(B + 8781824);                  // 196,608 B
  unsigned short* xnh = (unsigned short*)(B + 8978432);   // 18,874,368 B
  unsigned short* xnl = (unsigned short*)(B + 27852800);  // 18,874,368 B
  unsigned short* Wbh = (unsigned short*)(B + 46727168);  // 9,437,184 B
  unsigned short* Wbl = (unsigned short*)(B + 56164352);  // 9,437,184 B
  char* BIG = B + 65601536;                            // 113,246,208 B
  float* qkv = (float*)(BIG + 0);                      // 62,914,560 B
  unsigned short* aoh = (unsigned short*)(BIG + 62914560);   // 18,874,368 B
  unsigned short* aol = (unsigned short*)(BIG + 81788928);   // 18,874,368 B
  float* x2 = (float*)(BIG + 0);                       // 37,748,736 B (qkv dead)
  unsigned short* h1h = (unsigned short*)(BIG + 37748736);   // 37,748,736 B
  unsigned short* h1l = (unsigned short*)(BIG + 75497472);   // 37,748,736 B

  pos_embed_kernel<<<NDIST, 64, 0, stream>>>(pos);
  relk_kernel<<<NDIST, 512, 0, stream>>>(pos, Wrk, pb, rk, PRb);
  ln_kernel<<<MROWS, 256, 0, stream>>>(x, g1, be1, xnh, xnl);
  // fused QKV weights (transposed, hi/lo); fold 0.125 scale into Wq
  convw_kernel<<<dim3(512 / 32, 1536 / 32), 256, 0, stream>>>(Wq, Wbh, Wbl, 512, 1536, 1536, 0, 0.125f);
  convw_kernel<<<dim3(512 / 32, 1536 / 32), 256, 0, stream>>>(Wk, Wbh, Wbl, 512, 1536, 1536, 512, 1.0f);
  convw_kernel<<<dim3(1536 / 32, 1536 / 32), 256, 0, stream>>>(Wv, Wbh, Wbl, 1536, 1536, 1536, 1024, 1.0f);
  mgemm_kernel<0><<<dim3(2560 / 128, MROWS / 128), 256, 0, stream>>>(
      xnh, xnl, Wbh, Wbl, qkv, nullptr, nullptr, nullptr, nullptr, MROWS, 2560, 1536);
  ck_kernel<<<MROWS * 8 / 4, 256, 0, stream>>>(qkv, cb, CKb);
  attn_kernel<<<dim3(SEQN / 32, NH, 4), 256, 0, stream>>>(qkv, rk, PRb, CKb, aoh, aol);
  convw_kernel<<<dim3(1536 / 32, 1536 / 32), 256, 0, stream>>>(Wo, Wbh, Wbl, 1536, 1536, 1536, 0, 1.0f);
  mgemm_kernel<3><<<dim3(1536 / 128, MROWS / 128), 256, 0, stream>>>(
      aoh, aol, Wbh, Wbl, x2, nullptr, nullptr, bo, x, MROWS, 1536, 1536);
  ln_kernel<<<MROWS, 256, 0, stream>>>(x2, g2, be2, xnh, xnl);
  convw_kernel<<<dim3(3072 / 32, 1536 / 32), 256, 0, stream>>>(W1, Wbh, Wbl, 3072, 1536, 1536, 0, 1.0f);
  mgemm_kernel<2><<<dim3(3072 / 128, MROWS / 128), 256, 0, stream>>>(
      xnh, xnl, Wbh, Wbl, nullptr, h1h, h1l, b1, nullptr, MROWS, 3072, 1536);
  convw_kernel<<<dim3(1536 / 32, 3072 / 32), 256, 0, stream>>>(W2, Wbh, Wbl, 1536, 3072, 3072, 0, 1.0f);
  mgemm_kernel<3><<<dim3(1536 / 128, MROWS / 128), 256, 0, stream>>>(
      h1h, h1l, Wbh, Wbl, out, nullptr, nullptr, b2, x2, MROWS, 1536, 3072);
}

// Round 4
// 1294.987 us; speedup vs baseline: 2.9501x; 1.5062x over previous
//
#include <hip/hip_runtime.h>
#include <hip/hip_bf16.h>
#include <math.h>

#define SEQN 1536
#define NH 8
#define MROWS 6144      // BATCH*SEQ
#define NDIST 3071      // 2*SEQ-1

typedef __attribute__((ext_vector_type(8))) short bf16x8;
typedef __attribute__((ext_vector_type(4))) float f32x4;

#define MFMA16(a, b, c) __builtin_amdgcn_mfma_f32_16x16x32_bf16(a, b, c, 0, 0, 0)

__device__ __forceinline__ unsigned short f2bu(float x) {
  __hip_bfloat16 h = __float2bfloat16(x);
  return *reinterpret_cast<unsigned short*>(&h);
}
__device__ __forceinline__ float b2f(unsigned short u) {
  __hip_bfloat16 h;
  *reinterpret_cast<unsigned short*>(&h) = u;
  return __bfloat162float(h);
}

__device__ __forceinline__ void gl_lds16(const void* g, void* l) {
  __builtin_amdgcn_global_load_lds(
      (const __attribute__((address_space(1))) void*)g,
      (__attribute__((address_space(3))) void*)l, 16, 0, 0);
}

// ---------------- positional embedding table: pos[3071][192] ----------------
__global__ __launch_bounds__(64) void pos_embed_kernel(float* __restrict__ pos) {
  int row = blockIdx.x;
  int j = threadIdx.x;
  if (j >= 32) return;
  float dist = (float)(row - (SEQN - 1));
  float adist = fabsf(dist);
  float sgn = (dist > 0.f) ? 1.f : (dist < 0.f ? -1.f : 0.f);

  const float max_range = 10.58496250072116f;  // log2(1536)
  float hl = exp2f(3.0f + ((max_range - 3.0f) / 31.0f) * (float)j);
  float e_exp = expf(-0.6931471805599453f / hl * adist);

  float cw = exp2f((float)(j + 1)) - 1.0f;
  float e_cm = (cw > adist) ? 1.0f : 0.0f;

  float mean = 48.0f * (float)(j + 1);
  float tt = mean / 24.0f;
  float conc = tt * tt;
  float rate = mean / 576.0f;
  float log_unnorm = (conc - 1.0f) * logf(fmaxf(adist, 1e-20f)) - rate * adist;
  float log_norm = lgammaf(conc) - conc * logf(rate);
  float prob = expf(log_unnorm - log_norm) + 1e-8f;
  float mx = prob;
  #pragma unroll
  for (int off = 16; off >= 1; off >>= 1)
    mx = fmaxf(mx, __shfl_xor(mx, off, 32));
  float e_g = prob / mx;

  float* o = pos + (size_t)row * 192;
  o[j] = e_exp;        o[32 + j] = e_cm;        o[64 + j] = e_g;
  o[96 + j] = sgn * e_exp; o[128 + j] = sgn * e_cm; o[160 + j] = sgn * e_g;
}

// ------------- rel_k = pos @ Wrk -> bf16 hi/lo planes [3072 rows][512]; PR[h][d] -------------
__global__ __launch_bounds__(512) void relk_kernel(
    const float* __restrict__ pos, const float* __restrict__ Wrk,
    const float* __restrict__ pb, unsigned short* __restrict__ rkh,
    unsigned short* __restrict__ rkl, float* __restrict__ PR) {
  const int d = blockIdx.x;
  const int t = threadIdx.x;
  __shared__ float prow[192];
  if (t < 192) prow[t] = pos[(size_t)d * 192 + t];
  __syncthreads();
  float acc = 0.f;
  #pragma unroll 8
  for (int kk = 0; kk < 192; ++kk)
    acc = fmaf(prow[kk], Wrk[(size_t)kk * 512 + t], acc);
  unsigned short hh = f2bu(acc);
  rkh[(size_t)d * 512 + t] = hh;
  rkl[(size_t)d * 512 + t] = f2bu(acc - b2f(hh));
  float pv = pb[t] * acc;
  #pragma unroll
  for (int off = 32; off >= 1; off >>= 1) pv += __shfl_xor(pv, off);
  if ((t & 63) == 0) PR[(size_t)(t >> 6) * NDIST + d] = pv;
}

// ------------- CK[row][h] = cb_h . k[row,h,:] from bf16 hi/lo K planes -------------
__global__ __launch_bounds__(256) void ck_kernel(
    const unsigned short* __restrict__ Kh, const unsigned short* __restrict__ Kl,
    const float* __restrict__ cb, float* __restrict__ CK) {
  const int gid = blockIdx.x * 4 + (threadIdx.x >> 6);
  const int lane = threadIdx.x & 63;
  const int row = gid >> 3;
  const int h = gid & 7;
  size_t idx = (size_t)row * 512 + h * 64 + lane;
  float kv = b2f(Kh[idx]) + b2f(Kl[idx]);
  float pv = cb[h * 64 + lane] * kv;
  #pragma unroll
  for (int off = 32; off >= 1; off >>= 1) pv += __shfl_xor(pv, off);
  if (lane == 0) CK[(size_t)row * 8 + h] = pv;
}

// ------------- layernorm: fp32 in -> bf16 hi/lo planes out -------------
__global__ __launch_bounds__(256) void ln_kernel(
    const float* __restrict__ x, const float* __restrict__ g,
    const float* __restrict__ bta, unsigned short* __restrict__ oh,
    unsigned short* __restrict__ ol) {
  const int row = blockIdx.x;
  const int t = threadIdx.x;
  __shared__ float red[4];
  __shared__ float bc[2];
  const float4* xr = (const float4*)(x + (size_t)row * 1536);
  float4 v0 = xr[t];
  float4 v1 = make_float4(0.f, 0.f, 0.f, 0.f);
  if (t < 128) v1 = xr[256 + t];
  float s = v0.x + v0.y + v0.z + v0.w;
  if (t < 128) s += v1.x + v1.y + v1.z + v1.w;
  #pragma unroll
  for (int off = 32; off >= 1; off >>= 1) s += __shfl_xor(s, off);
  if ((t & 63) == 0) red[t >> 6] = s;
  __syncthreads();
  if (t == 0) bc[0] = (red[0] + red[1] + red[2] + red[3]) * (1.f / 1536.f);
  __syncthreads();
  const float mu = bc[0];
  float d, s2 = 0.f;
  d = v0.x - mu; s2 += d * d; d = v0.y - mu; s2 += d * d;
  d = v0.z - mu; s2 += d * d; d = v0.w - mu; s2 += d * d;
  if (t < 128) {
    d = v1.x - mu; s2 += d * d; d = v1.y - mu; s2 += d * d;
    d = v1.z - mu; s2 += d * d; d = v1.w - mu; s2 += d * d;
  }
  #pragma unroll
  for (int off = 32; off >= 1; off >>= 1) s2 += __shfl_xor(s2, off);
  if ((t & 63) == 0) red[t >> 6] = s2;
  __syncthreads();
  if (t == 0) bc[1] = (red[0] + red[1] + red[2] + red[3]) * (1.f / 1536.f);
  __syncthreads();
  const float inv = rsqrtf(bc[1] + 1e-5f);
  const float4* g4 = (const float4*)g;
  const float4* b4 = (const float4*)bta;
  float4 gg = g4[t], bb = b4[t];
  float o0 = (v0.x - mu) * inv * gg.x + bb.x;
  float o1 = (v0.y - mu) * inv * gg.y + bb.y;
  float o2 = (v0.z - mu) * inv * gg.z + bb.z;
  float o3 = (v0.w - mu) * inv * gg.w + bb.w;
  ushort4 hv, lv;
  hv.x = f2bu(o0); lv.x = f2bu(o0 - b2f(hv.x));
  hv.y = f2bu(o1); lv.y = f2bu(o1 - b2f(hv.y));
  hv.z = f2bu(o2); lv.z = f2bu(o2 - b2f(hv.z));
  hv.w = f2bu(o3); lv.w = f2bu(o3 - b2f(hv.w));
  *(ushort4*)(oh + (size_t)row * 1536 + t * 4) = hv;
  *(ushort4*)(ol + (size_t)row * 1536 + t * 4) = lv;
  if (t < 128) {
    gg = g4[256 + t]; bb = b4[256 + t];
    o0 = (v1.x - mu) * inv * gg.x + bb.x;
    o1 = (v1.y - mu) * inv * gg.y + bb.y;
    o2 = (v1.z - mu) * inv * gg.z + bb.z;
    o3 = (v1.w - mu) * inv * gg.w + bb.w;
    hv.x = f2bu(o0); lv.x = f2bu(o0 - b2f(hv.x));
    hv.y = f2bu(o1); lv.y = f2bu(o1 - b2f(hv.y));
    hv.z = f2bu(o2); lv.z = f2bu(o2 - b2f(hv.z));
    hv.w = f2bu(o3); lv.w = f2bu(o3 - b2f(hv.w));
    *(ushort4*)(oh + (size_t)row * 1536 + 1024 + t * 4) = hv;
    *(ushort4*)(ol + (size_t)row * 1536 + 1024 + t * 4) = lv;
  }
}

// ------------- weight convert + transpose: W[K][N] fp32 -> T{h,l}[roff+N][KD] -------------
__global__ __launch_bounds__(256) void convw_kernel(
    const float* __restrict__ W, unsigned short* __restrict__ Th,
    unsigned short* __restrict__ Tl, int N, int K, int KD, int roff, float scale) {
  __shared__ float tile[32][33];
  const int n0 = blockIdx.x * 32, k0 = blockIdx.y * 32;
  const int t = threadIdx.x;
  const int cr = t >> 5;
  const int cc = t & 31;
  #pragma unroll
  for (int p = 0; p < 4; ++p) {
    int r = cr + p * 8;
    tile[r][cc] = W[(size_t)(k0 + r) * N + n0 + cc];
  }
  __syncthreads();
  #pragma unroll
  for (int p = 0; p < 4; ++p) {
    int r = cr + p * 8;                    // local n
    float v = tile[cc][r] * scale;         // W[k0+cc][n0+r]
    unsigned short hh = f2bu(v);
    size_t o = (size_t)(roff + n0 + r) * KD + k0 + cc;
    Th[o] = hh;
    Tl[o] = f2bu(v - b2f(hh));
  }
}

// ------------- bf16x3 MFMA GEMM, 128x128 tile, BK=32 -------------
// EPI: 2 = bias+relu -> bf16 hi/lo planes; 3 = bias+residual -> fp32;
//      4 = QKV epilogue: Q/K bf16 hi/lo planes + V^T bf16 plane
template <int EPI>
__global__ __launch_bounds__(256, 2) void mgemm_kernel(
    const unsigned short* __restrict__ Ah, const unsigned short* __restrict__ Al,
    const unsigned short* __restrict__ Bh, const unsigned short* __restrict__ Bl,
    float* __restrict__ C, unsigned short* __restrict__ Ch, unsigned short* __restrict__ Cl,
    unsigned short* __restrict__ Kph, unsigned short* __restrict__ Kpl,
    unsigned short* __restrict__ Vt,
    const float* __restrict__ bias, const float* __restrict__ res,
    int M, int N, int K) {
  __shared__ unsigned short sm[16384];  // Ah[128][32] Al Bh Bl planes, 8KB each
  const int t = threadIdx.x;
  const int lane = t & 63;
  const int w = t >> 6;
  const int wm = w >> 1, wn = w & 1;
  const int m0 = blockIdx.y * 128, n0 = blockIdx.x * 128;

  f32x4 acc[4][4];
  #pragma unroll
  for (int i = 0; i < 4; ++i)
    #pragma unroll
    for (int j = 0; j < 4; ++j) acc[i][j] = (f32x4){0.f, 0.f, 0.f, 0.f};

  const int r0 = w * 32 + (lane >> 2);
  const int ks = lane & 3;
  const int lr = lane & 15;
  const int ko = (lane >> 4) * 8;
  char* smb = (char*)&sm[0];

  for (int k0 = 0; k0 < K; k0 += 32) {
    #pragma unroll
    for (int j = 0; j < 2; ++j) {
      int r = r0 + j * 16;
      size_t ga = (size_t)(m0 + r) * K + k0 + ks * 8;
      size_t gb = (size_t)(n0 + r) * K + k0 + ks * 8;
      int lo = (w * 2 + j) * 1024;
      gl_lds16(Ah + ga, smb + lo);
      gl_lds16(Al + ga, smb + 8192 + lo);
      gl_lds16(Bh + gb, smb + 16384 + lo);
      gl_lds16(Bl + gb, smb + 24576 + lo);
    }
    __syncthreads();
    bf16x8 ah[4], al[4], bh[4], bl[4];
    const unsigned short* pa = sm + (wm * 64 + lr) * 32 + ko;
    const unsigned short* pb2 = sm + 8192 + (wn * 64 + lr) * 32 + ko;
    #pragma unroll
    for (int i = 0; i < 4; ++i) {
      ah[i] = *(const bf16x8*)(pa + i * 512);
      al[i] = *(const bf16x8*)(pa + 4096 + i * 512);
      bh[i] = *(const bf16x8*)(pb2 + i * 512);
      bl[i] = *(const bf16x8*)(pb2 + 4096 + i * 512);
    }
    #pragma unroll
    for (int i = 0; i < 4; ++i)
      #pragma unroll
      for (int j = 0; j < 4; ++j) {
        acc[i][j] = MFMA16(ah[i], bh[j], acc[i][j]);
        acc[i][j] = MFMA16(ah[i], bl[j], acc[i][j]);
        acc[i][j] = MFMA16(al[i], bh[j], acc[i][j]);
      }
    __syncthreads();
  }

  const int lq = lane >> 4;
  #pragma unroll
  for (int i = 0; i < 4; ++i) {
    #pragma unroll
    for (int j = 0; j < 4; ++j) {
      const int c0 = n0 + wn * 64 + j * 16;   // tile col base (uniform)
      const int col = c0 + lr;
      const int rbase = m0 + wm * 64 + i * 16 + lq * 4;
      if (EPI == 3) {
        #pragma unroll
        for (int q = 0; q < 4; ++q) {
          size_t o = (size_t)(rbase + q) * N + col;
          C[o] = acc[i][j][q] + bias[col] + res[o];
        }
      } else if (EPI == 2) {
        #pragma unroll
        for (int q = 0; q < 4; ++q) {
          size_t o = (size_t)(rbase + q) * N + col;
          float v = fmaxf(acc[i][j][q] + bias[col], 0.f);
          unsigned short hh = f2bu(v);
          Ch[o] = hh;
          Cl[o] = f2bu(v - b2f(hh));
        }
      } else {  // EPI == 4: QKV split epilogue
        if (c0 < 512) {
          #pragma unroll
          for (int q = 0; q < 4; ++q) {
            float v = acc[i][j][q];
            unsigned short hh = f2bu(v);
            size_t o = (size_t)(rbase + q) * 512 + col;
            Ch[o] = hh;
            Cl[o] = f2bu(v - b2f(hh));
          }
        } else if (c0 < 1024) {
          #pragma unroll
          for (int q = 0; q < 4; ++q) {
            float v = acc[i][j][q];
            unsigned short hh = f2bu(v);
            size_t o = (size_t)(rbase + q) * 512 + (col - 512);
            Kph[o] = hh;
            Kpl[o] = f2bu(v - b2f(hh));
          }
        } else {
          int dv = col - 1024;
          int hd = dv / 192;
          int dvh = dv - hd * 192;
          int bb = rbase / 1536;
          int nloc = rbase - bb * 1536;
          ushort4 pk;
          pk.x = f2bu(acc[i][j][0]);
          pk.y = f2bu(acc[i][j][1]);
          pk.z = f2bu(acc[i][j][2]);
          pk.w = f2bu(acc[i][j][3]);
          *(ushort4*)(Vt + (((size_t)bb * 8 + hd) * 192 + dvh) * 1536 + nloc) = pk;
        }
      }
    }
  }
}

// ------------- MFMA flash attention with relative positions -------------
// Wave-autonomous: each wave owns 16 Q-rows; fragments loaded direct from global.
// S[i,j] = q.k (bf16x3) + gather(T[i,e]=q.relk+PR) + CK[j];  online softmax; PV bf16.
__global__ __launch_bounds__(256, 3) void attn_kernel(
    const unsigned short* __restrict__ Qh, const unsigned short* __restrict__ Ql,
    const unsigned short* __restrict__ Kh, const unsigned short* __restrict__ Kl,
    const unsigned short* __restrict__ Vt, const unsigned short* __restrict__ rkh,
    const unsigned short* __restrict__ rkl, const float* __restrict__ PR,
    const float* __restrict__ CK, unsigned short* __restrict__ aoh,
    unsigned short* __restrict__ aol) {
  __shared__ unsigned short Ps[4][16][72];
  const int id = blockIdx.x;
  const int xcd = id & 7, s = id >> 3;           // XCD-chunked (b,h) mapping
  const int bh = xcd * 4 + s / 24;
  const int it = s % 24;
  const int b = bh >> 3, h = bh & 7;
  const int w = threadIdx.x >> 6;
  const int lane = threadIdx.x & 63;
  const int c15 = lane & 15, g = lane >> 4;
  const int qrow0 = it * 64 + w * 16;            // wave's 16 Q rows

  // persistent Q fragments (A-operand: lane holds row c15, k = g*8..+8)
  bf16x8 qh0, qh1, ql0, ql1;
  {
    size_t qo = ((size_t)(b * SEQN + qrow0 + c15)) * 512 + h * 64 + g * 8;
    qh0 = *(const bf16x8*)(Qh + qo);
    qh1 = *(const bf16x8*)(Qh + qo + 32);
    ql0 = *(const bf16x8*)(Ql + qo);
    ql1 = *(const bf16x8*)(Ql + qo + 32);
  }

  f32x4 acc[12];
  #pragma unroll
  for (int d = 0; d < 12; ++d) acc[d] = (f32x4){0.f, 0.f, 0.f, 0.f};
  float mrun[4], lrun[4];
  #pragma unroll
  for (int q = 0; q < 4; ++q) { mrun[q] = -1e30f; lrun[q] = 0.f; }

  for (int j0 = 0; j0 < SEQN; j0 += 64) {
    const int dbase = 1520 + j0 - qrow0;         // min d in this chunk's band
    // ---- T[i][e] = q_i . relk[dbase+e] + PR[dbase+e],  e in [0,80) (79 used) ----
    f32x4 T[5];
    #pragma unroll
    for (int et = 0; et < 5; ++et) {
      size_t ro = ((size_t)(dbase + et * 16 + c15)) * 512 + h * 64 + g * 8;
      bf16x8 rh0 = *(const bf16x8*)(rkh + ro);
      bf16x8 rh1 = *(const bf16x8*)(rkh + ro + 32);
      bf16x8 rl0 = *(const bf16x8*)(rkl + ro);
      bf16x8 rl1 = *(const bf16x8*)(rkl + ro + 32);
      f32x4 tt = (f32x4){0.f, 0.f, 0.f, 0.f};
      tt = MFMA16(qh0, rh0, tt); tt = MFMA16(qh1, rh1, tt);
      tt = MFMA16(qh0, rl0, tt); tt = MFMA16(qh1, rl1, tt);
      tt = MFMA16(ql0, rh0, tt); tt = MFMA16(ql1, rh1, tt);
      float prv = PR[(size_t)h * NDIST + dbase + et * 16 + c15];
      #pragma unroll
      for (int q = 0; q < 4; ++q) tt[q] += prv;
      T[et] = tt;
    }
    // ---- S = Q @ K^T + CK + gather(T) ----
    f32x4 S[4];
    #pragma unroll
    for (int st = 0; st < 4; ++st) {
      size_t ko2 = ((size_t)(b * SEQN + j0 + st * 16 + c15)) * 512 + h * 64 + g * 8;
      bf16x8 kh0 = *(const bf16x8*)(Kh + ko2);
      bf16x8 kh1 = *(const bf16x8*)(Kh + ko2 + 32);
      bf16x8 kl0 = *(const bf16x8*)(Kl + ko2);
      bf16x8 kl1 = *(const bf16x8*)(Kl + ko2 + 32);
      f32x4 ss = (f32x4){0.f, 0.f, 0.f, 0.f};
      ss = MFMA16(qh0, kh0, ss); ss = MFMA16(qh1, kh1, ss);
      ss = MFMA16(qh0, kl0, ss); ss = MFMA16(qh1, kl1, ss);
      ss = MFMA16(ql0, kh0, ss); ss = MFMA16(ql1, kh1, ss);
      float ckv = CK[((size_t)(b * SEQN + j0 + st * 16 + c15)) * 8 + h];
      #pragma unroll
      for (int q = 0; q < 4; ++q) {
        int eoff = c15 + 15 - 4 * g - q;          // in [0,30]
        int src = (lane & 48) | (eoff & 15);
        float v0 = __shfl(T[st][q], src);
        float v1 = __shfl(T[st + 1][q], src);
        ss[q] += ckv + ((eoff < 16) ? v0 : v1);
      }
      S[st] = ss;
    }
    // ---- online softmax (row groups of 16 lanes) ----
    float mx[4], al[4], sum[4];
    #pragma unroll
    for (int q = 0; q < 4; ++q)
      mx[q] = fmaxf(fmaxf(S[0][q], S[1][q]), fmaxf(S[2][q], S[3][q]));
    #pragma unroll
    for (int off = 8; off >= 1; off >>= 1)
      #pragma unroll
      for (int q = 0; q < 4; ++q) mx[q] = fmaxf(mx[q], __shfl_xor(mx[q], off));
    #pragma unroll
    for (int q = 0; q < 4; ++q) {
      float mn = fmaxf(mrun[q], mx[q]);
      al[q] = __expf(mrun[q] - mn);
      mrun[q] = mn;
      sum[q] = 0.f;
    }
    #pragma unroll
    for (int st = 0; st < 4; ++st)
      #pragma unroll
      for (int q = 0; q < 4; ++q) {
        float p = __expf(S[st][q] - mrun[q]);
        sum[q] += p;
        Ps[w][4 * g + q][st * 16 + c15] = f2bu(p);
      }
    #pragma unroll
    for (int off = 8; off >= 1; off >>= 1)
      #pragma unroll
      for (int q = 0; q < 4; ++q) sum[q] += __shfl_xor(sum[q], off);
    #pragma unroll
    for (int q = 0; q < 4; ++q) lrun[q] = lrun[q] * al[q] + sum[q];
    #pragma unroll
    for (int d = 0; d < 12; ++d)
      #pragma unroll
      for (int q = 0; q < 4; ++q) acc[d][q] *= al[q];
    // ---- PV: P[16][64] @ V[64][192] ----
    #pragma unroll
    for (int jk = 0; jk < 2; ++jk) {
      bf16x8 pf = *(const bf16x8*)(&Ps[w][c15][jk * 32 + g * 8]);
      const unsigned short* vp =
          Vt + (((size_t)(b * 8 + h)) * 192 + c15) * SEQN + j0 + jk * 32 + g * 8;
      #pragma unroll
      for (int d = 0; d < 12; ++d) {
        bf16x8 vf = *(const bf16x8*)(vp + (size_t)d * 16 * SEQN);
        acc[d] = MFMA16(pf, vf, acc[d]);
      }
    }
  }
  // ---- epilogue: out = acc / l -> bf16 hi/lo planes ----
  float rinv[4];
  #pragma unroll
  for (int q = 0; q < 4; ++q) rinv[q] = 1.0f / lrun[q];
  #pragma unroll
  for (int d = 0; d < 12; ++d) {
    int col = h * 192 + d * 16 + c15;
    #pragma unroll
    for (int q = 0; q < 4; ++q) {
      size_t row = (size_t)(b * SEQN + qrow0 + 4 * g + q);
      float v = acc[d][q] * rinv[q];
      unsigned short hh = f2bu(v);
      aoh[row * 1536 + col] = hh;
      aol[row * 1536 + col] = f2bu(v - b2f(hh));
    }
  }
}

extern "C" void kernel_launch(void* const* d_in, const int* in_sizes, int n_in,
                              void* d_out, int out_size, void* d_ws, size_t ws_size,
                              hipStream_t stream) {
  (void)in_sizes; (void)n_in; (void)out_size; (void)ws_size;
  const float* x   = (const float*)d_in[0];
  const float* g1  = (const float*)d_in[1];
  const float* be1 = (const float*)d_in[2];
  const float* Wq  = (const float*)d_in[3];
  const float* Wk  = (const float*)d_in[4];
  const float* Wv  = (const float*)d_in[5];
  const float* Wo  = (const float*)d_in[6];
  const float* bo  = (const float*)d_in[7];
  const float* Wrk = (const float*)d_in[8];
  const float* cb  = (const float*)d_in[9];
  const float* pb  = (const float*)d_in[10];
  const float* g2  = (const float*)d_in[11];
  const float* be2 = (const float*)d_in[12];
  const float* W1  = (const float*)d_in[13];
  const float* b1  = (const float*)d_in[14];
  const float* W2  = (const float*)d_in[15];
  const float* b2  = (const float*)d_in[16];
  float* out = (float*)d_out;

  char* B = (char*)d_ws;
  float* pos          = (float*)(B + 0);                   //  2,359,296
  unsigned short* rkh = (unsigned short*)(B + 2359296);    //  3,145,728 (3072 rows)
  unsigned short* rkl = (unsigned short*)(B + 5505024);    //  3,145,728
  float* PRb          = (float*)(B + 8650752);             //     98,304
  float* CKb          = (float*)(B + 8749056);             //    196,608
  unsigned short* xnh = (unsigned short*)(B + 8945664);    // 18,874,368
  unsigned short* xnl = (unsigned short*)(B + 27820032);   // 18,874,368
  unsigned short* Wbh = (unsigned short*)(B + 46694400);   //  9,437,184
  unsigned short* Wbl = (unsigned short*)(B + 56131584);   //  9,437,184
  unsigned short* Qph = (unsigned short*)(B + 65568768);   //  6,291,456
  unsigned short* Qpl = (unsigned short*)(B + 71860224);   //  6,291,456
  unsigned short* Kph = (unsigned short*)(B + 78151680);   //  6,291,456
  unsigned short* Kpl = (unsigned short*)(B + 84443136);   //  6,291,456
  unsigned short* Vtp = (unsigned short*)(B + 90734592);   // 18,874,368
  float* x2           = (float*)(B + 65568768);            // 37,748,736 (after attn; overlays Q/K/Vt-head)
  unsigned short* aoh = (unsigned short*)(B + 109608960);  // 18,874,368
  unsigned short* aol = (unsigned short*)(B + 128483328);  // 18,874,368
  unsigned short* h1h = (unsigned short*)(B + 103317504);  // 37,748,736 (after Wo; overlays Vt-tail/aoh)
  unsigned short* h1l = (unsigned short*)(B + 141066240);  // 37,748,736 -> ends 178,814,976

  pos_embed_kernel<<<NDIST, 64, 0, stream>>>(pos);
  relk_kernel<<<NDIST, 512, 0, stream>>>(pos, Wrk, pb, rkh, rkl, PRb);
  ln_kernel<<<MROWS, 256, 0, stream>>>(x, g1, be1, xnh, xnl);
  // fused QKV weights (transposed, hi/lo); fold 0.125 scale into Wq
  convw_kernel<<<dim3(16, 48), 256, 0, stream>>>(Wq, Wbh, Wbl, 512, 1536, 1536, 0, 0.125f);
  convw_kernel<<<dim3(16, 48), 256, 0, stream>>>(Wk, Wbh, Wbl, 512, 1536, 1536, 512, 1.0f);
  convw_kernel<<<dim3(48, 48), 256, 0, stream>>>(Wv, Wbh, Wbl, 1536, 1536, 1536, 1024, 1.0f);
  mgemm_kernel<4><<<dim3(20, 48), 256, 0, stream>>>(
      xnh, xnl, Wbh, Wbl, nullptr, Qph, Qpl, Kph, Kpl, Vtp, nullptr, nullptr,
      MROWS, 2560, 1536);
  ck_kernel<<<MROWS * 2, 256, 0, stream>>>(Kph, Kpl, cb, CKb);
  attn_kernel<<<768, 256, 0, stream>>>(Qph, Qpl, Kph, Kpl, Vtp, rkh, rkl, PRb, CKb, aoh, aol);
  convw_kernel<<<dim3(48, 48), 256, 0, stream>>>(Wo, Wbh, Wbl, 1536, 1536, 1536, 0, 1.0f);
  mgemm_kernel<3><<<dim3(12, 48), 256, 0, stream>>>(
      aoh, aol, Wbh, Wbl, x2, nullptr, nullptr, nullptr, nullptr, nullptr, bo, x,
      MROWS, 1536, 1536);
  ln_kernel<<<MROWS, 256, 0, stream>>>(x2, g2, be2, xnh, xnl);
  convw_kernel<<<dim3(96, 48), 256, 0, stream>>>(W1, Wbh, Wbl, 3072, 1536, 1536, 0, 1.0f);
  mgemm_kernel<2><<<dim3(24, 48), 256, 0, stream>>>(
      xnh, xnl, Wbh, Wbl, nullptr, h1h, h1l, nullptr, nullptr, nullptr, b1, nullptr,
      MROWS, 3072, 1536);
  convw_kernel<<<dim3(48, 96), 256, 0, stream>>>(W2, Wbh, Wbl, 1536, 3072, 3072, 0, 1.0f);
  mgemm_kernel<3><<<dim3(12, 48), 256, 0, stream>>>(
      h1h, h1l, Wbh, Wbl, out, nullptr, nullptr, nullptr, nullptr, nullptr, b2, x2,
      MROWS, 1536, 3072);
}

// Round 5
// 1216.792 us; speedup vs baseline: 3.1397x; 1.0643x over previous
//
#include <hip/hip_runtime.h>
#include <hip/hip_bf16.h>
#include <math.h>

#define SEQN 1536
#define NH 8
#define MROWS 6144      // BATCH*SEQ
#define NDIST 3071      // 2*SEQ-1

typedef __attribute__((ext_vector_type(8))) short bf16x8;
typedef __attribute__((ext_vector_type(4))) float f32x4;

#define MFMA16(a, b, c) __builtin_amdgcn_mfma_f32_16x16x32_bf16(a, b, c, 0, 0, 0)

__device__ __forceinline__ unsigned short f2bu(float x) {
  __hip_bfloat16 h = __float2bfloat16(x);
  return *reinterpret_cast<unsigned short*>(&h);
}
__device__ __forceinline__ float b2f(unsigned short u) {
  __hip_bfloat16 h;
  *reinterpret_cast<unsigned short*>(&h) = u;
  return __bfloat162float(h);
}

__device__ __forceinline__ void gl_lds16(const void* g, void* l) {
  __builtin_amdgcn_global_load_lds(
      (const __attribute__((address_space(1))) void*)g,
      (__attribute__((address_space(3))) void*)l, 16, 0, 0);
}

// ---------------- positional embedding table: pos[3071][192] ----------------
__global__ __launch_bounds__(64) void pos_embed_kernel(float* __restrict__ pos) {
  int row = blockIdx.x;
  int j = threadIdx.x;
  if (j >= 32) return;
  float dist = (float)(row - (SEQN - 1));
  float adist = fabsf(dist);
  float sgn = (dist > 0.f) ? 1.f : (dist < 0.f ? -1.f : 0.f);

  const float max_range = 10.58496250072116f;  // log2(1536)
  float hl = exp2f(3.0f + ((max_range - 3.0f) / 31.0f) * (float)j);
  float e_exp = expf(-0.6931471805599453f / hl * adist);

  float cw = exp2f((float)(j + 1)) - 1.0f;
  float e_cm = (cw > adist) ? 1.0f : 0.0f;

  float mean = 48.0f * (float)(j + 1);
  float tt = mean / 24.0f;
  float conc = tt * tt;
  float rate = mean / 576.0f;
  float log_unnorm = (conc - 1.0f) * logf(fmaxf(adist, 1e-20f)) - rate * adist;
  float log_norm = lgammaf(conc) - conc * logf(rate);
  float prob = expf(log_unnorm - log_norm) + 1e-8f;
  float mx = prob;
  #pragma unroll
  for (int off = 16; off >= 1; off >>= 1)
    mx = fmaxf(mx, __shfl_xor(mx, off, 32));
  float e_g = prob / mx;

  float* o = pos + (size_t)row * 192;
  o[j] = e_exp;        o[32 + j] = e_cm;        o[64 + j] = e_g;
  o[96 + j] = sgn * e_exp; o[128 + j] = sgn * e_cm; o[160 + j] = sgn * e_g;
}

// ------------- rel_k = pos @ Wrk -> bf16 hi/lo planes [3072 rows][512]; PR[h][d] -------------
__global__ __launch_bounds__(512) void relk_kernel(
    const float* __restrict__ pos, const float* __restrict__ Wrk,
    const float* __restrict__ pb, unsigned short* __restrict__ rkh,
    unsigned short* __restrict__ rkl, float* __restrict__ PR) {
  const int d = blockIdx.x;
  const int t = threadIdx.x;
  __shared__ float prow[192];
  if (t < 192) prow[t] = pos[(size_t)d * 192 + t];
  __syncthreads();
  float acc = 0.f;
  #pragma unroll 8
  for (int kk = 0; kk < 192; ++kk)
    acc = fmaf(prow[kk], Wrk[(size_t)kk * 512 + t], acc);
  unsigned short hh = f2bu(acc);
  rkh[(size_t)d * 512 + t] = hh;
  rkl[(size_t)d * 512 + t] = f2bu(acc - b2f(hh));
  float pv = pb[t] * acc;
  #pragma unroll
  for (int off = 32; off >= 1; off >>= 1) pv += __shfl_xor(pv, off);
  if ((t & 63) == 0) PR[(size_t)(t >> 6) * NDIST + d] = pv;
}

// ------------- CK[row][h] = cb_h . k[row,h,:] from bf16 hi/lo K planes -------------
__global__ __launch_bounds__(256) void ck_kernel(
    const unsigned short* __restrict__ Kh, const unsigned short* __restrict__ Kl,
    const float* __restrict__ cb, float* __restrict__ CK) {
  const int gid = blockIdx.x * 4 + (threadIdx.x >> 6);
  const int lane = threadIdx.x & 63;
  const int row = gid >> 3;
  const int h = gid & 7;
  size_t idx = (size_t)row * 512 + h * 64 + lane;
  float kv = b2f(Kh[idx]) + b2f(Kl[idx]);
  float pv = cb[h * 64 + lane] * kv;
  #pragma unroll
  for (int off = 32; off >= 1; off >>= 1) pv += __shfl_xor(pv, off);
  if (lane == 0) CK[(size_t)row * 8 + h] = pv;
}

// ------------- layernorm: fp32 in -> bf16 hi/lo planes out -------------
__global__ __launch_bounds__(256) void ln_kernel(
    const float* __restrict__ x, const float* __restrict__ g,
    const float* __restrict__ bta, unsigned short* __restrict__ oh,
    unsigned short* __restrict__ ol) {
  const int row = blockIdx.x;
  const int t = threadIdx.x;
  __shared__ float red[4];
  __shared__ float bc[2];
  const float4* xr = (const float4*)(x + (size_t)row * 1536);
  float4 v0 = xr[t];
  float4 v1 = make_float4(0.f, 0.f, 0.f, 0.f);
  if (t < 128) v1 = xr[256 + t];
  float s = v0.x + v0.y + v0.z + v0.w;
  if (t < 128) s += v1.x + v1.y + v1.z + v1.w;
  #pragma unroll
  for (int off = 32; off >= 1; off >>= 1) s += __shfl_xor(s, off);
  if ((t & 63) == 0) red[t >> 6] = s;
  __syncthreads();
  if (t == 0) bc[0] = (red[0] + red[1] + red[2] + red[3]) * (1.f / 1536.f);
  __syncthreads();
  const float mu = bc[0];
  float d, s2 = 0.f;
  d = v0.x - mu; s2 += d * d; d = v0.y - mu; s2 += d * d;
  d = v0.z - mu; s2 += d * d; d = v0.w - mu; s2 += d * d;
  if (t < 128) {
    d = v1.x - mu; s2 += d * d; d = v1.y - mu; s2 += d * d;
    d = v1.z - mu; s2 += d * d; d = v1.w - mu; s2 += d * d;
  }
  #pragma unroll
  for (int off = 32; off >= 1; off >>= 1) s2 += __shfl_xor(s2, off);
  if ((t & 63) == 0) red[t >> 6] = s2;
  __syncthreads();
  if (t == 0) bc[1] = (red[0] + red[1] + red[2] + red[3]) * (1.f / 1536.f);
  __syncthreads();
  const float inv = rsqrtf(bc[1] + 1e-5f);
  const float4* g4 = (const float4*)g;
  const float4* b4 = (const float4*)bta;
  float4 gg = g4[t], bb = b4[t];
  float o0 = (v0.x - mu) * inv * gg.x + bb.x;
  float o1 = (v0.y - mu) * inv * gg.y + bb.y;
  float o2 = (v0.z - mu) * inv * gg.z + bb.z;
  float o3 = (v0.w - mu) * inv * gg.w + bb.w;
  ushort4 hv, lv;
  hv.x = f2bu(o0); lv.x = f2bu(o0 - b2f(hv.x));
  hv.y = f2bu(o1); lv.y = f2bu(o1 - b2f(hv.y));
  hv.z = f2bu(o2); lv.z = f2bu(o2 - b2f(hv.z));
  hv.w = f2bu(o3); lv.w = f2bu(o3 - b2f(hv.w));
  *(ushort4*)(oh + (size_t)row * 1536 + t * 4) = hv;
  *(ushort4*)(ol + (size_t)row * 1536 + t * 4) = lv;
  if (t < 128) {
    gg = g4[256 + t]; bb = b4[256 + t];
    o0 = (v1.x - mu) * inv * gg.x + bb.x;
    o1 = (v1.y - mu) * inv * gg.y + bb.y;
    o2 = (v1.z - mu) * inv * gg.z + bb.z;
    o3 = (v1.w - mu) * inv * gg.w + bb.w;
    hv.x = f2bu(o0); lv.x = f2bu(o0 - b2f(hv.x));
    hv.y = f2bu(o1); lv.y = f2bu(o1 - b2f(hv.y));
    hv.z = f2bu(o2); lv.z = f2bu(o2 - b2f(hv.z));
    hv.w = f2bu(o3); lv.w = f2bu(o3 - b2f(hv.w));
    *(ushort4*)(oh + (size_t)row * 1536 + 1024 + t * 4) = hv;
    *(ushort4*)(ol + (size_t)row * 1536 + 1024 + t * 4) = lv;
  }
}

// ------------- weight convert + transpose: W[K][N] fp32 -> T{h,l}[roff+N][KD] -------------
__global__ __launch_bounds__(256) void convw_kernel(
    const float* __restrict__ W, unsigned short* __restrict__ Th,
    unsigned short* __restrict__ Tl, int N, int K, int KD, int roff, float scale) {
  __shared__ float tile[32][33];
  const int n0 = blockIdx.x * 32, k0 = blockIdx.y * 32;
  const int t = threadIdx.x;
  const int cr = t >> 5;
  const int cc = t & 31;
  #pragma unroll
  for (int p = 0; p < 4; ++p) {
    int r = cr + p * 8;
    tile[r][cc] = W[(size_t)(k0 + r) * N + n0 + cc];
  }
  __syncthreads();
  #pragma unroll
  for (int p = 0; p < 4; ++p) {
    int r = cr + p * 8;                    // local n
    float v = tile[cc][r] * scale;         // W[k0+cc][n0+r]
    unsigned short hh = f2bu(v);
    size_t o = (size_t)(roff + n0 + r) * KD + k0 + cc;
    Th[o] = hh;
    Tl[o] = f2bu(v - b2f(hh));
  }
}

// ------------- bf16x3 MFMA GEMM, 128x128 tile, BK=32 -------------
// EPI: 2 = bias+relu -> bf16 hi/lo planes; 3 = bias+residual -> fp32;
//      4 = QKV epilogue: Q/K bf16 hi/lo planes + V^T bf16 plane
template <int EPI>
__global__ __launch_bounds__(256, 2) void mgemm_kernel(
    const unsigned short* __restrict__ Ah, const unsigned short* __restrict__ Al,
    const unsigned short* __restrict__ Bh, const unsigned short* __restrict__ Bl,
    float* __restrict__ C, unsigned short* __restrict__ Ch, unsigned short* __restrict__ Cl,
    unsigned short* __restrict__ Kph, unsigned short* __restrict__ Kpl,
    unsigned short* __restrict__ Vt,
    const float* __restrict__ bias, const float* __restrict__ res,
    int M, int N, int K) {
  __shared__ unsigned short sm[16384];  // Ah[128][32] Al Bh Bl planes, 8KB each
  const int t = threadIdx.x;
  const int lane = t & 63;
  const int w = t >> 6;
  const int wm = w >> 1, wn = w & 1;
  const int m0 = blockIdx.y * 128, n0 = blockIdx.x * 128;

  f32x4 acc[4][4];
  #pragma unroll
  for (int i = 0; i < 4; ++i)
    #pragma unroll
    for (int j = 0; j < 4; ++j) acc[i][j] = (f32x4){0.f, 0.f, 0.f, 0.f};

  const int r0 = w * 32 + (lane >> 2);
  const int ks = lane & 3;
  const int lr = lane & 15;
  const int ko = (lane >> 4) * 8;
  char* smb = (char*)&sm[0];

  for (int k0 = 0; k0 < K; k0 += 32) {
    #pragma unroll
    for (int j = 0; j < 2; ++j) {
      int r = r0 + j * 16;
      size_t ga = (size_t)(m0 + r) * K + k0 + ks * 8;
      size_t gb = (size_t)(n0 + r) * K + k0 + ks * 8;
      int lo = (w * 2 + j) * 1024;
      gl_lds16(Ah + ga, smb + lo);
      gl_lds16(Al + ga, smb + 8192 + lo);
      gl_lds16(Bh + gb, smb + 16384 + lo);
      gl_lds16(Bl + gb, smb + 24576 + lo);
    }
    __syncthreads();
    bf16x8 ah[4], al[4], bh[4], bl[4];
    const unsigned short* pa = sm + (wm * 64 + lr) * 32 + ko;
    const unsigned short* pb2 = sm + 8192 + (wn * 64 + lr) * 32 + ko;
    #pragma unroll
    for (int i = 0; i < 4; ++i) {
      ah[i] = *(const bf16x8*)(pa + i * 512);
      al[i] = *(const bf16x8*)(pa + 4096 + i * 512);
      bh[i] = *(const bf16x8*)(pb2 + i * 512);
      bl[i] = *(const bf16x8*)(pb2 + 4096 + i * 512);
    }
    #pragma unroll
    for (int i = 0; i < 4; ++i)
      #pragma unroll
      for (int j = 0; j < 4; ++j) {
        acc[i][j] = MFMA16(ah[i], bh[j], acc[i][j]);
        acc[i][j] = MFMA16(ah[i], bl[j], acc[i][j]);
        acc[i][j] = MFMA16(al[i], bh[j], acc[i][j]);
      }
    __syncthreads();
  }

  const int lq = lane >> 4;
  #pragma unroll
  for (int i = 0; i < 4; ++i) {
    #pragma unroll
    for (int j = 0; j < 4; ++j) {
      const int c0 = n0 + wn * 64 + j * 16;   // tile col base (uniform)
      const int col = c0 + lr;
      const int rbase = m0 + wm * 64 + i * 16 + lq * 4;
      if (EPI == 3) {
        #pragma unroll
        for (int q = 0; q < 4; ++q) {
          size_t o = (size_t)(rbase + q) * N + col;
          C[o] = acc[i][j][q] + bias[col] + res[o];
        }
      } else if (EPI == 2) {
        #pragma unroll
        for (int q = 0; q < 4; ++q) {
          size_t o = (size_t)(rbase + q) * N + col;
          float v = fmaxf(acc[i][j][q] + bias[col], 0.f);
          unsigned short hh = f2bu(v);
          Ch[o] = hh;
          Cl[o] = f2bu(v - b2f(hh));
        }
      } else {  // EPI == 4: QKV split epilogue
        if (c0 < 512) {
          #pragma unroll
          for (int q = 0; q < 4; ++q) {
            float v = acc[i][j][q];
            unsigned short hh = f2bu(v);
            size_t o = (size_t)(rbase + q) * 512 + col;
            Ch[o] = hh;
            Cl[o] = f2bu(v - b2f(hh));
          }
        } else if (c0 < 1024) {
          #pragma unroll
          for (int q = 0; q < 4; ++q) {
            float v = acc[i][j][q];
            unsigned short hh = f2bu(v);
            size_t o = (size_t)(rbase + q) * 512 + (col - 512);
            Kph[o] = hh;
            Kpl[o] = f2bu(v - b2f(hh));
          }
        } else {
          int dv = col - 1024;
          int hd = dv / 192;
          int dvh = dv - hd * 192;
          int bb = rbase / 1536;
          int nloc = rbase - bb * 1536;
          ushort4 pk;
          pk.x = f2bu(acc[i][j][0]);
          pk.y = f2bu(acc[i][j][1]);
          pk.z = f2bu(acc[i][j][2]);
          pk.w = f2bu(acc[i][j][3]);
          *(ushort4*)(Vt + (((size_t)bb * 8 + hd) * 192 + dvh) * 1536 + nloc) = pk;
        }
      }
    }
  }
}

// ------------- MFMA flash attention, LDS-staged K/R/V (shared across waves) -------------
// LDS plane layout (shorts, row = 64 shorts = 128B, slot = 8 shorts, slot ^= row&7):
//   K_h @0 (64 rows), K_l @4096, R_h @8192 (128 rows), R_l @16384, V^T @24576 (192 rows)
//   Ps (P repack, stride 80 shorts) overlays R_h after barrier B.
#define STAGE_LOAD(J0, DB)                                                      \
  do {                                                                          \
    _Pragma("unroll") for (int p = 0; p < 2; ++p) {                             \
      int id = t + p * 256; int r = id >> 3, s2 = id & 7;                       \
      size_t gk = ((size_t)(b * SEQN + (J0) + r)) * 512 + h * 64 + s2 * 8;      \
      sKh[p] = *(const uint4*)(Kh + gk);                                        \
      sKl[p] = *(const uint4*)(Kl + gk);                                        \
    }                                                                           \
    _Pragma("unroll") for (int p = 0; p < 4; ++p) {                             \
      int id = t + p * 256; int r = id >> 3, s2 = id & 7;                       \
      size_t gr = ((size_t)((DB) + r)) * 512 + h * 64 + s2 * 8;                 \
      sRh[p] = *(const uint4*)(rkh + gr);                                       \
      sRl[p] = *(const uint4*)(rkl + gr);                                       \
    }                                                                           \
    _Pragma("unroll") for (int p = 0; p < 6; ++p) {                             \
      int id = t + p * 256; int r = id >> 3, s2 = id & 7;                       \
      size_t gv = (((size_t)(b * 8 + h)) * 192 + r) * SEQN + (J0) + s2 * 8;     \
      sVv[p] = *(const uint4*)(Vt + gv);                                        \
    }                                                                           \
  } while (0)

#define STAGE_WRITE()                                                           \
  do {                                                                          \
    _Pragma("unroll") for (int p = 0; p < 2; ++p) {                             \
      int id = t + p * 256; int r = id >> 3, sw = (id & 7) ^ (r & 7);           \
      *(uint4*)(&lds[r * 64 + sw * 8]) = sKh[p];                                \
      *(uint4*)(&lds[4096 + r * 64 + sw * 8]) = sKl[p];                         \
    }                                                                           \
    _Pragma("unroll") for (int p = 0; p < 4; ++p) {                             \
      int id = t + p * 256; int r = id >> 3, sw = (id & 7) ^ (r & 7);           \
      *(uint4*)(&lds[8192 + r * 64 + sw * 8]) = sRh[p];                         \
      *(uint4*)(&lds[16384 + r * 64 + sw * 8]) = sRl[p];                        \
    }                                                                           \
    _Pragma("unroll") for (int p = 0; p < 6; ++p) {                             \
      int id = t + p * 256; int r = id >> 3, sw = (id & 7) ^ (r & 7);           \
      *(uint4*)(&lds[24576 + r * 64 + sw * 8]) = sVv[p];                        \
    }                                                                           \
  } while (0)

__global__ __launch_bounds__(256, 2) void attn_kernel(
    const unsigned short* __restrict__ Qh, const unsigned short* __restrict__ Ql,
    const unsigned short* __restrict__ Kh, const unsigned short* __restrict__ Kl,
    const unsigned short* __restrict__ Vt, const unsigned short* __restrict__ rkh,
    const unsigned short* __restrict__ rkl, const float* __restrict__ PR,
    const float* __restrict__ CK, unsigned short* __restrict__ aoh,
    unsigned short* __restrict__ aol) {
  __shared__ unsigned short lds[36864];
  const int id = blockIdx.x;
  const int xcd = id & 7, s = id >> 3;           // XCD-chunked (b,h) mapping
  const int bh = xcd * 4 + s / 24;
  const int it = s % 24;
  const int b = bh >> 3, h = bh & 7;
  const int t = threadIdx.x;
  const int w = t >> 6;
  const int lane = t & 63;
  const int c15 = lane & 15, g = lane >> 4;
  const int swz = c15 & 7;
  const int qrow0 = it * 64 + w * 16;            // wave's 16 Q rows

  uint4 sKh[2], sKl[2], sRh[4], sRl[4], sVv[6];

  // persistent Q fragments (A-operand: lane holds row c15, k = g*8..+8)
  bf16x8 qh0, qh1, ql0, ql1;
  {
    size_t qo = ((size_t)(b * SEQN + qrow0 + c15)) * 512 + h * 64 + g * 8;
    qh0 = *(const bf16x8*)(Qh + qo);
    qh1 = *(const bf16x8*)(Qh + qo + 32);
    ql0 = *(const bf16x8*)(Ql + qo);
    ql1 = *(const bf16x8*)(Ql + qo + 32);
  }

  f32x4 acc[12];
  #pragma unroll
  for (int d = 0; d < 12; ++d) acc[d] = (f32x4){0.f, 0.f, 0.f, 0.f};
  float mrun[4], lrun[4];
  #pragma unroll
  for (int q = 0; q < 4; ++q) { mrun[q] = -1e30f; lrun[q] = 0.f; }

  // prologue: stage chunk 0
  {
    const int dblk0 = 1472 - it * 64;
    STAGE_LOAD(0, dblk0);
    STAGE_WRITE();
  }
  __syncthreads();  // A

  const int rrow0 = (3 - w) * 16;                // this wave's R-row base in LDS

  for (int c = 0; c < 24; ++c) {
    const int j0 = c * 64;
    const int dbase = 1520 + j0 - qrow0;         // absolute d of this wave's band start
    // ---- T[i][e] = q_i . relk[dbase+e] + PR[dbase+e], e in [0,80) ----
    f32x4 T[5];
    #pragma unroll
    for (int et = 0; et < 5; ++et) {
      int rowR = rrow0 + et * 16 + c15;
      bf16x8 rh0 = *(const bf16x8*)(&lds[8192 + rowR * 64 + (g ^ swz) * 8]);
      bf16x8 rh1 = *(const bf16x8*)(&lds[8192 + rowR * 64 + ((4 + g) ^ swz) * 8]);
      bf16x8 rl0 = *(const bf16x8*)(&lds[16384 + rowR * 64 + (g ^ swz) * 8]);
      bf16x8 rl1 = *(const bf16x8*)(&lds[16384 + rowR * 64 + ((4 + g) ^ swz) * 8]);
      f32x4 tt = (f32x4){0.f, 0.f, 0.f, 0.f};
      tt = MFMA16(qh0, rh0, tt); tt = MFMA16(qh1, rh1, tt);
      tt = MFMA16(qh0, rl0, tt); tt = MFMA16(qh1, rl1, tt);
      tt = MFMA16(ql0, rh0, tt); tt = MFMA16(ql1, rh1, tt);
      float prv = PR[(size_t)h * NDIST + dbase + et * 16 + c15];
      #pragma unroll
      for (int q = 0; q < 4; ++q) tt[q] += prv;
      T[et] = tt;
    }
    // ---- S = Q @ K^T + CK + gather(T) ----
    f32x4 S[4];
    #pragma unroll
    for (int st = 0; st < 4; ++st) {
      int rowK = st * 16 + c15;
      bf16x8 kh0 = *(const bf16x8*)(&lds[rowK * 64 + (g ^ swz) * 8]);
      bf16x8 kh1 = *(const bf16x8*)(&lds[rowK * 64 + ((4 + g) ^ swz) * 8]);
      bf16x8 kl0 = *(const bf16x8*)(&lds[4096 + rowK * 64 + (g ^ swz) * 8]);
      bf16x8 kl1 = *(const bf16x8*)(&lds[4096 + rowK * 64 + ((4 + g) ^ swz) * 8]);
      f32x4 ss = (f32x4){0.f, 0.f, 0.f, 0.f};
      ss = MFMA16(qh0, kh0, ss); ss = MFMA16(qh1, kh1, ss);
      ss = MFMA16(qh0, kl0, ss); ss = MFMA16(qh1, kl1, ss);
      ss = MFMA16(ql0, kh0, ss); ss = MFMA16(ql1, kh1, ss);
      float ckv = CK[((size_t)(b * SEQN + j0 + st * 16 + c15)) * 8 + h];
      #pragma unroll
      for (int q = 0; q < 4; ++q) {
        int eoff = c15 + 15 - 4 * g - q;          // in [0,30]
        int src = (lane & 48) | (eoff & 15);
        float v0 = __shfl(T[st][q], src);
        float v1 = __shfl(T[st + 1][q], src);
        ss[q] += ckv + ((eoff < 16) ? v0 : v1);
      }
      S[st] = ss;
    }
    // ---- online softmax (row groups of 16 lanes) ----
    float mx[4], al[4], sum[4];
    #pragma unroll
    for (int q = 0; q < 4; ++q)
      mx[q] = fmaxf(fmaxf(S[0][q], S[1][q]), fmaxf(S[2][q], S[3][q]));
    #pragma unroll
    for (int off = 8; off >= 1; off >>= 1)
      #pragma unroll
      for (int q = 0; q < 4; ++q) mx[q] = fmaxf(mx[q], __shfl_xor(mx[q], off));
    #pragma unroll
    for (int q = 0; q < 4; ++q) {
      float mn = fmaxf(mrun[q], mx[q]);
      al[q] = __expf(mrun[q] - mn);
      mrun[q] = mn;
      sum[q] = 0.f;
    }
    float pv16[4][4];
    #pragma unroll
    for (int st = 0; st < 4; ++st)
      #pragma unroll
      for (int q = 0; q < 4; ++q) {
        float p = __expf(S[st][q] - mrun[q]);
        sum[q] += p;
        pv16[st][q] = p;
      }
    #pragma unroll
    for (int off = 8; off >= 1; off >>= 1)
      #pragma unroll
      for (int q = 0; q < 4; ++q) sum[q] += __shfl_xor(sum[q], off);
    #pragma unroll
    for (int q = 0; q < 4; ++q) lrun[q] = lrun[q] * al[q] + sum[q];
    #pragma unroll
    for (int d = 0; d < 12; ++d)
      #pragma unroll
      for (int q = 0; q < 4; ++q) acc[d][q] *= al[q];

    __syncthreads();  // B: all R/K LDS reads done; Ps may overlay R_h
    #pragma unroll
    for (int st = 0; st < 4; ++st)
      #pragma unroll
      for (int q = 0; q < 4; ++q)
        lds[8192 + (w * 16 + 4 * g + q) * 80 + st * 16 + c15] = f2bu(pv16[st][q]);

    // T14: issue next chunk's global loads; latency hides under PV
    if (c < 23) {
      const int dblk0n = 1472 + j0 + 64 - it * 64;
      STAGE_LOAD(j0 + 64, dblk0n);
    }

    // ---- PV: P[16][64] @ V^T fragments ----
    #pragma unroll
    for (int jk = 0; jk < 2; ++jk) {
      bf16x8 pf = *(const bf16x8*)(&lds[8192 + (w * 16 + c15) * 80 + jk * 32 + g * 8]);
      #pragma unroll
      for (int d = 0; d < 12; ++d) {
        int rowV = d * 16 + c15;
        bf16x8 vf = *(const bf16x8*)(
            &lds[24576 + rowV * 64 + (((jk * 4 + g) ^ swz)) * 8]);
        acc[d] = MFMA16(pf, vf, acc[d]);
      }
    }
    __syncthreads();  // C: all LDS reads (Ps, V) done
    if (c < 23) STAGE_WRITE();
    __syncthreads();  // A': staged data visible
  }

  // ---- epilogue: out = acc / l -> bf16 hi/lo planes ----
  float rinv[4];
  #pragma unroll
  for (int q = 0; q < 4; ++q) rinv[q] = 1.0f / lrun[q];
  #pragma unroll
  for (int d = 0; d < 12; ++d) {
    int col = h * 192 + d * 16 + c15;
    #pragma unroll
    for (int q = 0; q < 4; ++q) {
      size_t row = (size_t)(b * SEQN + qrow0 + 4 * g + q);
      float v = acc[d][q] * rinv[q];
      unsigned short hh = f2bu(v);
      aoh[row * 1536 + col] = hh;
      aol[row * 1536 + col] = f2bu(v - b2f(hh));
    }
  }
}

extern "C" void kernel_launch(void* const* d_in, const int* in_sizes, int n_in,
                              void* d_out, int out_size, void* d_ws, size_t ws_size,
                              hipStream_t stream) {
  (void)in_sizes; (void)n_in; (void)out_size; (void)ws_size;
  const float* x   = (const float*)d_in[0];
  const float* g1  = (const float*)d_in[1];
  const float* be1 = (const float*)d_in[2];
  const float* Wq  = (const float*)d_in[3];
  const float* Wk  = (const float*)d_in[4];
  const float* Wv  = (const float*)d_in[5];
  const float* Wo  = (const float*)d_in[6];
  const float* bo  = (const float*)d_in[7];
  const float* Wrk = (const float*)d_in[8];
  const float* cb  = (const float*)d_in[9];
  const float* pb  = (const float*)d_in[10];
  const float* g2  = (const float*)d_in[11];
  const float* be2 = (const float*)d_in[12];
  const float* W1  = (const float*)d_in[13];
  const float* b1  = (const float*)d_in[14];
  const float* W2  = (const float*)d_in[15];
  const float* b2  = (const float*)d_in[16];
  float* out = (float*)d_out;

  char* B = (char*)d_ws;
  float* pos          = (float*)(B + 0);                   //  2,359,296
  unsigned short* rkh = (unsigned short*)(B + 2359296);    //  3,145,728 (3072 rows)
  unsigned short* rkl = (unsigned short*)(B + 5505024);    //  3,145,728
  float* PRb          = (float*)(B + 8650752);             //     98,304
  float* CKb          = (float*)(B + 8749056);             //    196,608
  unsigned short* xnh = (unsigned short*)(B + 8945664);    // 18,874,368
  unsigned short* xnl = (unsigned short*)(B + 27820032);   // 18,874,368
  unsigned short* Wbh = (unsigned short*)(B + 46694400);   //  9,437,184
  unsigned short* Wbl = (unsigned short*)(B + 56131584);   //  9,437,184
  unsigned short* Qph = (unsigned short*)(B + 65568768);   //  6,291,456
  unsigned short* Qpl = (unsigned short*)(B + 71860224);   //  6,291,456
  unsigned short* Kph = (unsigned short*)(B + 78151680);   //  6,291,456
  unsigned short* Kpl = (unsigned short*)(B + 84443136);   //  6,291,456
  unsigned short* Vtp = (unsigned short*)(B + 90734592);   // 18,874,368
  float* x2           = (float*)(B + 65568768);            // 37,748,736 (after attn)
  unsigned short* aoh = (unsigned short*)(B + 109608960);  // 18,874,368
  unsigned short* aol = (unsigned short*)(B + 128483328);  // 18,874,368
  unsigned short* h1h = (unsigned short*)(B + 103317504);  // 37,748,736 (after Wo)
  unsigned short* h1l = (unsigned short*)(B + 141066240);  // 37,748,736 -> ends 178,814,976

  pos_embed_kernel<<<NDIST, 64, 0, stream>>>(pos);
  relk_kernel<<<NDIST, 512, 0, stream>>>(pos, Wrk, pb, rkh, rkl, PRb);
  ln_kernel<<<MROWS, 256, 0, stream>>>(x, g1, be1, xnh, xnl);
  // fused QKV weights (transposed, hi/lo); fold 0.125 scale into Wq
  convw_kernel<<<dim3(16, 48), 256, 0, stream>>>(Wq, Wbh, Wbl, 512, 1536, 1536, 0, 0.125f);
  convw_kernel<<<dim3(16, 48), 256, 0, stream>>>(Wk, Wbh, Wbl, 512, 1536, 1536, 512, 1.0f);
  convw_kernel<<<dim3(48, 48), 256, 0, stream>>>(Wv, Wbh, Wbl, 1536, 1536, 1536, 1024, 1.0f);
  mgemm_kernel<4><<<dim3(20, 48), 256, 0, stream>>>(
      xnh, xnl, Wbh, Wbl, nullptr, Qph, Qpl, Kph, Kpl, Vtp, nullptr, nullptr,
      MROWS, 2560, 1536);
  ck_kernel<<<MROWS * 2, 256, 0, stream>>>(Kph, Kpl, cb, CKb);
  attn_kernel<<<768, 256, 0, stream>>>(Qph, Qpl, Kph, Kpl, Vtp, rkh, rkl, PRb, CKb, aoh, aol);
  convw_kernel<<<dim3(48, 48), 256, 0, stream>>>(Wo, Wbh, Wbl, 1536, 1536, 1536, 0, 1.0f);
  mgemm_kernel<3><<<dim3(12, 48), 256, 0, stream>>>(
      aoh, aol, Wbh, Wbl, x2, nullptr, nullptr, nullptr, nullptr, nullptr, bo, x,
      MROWS, 1536, 1536);
  ln_kernel<<<MROWS, 256, 0, stream>>>(x2, g2, be2, xnh, xnl);
  convw_kernel<<<dim3(96, 48), 256, 0, stream>>>(W1, Wbh, Wbl, 3072, 1536, 1536, 0, 1.0f);
  mgemm_kernel<2><<<dim3(24, 48), 256, 0, stream>>>(
      xnh, xnl, Wbh, Wbl, nullptr, h1h, h1l, nullptr, nullptr, nullptr, b1, nullptr,
      MROWS, 3072, 1536);
  convw_kernel<<<dim3(48, 96), 256, 0, stream>>>(W2, Wbh, Wbl, 1536, 3072, 3072, 0, 1.0f);
  mgemm_kernel<3><<<dim3(12, 48), 256, 0, stream>>>(
      h1h, h1l, Wbh, Wbl, out, nullptr, nullptr, nullptr, nullptr, nullptr, b2, x2,
      MROWS, 1536, 3072);
}

// Round 7
// 1039.109 us; speedup vs baseline: 3.6766x; 1.1710x over previous
//
#include <hip/hip_runtime.h>
#include <hip/hip_bf16.h>
#include <math.h>

#define SEQN 1536
#define NH 8
#define MROWS 6144      // BATCH*SEQ
#define NDIST 3071      // 2*SEQ-1

typedef __attribute__((ext_vector_type(8))) short bf16x8;
typedef __attribute__((ext_vector_type(4))) float f32x4;

#define MFMA16(a, b, c) __builtin_amdgcn_mfma_f32_16x16x32_bf16(a, b, c, 0, 0, 0)

__device__ __forceinline__ unsigned short f2bu(float x) {
  __hip_bfloat16 h = __float2bfloat16(x);
  return *reinterpret_cast<unsigned short*>(&h);
}
__device__ __forceinline__ float b2f(unsigned short u) {
  __hip_bfloat16 h;
  *reinterpret_cast<unsigned short*>(&h) = u;
  return __bfloat162float(h);
}

__device__ __forceinline__ void gl_lds16(const void* g, void* l) {
  __builtin_amdgcn_global_load_lds(
      (const __attribute__((address_space(1))) void*)g,
      (__attribute__((address_space(3))) void*)l, 16, 0, 0);
}

// ---------------- positional embedding table: pos[3071][192] ----------------
__global__ __launch_bounds__(64) void pos_embed_kernel(float* __restrict__ pos) {
  int row = blockIdx.x;
  int j = threadIdx.x;
  if (j >= 32) return;
  float dist = (float)(row - (SEQN - 1));
  float adist = fabsf(dist);
  float sgn = (dist > 0.f) ? 1.f : (dist < 0.f ? -1.f : 0.f);

  const float max_range = 10.58496250072116f;  // log2(1536)
  float hl = exp2f(3.0f + ((max_range - 3.0f) / 31.0f) * (float)j);
  float e_exp = expf(-0.6931471805599453f / hl * adist);

  float cw = exp2f((float)(j + 1)) - 1.0f;
  float e_cm = (cw > adist) ? 1.0f : 0.0f;

  float mean = 48.0f * (float)(j + 1);
  float tt = mean / 24.0f;
  float conc = tt * tt;
  float rate = mean / 576.0f;
  float log_unnorm = (conc - 1.0f) * logf(fmaxf(adist, 1e-20f)) - rate * adist;
  float log_norm = lgammaf(conc) - conc * logf(rate);
  float prob = expf(log_unnorm - log_norm) + 1e-8f;
  float mx = prob;
  #pragma unroll
  for (int off = 16; off >= 1; off >>= 1)
    mx = fmaxf(mx, __shfl_xor(mx, off, 32));
  float e_g = prob / mx;

  float* o = pos + (size_t)row * 192;
  o[j] = e_exp;        o[32 + j] = e_cm;        o[64 + j] = e_g;
  o[96 + j] = sgn * e_exp; o[128 + j] = sgn * e_cm; o[160 + j] = sgn * e_g;
}

// ------------- rel_k = pos @ Wrk -> bf16 hi/lo planes [3072 rows][512]; PR[h][d] -------------
__global__ __launch_bounds__(512) void relk_kernel(
    const float* __restrict__ pos, const float* __restrict__ Wrk,
    const float* __restrict__ pb, unsigned short* __restrict__ rkh,
    unsigned short* __restrict__ rkl, float* __restrict__ PR) {
  const int d = blockIdx.x;
  const int t = threadIdx.x;
  __shared__ float prow[192];
  if (t < 192) prow[t] = pos[(size_t)d * 192 + t];
  __syncthreads();
  float acc = 0.f;
  #pragma unroll 8
  for (int kk = 0; kk < 192; ++kk)
    acc = fmaf(prow[kk], Wrk[(size_t)kk * 512 + t], acc);
  unsigned short hh = f2bu(acc);
  rkh[(size_t)d * 512 + t] = hh;
  rkl[(size_t)d * 512 + t] = f2bu(acc - b2f(hh));
  float pv = pb[t] * acc;
  #pragma unroll
  for (int off = 32; off >= 1; off >>= 1) pv += __shfl_xor(pv, off);
  if ((t & 63) == 0) PR[(size_t)(t >> 6) * NDIST + d] = pv;
}

// ------------- CK[row][h] = cb_h . k[row,h,:] from bf16 hi/lo K planes -------------
__global__ __launch_bounds__(256) void ck_kernel(
    const unsigned short* __restrict__ Kh, const unsigned short* __restrict__ Kl,
    const float* __restrict__ cb, float* __restrict__ CK) {
  const int gid = blockIdx.x * 4 + (threadIdx.x >> 6);
  const int lane = threadIdx.x & 63;
  const int row = gid >> 3;
  const int h = gid & 7;
  size_t idx = (size_t)row * 512 + h * 64 + lane;
  float kv = b2f(Kh[idx]) + b2f(Kl[idx]);
  float pv = cb[h * 64 + lane] * kv;
  #pragma unroll
  for (int off = 32; off >= 1; off >>= 1) pv += __shfl_xor(pv, off);
  if (lane == 0) CK[(size_t)row * 8 + h] = pv;
}

// ------------- layernorm: fp32 in -> bf16 hi/lo planes out -------------
__global__ __launch_bounds__(256) void ln_kernel(
    const float* __restrict__ x, const float* __restrict__ g,
    const float* __restrict__ bta, unsigned short* __restrict__ oh,
    unsigned short* __restrict__ ol) {
  const int row = blockIdx.x;
  const int t = threadIdx.x;
  __shared__ float red[4];
  __shared__ float bc[2];
  const float4* xr = (const float4*)(x + (size_t)row * 1536);
  float4 v0 = xr[t];
  float4 v1 = make_float4(0.f, 0.f, 0.f, 0.f);
  if (t < 128) v1 = xr[256 + t];
  float s = v0.x + v0.y + v0.z + v0.w;
  if (t < 128) s += v1.x + v1.y + v1.z + v1.w;
  #pragma unroll
  for (int off = 32; off >= 1; off >>= 1) s += __shfl_xor(s, off);
  if ((t & 63) == 0) red[t >> 6] = s;
  __syncthreads();
  if (t == 0) bc[0] = (red[0] + red[1] + red[2] + red[3]) * (1.f / 1536.f);
  __syncthreads();
  const float mu = bc[0];
  float d, s2 = 0.f;
  d = v0.x - mu; s2 += d * d; d = v0.y - mu; s2 += d * d;
  d = v0.z - mu; s2 += d * d; d = v0.w - mu; s2 += d * d;
  if (t < 128) {
    d = v1.x - mu; s2 += d * d; d = v1.y - mu; s2 += d * d;
    d = v1.z - mu; s2 += d * d; d = v1.w - mu; s2 += d * d;
  }
  #pragma unroll
  for (int off = 32; off >= 1; off >>= 1) s2 += __shfl_xor(s2, off);
  if ((t & 63) == 0) red[t >> 6] = s2;
  __syncthreads();
  if (t == 0) bc[1] = (red[0] + red[1] + red[2] + red[3]) * (1.f / 1536.f);
  __syncthreads();
  const float inv = rsqrtf(bc[1] + 1e-5f);
  const float4* g4 = (const float4*)g;
  const float4* b4 = (const float4*)bta;
  float4 gg = g4[t], bb = b4[t];
  float o0 = (v0.x - mu) * inv * gg.x + bb.x;
  float o1 = (v0.y - mu) * inv * gg.y + bb.y;
  float o2 = (v0.z - mu) * inv * gg.z + bb.z;
  float o3 = (v0.w - mu) * inv * gg.w + bb.w;
  ushort4 hv, lv;
  hv.x = f2bu(o0); lv.x = f2bu(o0 - b2f(hv.x));
  hv.y = f2bu(o1); lv.y = f2bu(o1 - b2f(hv.y));
  hv.z = f2bu(o2); lv.z = f2bu(o2 - b2f(hv.z));
  hv.w = f2bu(o3); lv.w = f2bu(o3 - b2f(hv.w));
  *(ushort4*)(oh + (size_t)row * 1536 + t * 4) = hv;
  *(ushort4*)(ol + (size_t)row * 1536 + t * 4) = lv;
  if (t < 128) {
    gg = g4[256 + t]; bb = b4[256 + t];
    o0 = (v1.x - mu) * inv * gg.x + bb.x;
    o1 = (v1.y - mu) * inv * gg.y + bb.y;
    o2 = (v1.z - mu) * inv * gg.z + bb.z;
    o3 = (v1.w - mu) * inv * gg.w + bb.w;
    hv.x = f2bu(o0); lv.x = f2bu(o0 - b2f(hv.x));
    hv.y = f2bu(o1); lv.y = f2bu(o1 - b2f(hv.y));
    hv.z = f2bu(o2); lv.z = f2bu(o2 - b2f(hv.z));
    hv.w = f2bu(o3); lv.w = f2bu(o3 - b2f(hv.w));
    *(ushort4*)(oh + (size_t)row * 1536 + 1024 + t * 4) = hv;
    *(ushort4*)(ol + (size_t)row * 1536 + 1024 + t * 4) = lv;
  }
}

// ------------- weight convert + transpose: W[K][N] fp32 -> T{h,l}[roff+N][KD] -------------
__global__ __launch_bounds__(256) void convw_kernel(
    const float* __restrict__ W, unsigned short* __restrict__ Th,
    unsigned short* __restrict__ Tl, int N, int K, int KD, int roff, float scale) {
  __shared__ float tile[32][33];
  const int n0 = blockIdx.x * 32, k0 = blockIdx.y * 32;
  const int t = threadIdx.x;
  const int cr = t >> 5;
  const int cc = t & 31;
  #pragma unroll
  for (int p = 0; p < 4; ++p) {
    int r = cr + p * 8;
    tile[r][cc] = W[(size_t)(k0 + r) * N + n0 + cc];
  }
  __syncthreads();
  #pragma unroll
  for (int p = 0; p < 4; ++p) {
    int r = cr + p * 8;                    // local n
    float v = tile[cc][r] * scale;         // W[k0+cc][n0+r]
    unsigned short hh = f2bu(v);
    size_t o = (size_t)(roff + n0 + r) * KD + k0 + cc;
    Th[o] = hh;
    Tl[o] = f2bu(v - b2f(hh));
  }
}

// ------------- bf16x3 MFMA GEMM, 128x128 tile, BK=32 -------------
// EPI: 2 = bias+relu -> bf16 hi/lo planes; 3 = bias+residual -> fp32;
//      4 = QKV epilogue: Q/K bf16 hi/lo planes + V^T bf16 plane
template <int EPI>
__global__ __launch_bounds__(256, 2) void mgemm_kernel(
    const unsigned short* __restrict__ Ah, const unsigned short* __restrict__ Al,
    const unsigned short* __restrict__ Bh, const unsigned short* __restrict__ Bl,
    float* __restrict__ C, unsigned short* __restrict__ Ch, unsigned short* __restrict__ Cl,
    unsigned short* __restrict__ Kph, unsigned short* __restrict__ Kpl,
    unsigned short* __restrict__ Vt,
    const float* __restrict__ bias, const float* __restrict__ res,
    int M, int N, int K) {
  __shared__ unsigned short sm[16384];  // Ah[128][32] Al Bh Bl planes, 8KB each
  const int t = threadIdx.x;
  const int lane = t & 63;
  const int w = t >> 6;
  const int wm = w >> 1, wn = w & 1;
  const int m0 = blockIdx.y * 128, n0 = blockIdx.x * 128;

  f32x4 acc[4][4];
  #pragma unroll
  for (int i = 0; i < 4; ++i)
    #pragma unroll
    for (int j = 0; j < 4; ++j) acc[i][j] = (f32x4){0.f, 0.f, 0.f, 0.f};

  const int r0 = w * 32 + (lane >> 2);
  const int ks = lane & 3;
  const int lr = lane & 15;
  const int ko = (lane >> 4) * 8;
  char* smb = (char*)&sm[0];

  for (int k0 = 0; k0 < K; k0 += 32) {
    #pragma unroll
    for (int j = 0; j < 2; ++j) {
      int r = r0 + j * 16;
      size_t ga = (size_t)(m0 + r) * K + k0 + ks * 8;
      size_t gb = (size_t)(n0 + r) * K + k0 + ks * 8;
      int lo = (w * 2 + j) * 1024;
      gl_lds16(Ah + ga, smb + lo);
      gl_lds16(Al + ga, smb + 8192 + lo);
      gl_lds16(Bh + gb, smb + 16384 + lo);
      gl_lds16(Bl + gb, smb + 24576 + lo);
    }
    __syncthreads();
    bf16x8 ah[4], al[4], bh[4], bl[4];
    const unsigned short* pa = sm + (wm * 64 + lr) * 32 + ko;
    const unsigned short* pb2 = sm + 8192 + (wn * 64 + lr) * 32 + ko;
    #pragma unroll
    for (int i = 0; i < 4; ++i) {
      ah[i] = *(const bf16x8*)(pa + i * 512);
      al[i] = *(const bf16x8*)(pa + 4096 + i * 512);
      bh[i] = *(const bf16x8*)(pb2 + i * 512);
      bl[i] = *(const bf16x8*)(pb2 + 4096 + i * 512);
    }
    #pragma unroll
    for (int i = 0; i < 4; ++i)
      #pragma unroll
      for (int j = 0; j < 4; ++j) {
        acc[i][j] = MFMA16(ah[i], bh[j], acc[i][j]);
        acc[i][j] = MFMA16(ah[i], bl[j], acc[i][j]);
        acc[i][j] = MFMA16(al[i], bh[j], acc[i][j]);
      }
    __syncthreads();
  }

  const int lq = lane >> 4;
  #pragma unroll
  for (int i = 0; i < 4; ++i) {
    #pragma unroll
    for (int j = 0; j < 4; ++j) {
      const int c0 = n0 + wn * 64 + j * 16;   // tile col base (uniform)
      const int col = c0 + lr;
      const int rbase = m0 + wm * 64 + i * 16 + lq * 4;
      if (EPI == 3) {
        #pragma unroll
        for (int q = 0; q < 4; ++q) {
          size_t o = (size_t)(rbase + q) * N + col;
          C[o] = acc[i][j][q] + bias[col] + res[o];
        }
      } else if (EPI == 2) {
        #pragma unroll
        for (int q = 0; q < 4; ++q) {
          size_t o = (size_t)(rbase + q) * N + col;
          float v = fmaxf(acc[i][j][q] + bias[col], 0.f);
          unsigned short hh = f2bu(v);
          Ch[o] = hh;
          Cl[o] = f2bu(v - b2f(hh));
        }
      } else {  // EPI == 4: QKV split epilogue
        if (c0 < 512) {
          #pragma unroll
          for (int q = 0; q < 4; ++q) {
            float v = acc[i][j][q];
            unsigned short hh = f2bu(v);
            size_t o = (size_t)(rbase + q) * 512 + col;
            Ch[o] = hh;
            Cl[o] = f2bu(v - b2f(hh));
          }
        } else if (c0 < 1024) {
          #pragma unroll
          for (int q = 0; q < 4; ++q) {
            float v = acc[i][j][q];
            unsigned short hh = f2bu(v);
            size_t o = (size_t)(rbase + q) * 512 + (col - 512);
            Kph[o] = hh;
            Kpl[o] = f2bu(v - b2f(hh));
          }
        } else {
          int dv = col - 1024;
          int hd = dv / 192;
          int dvh = dv - hd * 192;
          int bb = rbase / 1536;
          int nloc = rbase - bb * 1536;
          ushort4 pk;
          pk.x = f2bu(acc[i][j][0]);
          pk.y = f2bu(acc[i][j][1]);
          pk.z = f2bu(acc[i][j][2]);
          pk.w = f2bu(acc[i][j][3]);
          *(ushort4*)(Vt + (((size_t)bb * 8 + hd) * 192 + dvh) * 1536 + nloc) = pk;
        }
      }
    }
  }
}

// ------------- MFMA flash attention, async LDS staging (global_load_lds) -------------
// 512 threads / 8 waves; block = 128 Q rows x full KV sweep in 64-j chunks.
// LDS layout (shorts): K dbuf {hi,lo} @ cur*8192 (+4096); V^T dbuf @ 16384+cur*12288;
//   R band hi @ 40960, lo @ 53248 (192 rows); Ps @ 65536 (128 rows x stride 80).
// XOR slot-swizzle (slot ^= row&7) realized by pre-swizzling the global source
// address (LDS dest of global_load_lds stays linear: base + lane*16B).
__global__ __launch_bounds__(512, 2) void attn_kernel(
    const unsigned short* __restrict__ Qh, const unsigned short* __restrict__ Ql,
    const unsigned short* __restrict__ Kh, const unsigned short* __restrict__ Kl,
    const unsigned short* __restrict__ Vt, const unsigned short* __restrict__ rkh,
    const unsigned short* __restrict__ rkl, const float* __restrict__ PR,
    const float* __restrict__ CK, unsigned short* __restrict__ aoh,
    unsigned short* __restrict__ aol) {
  __shared__ unsigned short lds[75776];   // 151,552 B
  const int id = blockIdx.x;
  const int xcd = id & 7, s = id >> 3;    // XCD-chunked (b,h) mapping
  const int bh = xcd * 4 + s / 12;
  const int it = s % 12;
  const int b = bh >> 3, h = bh & 7;
  const int t = threadIdx.x;
  const int w = t >> 6;
  const int lane = t & 63;
  const int c15 = lane & 15, g = lane >> 4;
  const int swz = c15 & 7;
  const int qrow0 = it * 128 + w * 16;    // wave's 16 Q rows
  const int rrow0 = 112 - w * 16;         // wave's R-row base within block band

  // staging lane geometry: lane covers (local row lr, slot sl); source slot pre-swizzled
  const int lr = lane >> 3, sl = lane & 7;
  const int ss = sl ^ lr;                 // row&7 == lr for all staged rows

  // persistent Q fragments (A-operand: lane holds row c15, k = g*8..+8)
  bf16x8 qh0, qh1, ql0, ql1;
  {
    size_t qo = ((size_t)(b * SEQN + qrow0 + c15)) * 512 + h * 64 + g * 8;
    qh0 = *(const bf16x8*)(Qh + qo);
    qh1 = *(const bf16x8*)(Qh + qo + 32);
    ql0 = *(const bf16x8*)(Ql + qo);
    ql1 = *(const bf16x8*)(Ql + qo + 32);
  }

  f32x4 acc[12];
  #pragma unroll
  for (int d = 0; d < 12; ++d) acc[d] = (f32x4){0.f, 0.f, 0.f, 0.f};
  float mrun[4], lrun[4];
  #pragma unroll
  for (int q = 0; q < 4; ++q) { mrun[q] = -1e30f; lrun[q] = 0.f; }

  // ---- staging helpers (wave-uniform LDS base; per-lane global addr) ----
  #define STAGE_KV(J0, KB, VB)                                                  \
    do {                                                                        \
      int r = w * 8 + lr;                                                       \
      size_t gk = ((size_t)(b * SEQN + (J0) + r)) * 512 + h * 64 + ss * 8;      \
      gl_lds16(Kh + gk, &lds[(KB) + w * 512]);                                  \
      gl_lds16(Kl + gk, &lds[(KB) + 4096 + w * 512]);                           \
      _Pragma("unroll") for (int p = 0; p < 3; ++p) {                           \
        int rv = w * 24 + p * 8 + lr;                                           \
        size_t gv = (((size_t)(b * 8 + h)) * 192 + rv) * SEQN + (J0) + ss * 8;  \
        gl_lds16(Vt + gv, &lds[(VB) + (w * 24 + p * 8) * 64]);                  \
      }                                                                         \
    } while (0)

  #define STAGE_R(DB)                                                           \
    do {                                                                        \
      _Pragma("unroll") for (int p = 0; p < 3; ++p) {                           \
        int rr = w * 24 + p * 8 + lr;                                           \
        size_t gr = ((size_t)((DB) + rr)) * 512 + h * 64 + ss * 8;              \
        gl_lds16(rkh + gr, &lds[40960 + (w * 24 + p * 8) * 64]);                \
        gl_lds16(rkl + gr, &lds[53248 + (w * 24 + p * 8) * 64]);                \
      }                                                                         \
    } while (0)

  // prologue: stage chunk 0
  STAGE_KV(0, 0, 16384);
  STAGE_R(1408 - it * 128);

  for (int c = 0; c < 24; ++c) {
    const int j0 = c * 64;
    const int cur = c & 1;
    const int KB = cur * 8192;
    const int VB = 16384 + cur * 12288;
    __syncthreads();  // A: staged data for chunk c visible

    // prefetch next K/V into alternate buffers (drained at barrier B)
    if (c < 23) {
      const int KBn = (cur ^ 1) * 8192;
      const int VBn = 16384 + (cur ^ 1) * 12288;
      STAGE_KV(j0 + 64, KBn, VBn);
    }

    const int dbase = 1520 + j0 - qrow0;   // absolute d at wave band start
    // ---- T[i][e] = q_i . relk[dbase+e] + PR[dbase+e], e in [0,80) ----
    f32x4 T[5];
    #pragma unroll
    for (int et = 0; et < 5; ++et) {
      int rowR = rrow0 + et * 16 + c15;
      bf16x8 rh0 = *(const bf16x8*)(&lds[40960 + rowR * 64 + (g ^ swz) * 8]);
      bf16x8 rh1 = *(const bf16x8*)(&lds[40960 + rowR * 64 + ((4 + g) ^ swz) * 8]);
      bf16x8 rl0 = *(const bf16x8*)(&lds[53248 + rowR * 64 + (g ^ swz) * 8]);
      bf16x8 rl1 = *(const bf16x8*)(&lds[53248 + rowR * 64 + ((4 + g) ^ swz) * 8]);
      f32x4 tt = (f32x4){0.f, 0.f, 0.f, 0.f};
      tt = MFMA16(qh0, rh0, tt); tt = MFMA16(qh1, rh1, tt);
      tt = MFMA16(qh0, rl0, tt); tt = MFMA16(qh1, rl1, tt);
      tt = MFMA16(ql0, rh0, tt); tt = MFMA16(ql1, rh1, tt);
      float prv = PR[(size_t)h * NDIST + dbase + et * 16 + c15];
      #pragma unroll
      for (int q = 0; q < 4; ++q) tt[q] += prv;
      T[et] = tt;
    }
    // ---- S = Q @ K^T + CK + gather(T) ----
    f32x4 S[4];
    #pragma unroll
    for (int st = 0; st < 4; ++st) {
      int rowK = st * 16 + c15;
      bf16x8 kh0 = *(const bf16x8*)(&lds[KB + rowK * 64 + (g ^ swz) * 8]);
      bf16x8 kh1 = *(const bf16x8*)(&lds[KB + rowK * 64 + ((4 + g) ^ swz) * 8]);
      bf16x8 kl0 = *(const bf16x8*)(&lds[KB + 4096 + rowK * 64 + (g ^ swz) * 8]);
      bf16x8 kl1 = *(const bf16x8*)(&lds[KB + 4096 + rowK * 64 + ((4 + g) ^ swz) * 8]);
      f32x4 ssv = (f32x4){0.f, 0.f, 0.f, 0.f};
      ssv = MFMA16(qh0, kh0, ssv); ssv = MFMA16(qh1, kh1, ssv);
      ssv = MFMA16(qh0, kl0, ssv); ssv = MFMA16(qh1, kl1, ssv);
      ssv = MFMA16(ql0, kh0, ssv); ssv = MFMA16(ql1, kh1, ssv);
      float ckv = CK[((size_t)(b * SEQN + j0 + st * 16 + c15)) * 8 + h];
      #pragma unroll
      for (int q = 0; q < 4; ++q) {
        int eoff = c15 + 15 - 4 * g - q;     // in [0,30]
        int src = (lane & 48) | (eoff & 15);
        float v0 = __shfl(T[st][q], src);
        float v1 = __shfl(T[st + 1][q], src);
        ssv[q] += ckv + ((eoff < 16) ? v0 : v1);
      }
      S[st] = ssv;
    }
    // ---- online softmax (16-lane row groups) ----
    float mx[4], al[4], sum[4];
    #pragma unroll
    for (int q = 0; q < 4; ++q)
      mx[q] = fmaxf(fmaxf(S[0][q], S[1][q]), fmaxf(S[2][q], S[3][q]));
    #pragma unroll
    for (int off = 8; off >= 1; off >>= 1)
      #pragma unroll
      for (int q = 0; q < 4; ++q) mx[q] = fmaxf(mx[q], __shfl_xor(mx[q], off));
    #pragma unroll
    for (int q = 0; q < 4; ++q) {
      float mn = fmaxf(mrun[q], mx[q]);
      al[q] = __expf(mrun[q] - mn);
      mrun[q] = mn;
      sum[q] = 0.f;
    }
    float pv16[4][4];
    #pragma unroll
    for (int st = 0; st < 4; ++st)
      #pragma unroll
      for (int q = 0; q < 4; ++q) {
        float p = __expf(S[st][q] - mrun[q]);
        sum[q] += p;
        pv16[st][q] = p;
      }
    #pragma unroll
    for (int off = 8; off >= 1; off >>= 1)
      #pragma unroll
      for (int q = 0; q < 4; ++q) sum[q] += __shfl_xor(sum[q], off);
    #pragma unroll
    for (int q = 0; q < 4; ++q) lrun[q] = lrun[q] * al[q] + sum[q];
    #pragma unroll
    for (int d = 0; d < 12; ++d)
      #pragma unroll
      for (int q = 0; q < 4; ++q) acc[d][q] *= al[q];

    __syncthreads();  // B: R/K reads done (R safe to overwrite)

    if (c < 23) STAGE_R(1408 + j0 + 64 - it * 128);

    // Ps repack (per-wave private region; same-wave write->read)
    #pragma unroll
    for (int st = 0; st < 4; ++st)
      #pragma unroll
      for (int q = 0; q < 4; ++q)
        lds[65536 + (w * 16 + 4 * g + q) * 80 + st * 16 + c15] = f2bu(pv16[st][q]);

    // ---- PV: P[16][64] @ V^T fragments ----
    #pragma unroll
    for (int jk = 0; jk < 2; ++jk) {
      bf16x8 pf = *(const bf16x8*)(&lds[65536 + (w * 16 + c15) * 80 + jk * 32 + g * 8]);
      #pragma unroll
      for (int d = 0; d < 12; ++d) {
        int rowV = d * 16 + c15;
        bf16x8 vf = *(const bf16x8*)(&lds[VB + rowV * 64 + ((jk * 4 + g) ^ swz) * 8]);
        acc[d] = MFMA16(pf, vf, acc[d]);
      }
    }
  }

  // ---- epilogue: out = acc / l -> bf16 hi/lo planes ----
  float rinv[4];
  #pragma unroll
  for (int q = 0; q < 4; ++q) rinv[q] = 1.0f / lrun[q];
  #pragma unroll
  for (int d = 0; d < 12; ++d) {
    int col = h * 192 + d * 16 + c15;
    #pragma unroll
    for (int q = 0; q < 4; ++q) {
      size_t row = (size_t)(b * SEQN + qrow0 + 4 * g + q);
      float v = acc[d][q] * rinv[q];
      unsigned short hh = f2bu(v);
      aoh[row * 1536 + col] = hh;
      aol[row * 1536 + col] = f2bu(v - b2f(hh));
    }
  }
  #undef STAGE_KV
  #undef STAGE_R
}

extern "C" void kernel_launch(void* const* d_in, const int* in_sizes, int n_in,
                              void* d_out, int out_size, void* d_ws, size_t ws_size,
                              hipStream_t stream) {
  (void)in_sizes; (void)n_in; (void)out_size; (void)ws_size;
  const float* x   = (const float*)d_in[0];
  const float* g1  = (const float*)d_in[1];
  const float* be1 = (const float*)d_in[2];
  const float* Wq  = (const float*)d_in[3];
  const float* Wk  = (const float*)d_in[4];
  const float* Wv  = (const float*)d_in[5];
  const float* Wo  = (const float*)d_in[6];
  const float* bo  = (const float*)d_in[7];
  const float* Wrk = (const float*)d_in[8];
  const float* cb  = (const float*)d_in[9];
  const float* pb  = (const float*)d_in[10];
  const float* g2  = (const float*)d_in[11];
  const float* be2 = (const float*)d_in[12];
  const float* W1  = (const float*)d_in[13];
  const float* b1  = (const float*)d_in[14];
  const float* W2  = (const float*)d_in[15];
  const float* b2  = (const float*)d_in[16];
  float* out = (float*)d_out;

  char* B = (char*)d_ws;
  float* pos          = (float*)(B + 0);                   //  2,359,296
  unsigned short* rkh = (unsigned short*)(B + 2359296);    //  3,145,728 (3072 rows)
  unsigned short* rkl = (unsigned short*)(B + 5505024);    //  3,145,728
  float* PRb          = (float*)(B + 8650752);             //     98,304
  float* CKb          = (float*)(B + 8749056);             //    196,608
  unsigned short* xnh = (unsigned short*)(B + 8945664);    // 18,874,368
  unsigned short* xnl = (unsigned short*)(B + 27820032);   // 18,874,368
  unsigned short* Wbh = (unsigned short*)(B + 46694400);   //  9,437,184
  unsigned short* Wbl = (unsigned short*)(B + 56131584);   //  9,437,184
  unsigned short* Qph = (unsigned short*)(B + 65568768);   //  6,291,456
  unsigned short* Qpl = (unsigned short*)(B + 71860224);   //  6,291,456
  unsigned short* Kph = (unsigned short*)(B + 78151680);   //  6,291,456
  unsigned short* Kpl = (unsigned short*)(B + 84443136);   //  6,291,456
  unsigned short* Vtp = (unsigned short*)(B + 90734592);   // 18,874,368
  float* x2           = (float*)(B + 65568768);            // 37,748,736 (after attn)
  unsigned short* aoh = (unsigned short*)(B + 109608960);  // 18,874,368
  unsigned short* aol = (unsigned short*)(B + 128483328);  // 18,874,368
  unsigned short* h1h = (unsigned short*)(B + 103317504);  // 37,748,736 (after Wo)
  unsigned short* h1l = (unsigned short*)(B + 141066240);  // 37,748,736 -> ends 178,814,976

  pos_embed_kernel<<<NDIST, 64, 0, stream>>>(pos);
  relk_kernel<<<NDIST, 512, 0, stream>>>(pos, Wrk, pb, rkh, rkl, PRb);
  ln_kernel<<<MROWS, 256, 0, stream>>>(x, g1, be1, xnh, xnl);
  // fused QKV weights (transposed, hi/lo); fold 0.125 scale into Wq
  convw_kernel<<<dim3(16, 48), 256, 0, stream>>>(Wq, Wbh, Wbl, 512, 1536, 1536, 0, 0.125f);
  convw_kernel<<<dim3(16, 48), 256, 0, stream>>>(Wk, Wbh, Wbl, 512, 1536, 1536, 512, 1.0f);
  convw_kernel<<<dim3(48, 48), 256, 0, stream>>>(Wv, Wbh, Wbl, 1536, 1536, 1536, 1024, 1.0f);
  mgemm_kernel<4><<<dim3(20, 48), 256, 0, stream>>>(
      xnh, xnl, Wbh, Wbl, nullptr, Qph, Qpl, Kph, Kpl, Vtp, nullptr, nullptr,
      MROWS, 2560, 1536);
  ck_kernel<<<MROWS * 2, 256, 0, stream>>>(Kph, Kpl, cb, CKb);
  attn_kernel<<<384, 512, 0, stream>>>(Qph, Qpl, Kph, Kpl, Vtp, rkh, rkl, PRb, CKb, aoh, aol);
  convw_kernel<<<dim3(48, 48), 256, 0, stream>>>(Wo, Wbh, Wbl, 1536, 1536, 1536, 0, 1.0f);
  mgemm_kernel<3><<<dim3(12, 48), 256, 0, stream>>>(
      aoh, aol, Wbh, Wbl, x2, nullptr, nullptr, nullptr, nullptr, nullptr, bo, x,
      MROWS, 1536, 1536);
  ln_kernel<<<MROWS, 256, 0, stream>>>(x2, g2, be2, xnh, xnl);
  convw_kernel<<<dim3(96, 48), 256, 0, stream>>>(W1, Wbh, Wbl, 3072, 1536, 1536, 0, 1.0f);
  mgemm_kernel<2><<<dim3(24, 48), 256, 0, stream>>>(
      xnh, xnl, Wbh, Wbl, nullptr, h1h, h1l, nullptr, nullptr, nullptr, b1, nullptr,
      MROWS, 3072, 1536);
  convw_kernel<<<dim3(48, 96), 256, 0, stream>>>(W2, Wbh, Wbl, 1536, 3072, 3072, 0, 1.0f);
  mgemm_kernel<3><<<dim3(12, 48), 256, 0, stream>>>(
      h1h, h1l, Wbh, Wbl, out, nullptr, nullptr, nullptr, nullptr, nullptr, b2, x2,
      MROWS, 1536, 3072);
}

// Round 8
// 944.867 us; speedup vs baseline: 4.0433x; 1.0997x over previous
//
#include <hip/hip_runtime.h>
#include <hip/hip_bf16.h>
#include <math.h>

#define SEQN 1536
#define NH 8
#define MROWS 6144      // BATCH*SEQ
#define NDIST 3071      // 2*SEQ-1

typedef __attribute__((ext_vector_type(8))) short bf16x8;
typedef __attribute__((ext_vector_type(4))) float f32x4;

#define MFMA16(a, b, c) __builtin_amdgcn_mfma_f32_16x16x32_bf16(a, b, c, 0, 0, 0)

__device__ __forceinline__ unsigned short f2bu(float x) {
  __hip_bfloat16 h = __float2bfloat16(x);
  return *reinterpret_cast<unsigned short*>(&h);
}
__device__ __forceinline__ float b2f(unsigned short u) {
  __hip_bfloat16 h;
  *reinterpret_cast<unsigned short*>(&h) = u;
  return __bfloat162float(h);
}

__device__ __forceinline__ void gl_lds16(const void* g, void* l) {
  __builtin_amdgcn_global_load_lds(
      (const __attribute__((address_space(1))) void*)g,
      (__attribute__((address_space(3))) void*)l, 16, 0, 0);
}

// ---------------- positional embedding table: pos[3071][192] ----------------
__global__ __launch_bounds__(64) void pos_embed_kernel(float* __restrict__ pos) {
  int row = blockIdx.x;
  int j = threadIdx.x;
  if (j >= 32) return;
  float dist = (float)(row - (SEQN - 1));
  float adist = fabsf(dist);
  float sgn = (dist > 0.f) ? 1.f : (dist < 0.f ? -1.f : 0.f);

  const float max_range = 10.58496250072116f;  // log2(1536)
  float hl = exp2f(3.0f + ((max_range - 3.0f) / 31.0f) * (float)j);
  float e_exp = expf(-0.6931471805599453f / hl * adist);

  float cw = exp2f((float)(j + 1)) - 1.0f;
  float e_cm = (cw > adist) ? 1.0f : 0.0f;

  float mean = 48.0f * (float)(j + 1);
  float tt = mean / 24.0f;
  float conc = tt * tt;
  float rate = mean / 576.0f;
  float log_unnorm = (conc - 1.0f) * logf(fmaxf(adist, 1e-20f)) - rate * adist;
  float log_norm = lgammaf(conc) - conc * logf(rate);
  float prob = expf(log_unnorm - log_norm) + 1e-8f;
  float mx = prob;
  #pragma unroll
  for (int off = 16; off >= 1; off >>= 1)
    mx = fmaxf(mx, __shfl_xor(mx, off, 32));
  float e_g = prob / mx;

  float* o = pos + (size_t)row * 192;
  o[j] = e_exp;        o[32 + j] = e_cm;        o[64 + j] = e_g;
  o[96 + j] = sgn * e_exp; o[128 + j] = sgn * e_cm; o[160 + j] = sgn * e_g;
}

// ------------- rel_k = pos @ Wrk -> bf16 hi/lo planes [3072 rows][512]; PR[h][d] -------------
__global__ __launch_bounds__(512) void relk_kernel(
    const float* __restrict__ pos, const float* __restrict__ Wrk,
    const float* __restrict__ pb, unsigned short* __restrict__ rkh,
    unsigned short* __restrict__ rkl, float* __restrict__ PR) {
  const int d = blockIdx.x;
  const int t = threadIdx.x;
  __shared__ float prow[192];
  if (t < 192) prow[t] = pos[(size_t)d * 192 + t];
  __syncthreads();
  float acc = 0.f;
  #pragma unroll 8
  for (int kk = 0; kk < 192; ++kk)
    acc = fmaf(prow[kk], Wrk[(size_t)kk * 512 + t], acc);
  unsigned short hh = f2bu(acc);
  rkh[(size_t)d * 512 + t] = hh;
  rkl[(size_t)d * 512 + t] = f2bu(acc - b2f(hh));
  float pv = pb[t] * acc;
  #pragma unroll
  for (int off = 32; off >= 1; off >>= 1) pv += __shfl_xor(pv, off);
  if ((t & 63) == 0) PR[(size_t)(t >> 6) * NDIST + d] = pv;
}

// ------------- CK[row][h] = cb_h . k[row,h,:] from bf16 hi/lo K planes -------------
__global__ __launch_bounds__(256) void ck_kernel(
    const unsigned short* __restrict__ Kh, const unsigned short* __restrict__ Kl,
    const float* __restrict__ cb, float* __restrict__ CK) {
  const int gid = blockIdx.x * 4 + (threadIdx.x >> 6);
  const int lane = threadIdx.x & 63;
  const int row = gid >> 3;
  const int h = gid & 7;
  size_t idx = (size_t)row * 512 + h * 64 + lane;
  float kv = b2f(Kh[idx]) + b2f(Kl[idx]);
  float pv = cb[h * 64 + lane] * kv;
  #pragma unroll
  for (int off = 32; off >= 1; off >>= 1) pv += __shfl_xor(pv, off);
  if (lane == 0) CK[(size_t)row * 8 + h] = pv;
}

// ------------- layernorm: fp32 in -> bf16 hi/lo planes out -------------
__global__ __launch_bounds__(256) void ln_kernel(
    const float* __restrict__ x, const float* __restrict__ g,
    const float* __restrict__ bta, unsigned short* __restrict__ oh,
    unsigned short* __restrict__ ol) {
  const int row = blockIdx.x;
  const int t = threadIdx.x;
  __shared__ float red[4];
  __shared__ float bc[2];
  const float4* xr = (const float4*)(x + (size_t)row * 1536);
  float4 v0 = xr[t];
  float4 v1 = make_float4(0.f, 0.f, 0.f, 0.f);
  if (t < 128) v1 = xr[256 + t];
  float s = v0.x + v0.y + v0.z + v0.w;
  if (t < 128) s += v1.x + v1.y + v1.z + v1.w;
  #pragma unroll
  for (int off = 32; off >= 1; off >>= 1) s += __shfl_xor(s, off);
  if ((t & 63) == 0) red[t >> 6] = s;
  __syncthreads();
  if (t == 0) bc[0] = (red[0] + red[1] + red[2] + red[3]) * (1.f / 1536.f);
  __syncthreads();
  const float mu = bc[0];
  float d, s2 = 0.f;
  d = v0.x - mu; s2 += d * d; d = v0.y - mu; s2 += d * d;
  d = v0.z - mu; s2 += d * d; d = v0.w - mu; s2 += d * d;
  if (t < 128) {
    d = v1.x - mu; s2 += d * d; d = v1.y - mu; s2 += d * d;
    d = v1.z - mu; s2 += d * d; d = v1.w - mu; s2 += d * d;
  }
  #pragma unroll
  for (int off = 32; off >= 1; off >>= 1) s2 += __shfl_xor(s2, off);
  if ((t & 63) == 0) red[t >> 6] = s2;
  __syncthreads();
  if (t == 0) bc[1] = (red[0] + red[1] + red[2] + red[3]) * (1.f / 1536.f);
  __syncthreads();
  const float inv = rsqrtf(bc[1] + 1e-5f);
  const float4* g4 = (const float4*)g;
  const float4* b4 = (const float4*)bta;
  float4 gg = g4[t], bb = b4[t];
  float o0 = (v0.x - mu) * inv * gg.x + bb.x;
  float o1 = (v0.y - mu) * inv * gg.y + bb.y;
  float o2 = (v0.z - mu) * inv * gg.z + bb.z;
  float o3 = (v0.w - mu) * inv * gg.w + bb.w;
  ushort4 hv, lv;
  hv.x = f2bu(o0); lv.x = f2bu(o0 - b2f(hv.x));
  hv.y = f2bu(o1); lv.y = f2bu(o1 - b2f(hv.y));
  hv.z = f2bu(o2); lv.z = f2bu(o2 - b2f(hv.z));
  hv.w = f2bu(o3); lv.w = f2bu(o3 - b2f(hv.w));
  *(ushort4*)(oh + (size_t)row * 1536 + t * 4) = hv;
  *(ushort4*)(ol + (size_t)row * 1536 + t * 4) = lv;
  if (t < 128) {
    gg = g4[256 + t]; bb = b4[256 + t];
    o0 = (v1.x - mu) * inv * gg.x + bb.x;
    o1 = (v1.y - mu) * inv * gg.y + bb.y;
    o2 = (v1.z - mu) * inv * gg.z + bb.z;
    o3 = (v1.w - mu) * inv * gg.w + bb.w;
    hv.x = f2bu(o0); lv.x = f2bu(o0 - b2f(hv.x));
    hv.y = f2bu(o1); lv.y = f2bu(o1 - b2f(hv.y));
    hv.z = f2bu(o2); lv.z = f2bu(o2 - b2f(hv.z));
    hv.w = f2bu(o3); lv.w = f2bu(o3 - b2f(hv.w));
    *(ushort4*)(oh + (size_t)row * 1536 + 1024 + t * 4) = hv;
    *(ushort4*)(ol + (size_t)row * 1536 + 1024 + t * 4) = lv;
  }
}

// ------------- weight convert + transpose: W[K][N] fp32 -> T{h,l}[roff+N][KD] -------------
__global__ __launch_bounds__(256) void convw_kernel(
    const float* __restrict__ W, unsigned short* __restrict__ Th,
    unsigned short* __restrict__ Tl, int N, int K, int KD, int roff, float scale) {
  __shared__ float tile[32][33];
  const int n0 = blockIdx.x * 32, k0 = blockIdx.y * 32;
  const int t = threadIdx.x;
  const int cr = t >> 5;
  const int cc = t & 31;
  #pragma unroll
  for (int p = 0; p < 4; ++p) {
    int r = cr + p * 8;
    tile[r][cc] = W[(size_t)(k0 + r) * N + n0 + cc];
  }
  __syncthreads();
  #pragma unroll
  for (int p = 0; p < 4; ++p) {
    int r = cr + p * 8;                    // local n
    float v = tile[cc][r] * scale;         // W[k0+cc][n0+r]
    unsigned short hh = f2bu(v);
    size_t o = (size_t)(roff + n0 + r) * KD + k0 + cc;
    Th[o] = hh;
    Tl[o] = f2bu(v - b2f(hh));
  }
}

// ------------- bf16x3 MFMA GEMM, 128x128 tile, BK=32 -------------
// EPI: 2 = bias+relu -> bf16 hi/lo planes; 3 = bias+residual -> fp32;
//      4 = QKV epilogue: Q/K bf16 hi/lo planes + V^T bf16 plane
template <int EPI>
__global__ __launch_bounds__(256, 2) void mgemm_kernel(
    const unsigned short* __restrict__ Ah, const unsigned short* __restrict__ Al,
    const unsigned short* __restrict__ Bh, const unsigned short* __restrict__ Bl,
    float* __restrict__ C, unsigned short* __restrict__ Ch, unsigned short* __restrict__ Cl,
    unsigned short* __restrict__ Kph, unsigned short* __restrict__ Kpl,
    unsigned short* __restrict__ Vt,
    const float* __restrict__ bias, const float* __restrict__ res,
    int M, int N, int K) {
  __shared__ unsigned short sm[16384];  // Ah[128][32] Al Bh Bl planes, 8KB each
  const int t = threadIdx.x;
  const int lane = t & 63;
  const int w = t >> 6;
  const int wm = w >> 1, wn = w & 1;
  const int m0 = blockIdx.y * 128, n0 = blockIdx.x * 128;

  f32x4 acc[4][4];
  #pragma unroll
  for (int i = 0; i < 4; ++i)
    #pragma unroll
    for (int j = 0; j < 4; ++j) acc[i][j] = (f32x4){0.f, 0.f, 0.f, 0.f};

  const int r0 = w * 32 + (lane >> 2);
  const int ks = lane & 3;
  const int lr = lane & 15;
  const int ko = (lane >> 4) * 8;
  char* smb = (char*)&sm[0];

  for (int k0 = 0; k0 < K; k0 += 32) {
    #pragma unroll
    for (int j = 0; j < 2; ++j) {
      int r = r0 + j * 16;
      size_t ga = (size_t)(m0 + r) * K + k0 + ks * 8;
      size_t gb = (size_t)(n0 + r) * K + k0 + ks * 8;
      int lo = (w * 2 + j) * 1024;
      gl_lds16(Ah + ga, smb + lo);
      gl_lds16(Al + ga, smb + 8192 + lo);
      gl_lds16(Bh + gb, smb + 16384 + lo);
      gl_lds16(Bl + gb, smb + 24576 + lo);
    }
    __syncthreads();
    bf16x8 ah[4], al[4], bh[4], bl[4];
    const unsigned short* pa = sm + (wm * 64 + lr) * 32 + ko;
    const unsigned short* pb2 = sm + 8192 + (wn * 64 + lr) * 32 + ko;
    #pragma unroll
    for (int i = 0; i < 4; ++i) {
      ah[i] = *(const bf16x8*)(pa + i * 512);
      al[i] = *(const bf16x8*)(pa + 4096 + i * 512);
      bh[i] = *(const bf16x8*)(pb2 + i * 512);
      bl[i] = *(const bf16x8*)(pb2 + 4096 + i * 512);
    }
    #pragma unroll
    for (int i = 0; i < 4; ++i)
      #pragma unroll
      for (int j = 0; j < 4; ++j) {
        acc[i][j] = MFMA16(ah[i], bh[j], acc[i][j]);
        acc[i][j] = MFMA16(ah[i], bl[j], acc[i][j]);
        acc[i][j] = MFMA16(al[i], bh[j], acc[i][j]);
      }
    __syncthreads();
  }

  const int lq = lane >> 4;
  #pragma unroll
  for (int i = 0; i < 4; ++i) {
    #pragma unroll
    for (int j = 0; j < 4; ++j) {
      const int c0 = n0 + wn * 64 + j * 16;   // tile col base (uniform)
      const int col = c0 + lr;
      const int rbase = m0 + wm * 64 + i * 16 + lq * 4;
      if (EPI == 3) {
        #pragma unroll
        for (int q = 0; q < 4; ++q) {
          size_t o = (size_t)(rbase + q) * N + col;
          C[o] = acc[i][j][q] + bias[col] + res[o];
        }
      } else if (EPI == 2) {
        #pragma unroll
        for (int q = 0; q < 4; ++q) {
          size_t o = (size_t)(rbase + q) * N + col;
          float v = fmaxf(acc[i][j][q] + bias[col], 0.f);
          unsigned short hh = f2bu(v);
          Ch[o] = hh;
          Cl[o] = f2bu(v - b2f(hh));
        }
      } else {  // EPI == 4: QKV split epilogue
        if (c0 < 512) {
          #pragma unroll
          for (int q = 0; q < 4; ++q) {
            float v = acc[i][j][q];
            unsigned short hh = f2bu(v);
            size_t o = (size_t)(rbase + q) * 512 + col;
            Ch[o] = hh;
            Cl[o] = f2bu(v - b2f(hh));
          }
        } else if (c0 < 1024) {
          #pragma unroll
          for (int q = 0; q < 4; ++q) {
            float v = acc[i][j][q];
            unsigned short hh = f2bu(v);
            size_t o = (size_t)(rbase + q) * 512 + (col - 512);
            Kph[o] = hh;
            Kpl[o] = f2bu(v - b2f(hh));
          }
        } else {
          int dv = col - 1024;
          int hd = dv / 192;
          int dvh = dv - hd * 192;
          int bb = rbase / 1536;
          int nloc = rbase - bb * 1536;
          ushort4 pk;
          pk.x = f2bu(acc[i][j][0]);
          pk.y = f2bu(acc[i][j][1]);
          pk.z = f2bu(acc[i][j][2]);
          pk.w = f2bu(acc[i][j][3]);
          *(ushort4*)(Vt + (((size_t)bb * 8 + hd) * 192 + dvh) * 1536 + nloc) = pk;
        }
      }
    }
  }
}

// ------------- MFMA flash attention v3: bf16 logits, chunk 32, 3 blocks/CU -------------
// 256 threads / 4 waves; block = 64 Q rows; 48 chunks of 32 j.
// LDS (shorts): K dbuf [2][32][64] @0; V^T dbuf [2][192][32] @4096;
//   R [96][64] @16384; Ps [64][34] @22528.  Total 24704 shorts = 49.4 KB.
// K/R: 8-slot XOR swizzle (slot ^= row&7); V: 4-slot swizzle (slot ^= (row>>1)&3);
// both realized by pre-swizzled global source (LDS dest of global_load_lds linear).
__global__ __launch_bounds__(256, 3) void attn_kernel(
    const unsigned short* __restrict__ Qh, const unsigned short* __restrict__ Kh,
    const unsigned short* __restrict__ Vt, const unsigned short* __restrict__ rkh,
    const float* __restrict__ PR, const float* __restrict__ CK,
    unsigned short* __restrict__ aoh, unsigned short* __restrict__ aol) {
  __shared__ unsigned short lds[24704];
  const int id = blockIdx.x;
  const int xcd = id & 7, s = id >> 3;    // XCD-chunked (b,h) mapping
  const int bh = xcd * 4 + s / 24;
  const int it = s % 24;
  const int b = bh >> 3, h = bh & 7;
  const int t = threadIdx.x;
  const int w = t >> 6;
  const int lane = t & 63;
  const int c15 = lane & 15, g = lane >> 4;
  const int swz = c15 & 7;                // K/R read swizzle (row&7 == c15&7)
  const int vsz = (c15 >> 1) & 3;         // V read swizzle ((row>>1)&3)
  const int qrow0 = it * 64 + w * 16;     // wave's 16 Q rows
  const int rrow0 = 48 - w * 16;          // wave's R-row base in LDS band

  // staging lane geometry
  const int lr = lane >> 3, sl = lane & 7;
  const int ss = sl ^ lr;                           // K/R source slot
  const int ss2 = (lane & 3) ^ ((lane >> 3) & 3);   // V source slot

  // persistent Q fragment (A-operand: lane holds row c15, k = g*8..+8, 32+g*8..+8)
  bf16x8 qh0, qh1;
  {
    size_t qo = ((size_t)(b * SEQN + qrow0 + c15)) * 512 + h * 64 + g * 8;
    qh0 = *(const bf16x8*)(Qh + qo);
    qh1 = *(const bf16x8*)(Qh + qo + 32);
  }
  const float* PRrow = PR + (size_t)h * NDIST;
  const float* CKb2 = CK + (size_t)b * SEQN * 8 + h;

  f32x4 acc[12];
  #pragma unroll
  for (int d = 0; d < 12; ++d) acc[d] = (f32x4){0.f, 0.f, 0.f, 0.f};
  float mrun[4], lrun[4];
  #pragma unroll
  for (int q = 0; q < 4; ++q) { mrun[q] = -1e30f; lrun[q] = 0.f; }

  #define STAGE_KV(J0, KB, VB)                                                   \
    do {                                                                         \
      size_t gk = ((size_t)(b * SEQN + (J0) + w * 8 + lr)) * 512 + h * 64 + ss * 8; \
      gl_lds16(Kh + gk, &lds[(KB) + w * 512]);                                   \
      _Pragma("unroll") for (int p = 0; p < 3; ++p) {                            \
        int rv = w * 48 + p * 16 + (lane >> 2);                                  \
        size_t gv = (((size_t)(b * 8 + h)) * 192 + rv) * SEQN + (J0) + ss2 * 8;  \
        gl_lds16(Vt + gv, &lds[(VB) + (w * 48 + p * 16) * 32]);                  \
      }                                                                          \
    } while (0)

  #define STAGE_R(DB)                                                            \
    do {                                                                         \
      _Pragma("unroll") for (int p = 0; p < 3; ++p) {                            \
        int rr = w * 24 + p * 8 + lr;                                            \
        size_t gr = ((size_t)((DB) + rr)) * 512 + h * 64 + ss * 8;               \
        gl_lds16(rkh + gr, &lds[16384 + (w * 24 + p * 8) * 64]);                 \
      }                                                                          \
    } while (0)

  // prologue: stage chunk 0
  STAGE_KV(0, 0, 4096);
  STAGE_R(1472 - it * 64);

  for (int c = 0; c < 48; ++c) {
    const int j0 = c * 32;
    const int cur = c & 1;
    const int KB = cur * 2048;
    const int VB = 4096 + cur * 6144;
    __syncthreads();  // A: staged data for chunk c visible

    // prefetch next chunk's K/V into alternate buffers (drains at barrier B)
    if (c < 47) STAGE_KV(j0 + 32, (cur ^ 1) * 2048, 4096 + (cur ^ 1) * 6144);

    const int dbase = 1520 + j0 - qrow0;
    // ---- T[e] = q . relk[dbase+e] + PR[dbase+e], e in [0,48) ----
    f32x4 T[3];
    #pragma unroll
    for (int et = 0; et < 3; ++et) {
      int rowR = rrow0 + et * 16 + c15;
      bf16x8 rh0 = *(const bf16x8*)(&lds[16384 + rowR * 64 + (g ^ swz) * 8]);
      bf16x8 rh1 = *(const bf16x8*)(&lds[16384 + rowR * 64 + ((4 + g) ^ swz) * 8]);
      f32x4 tt = (f32x4){0.f, 0.f, 0.f, 0.f};
      tt = MFMA16(qh0, rh0, tt);
      tt = MFMA16(qh1, rh1, tt);
      float prv = PRrow[dbase + et * 16 + c15];
      #pragma unroll
      for (int q = 0; q < 4; ++q) tt[q] += prv;
      T[et] = tt;
    }
    // ---- S = Q @ K^T + CK + gather(T) ----
    f32x4 S[2];
    #pragma unroll
    for (int st = 0; st < 2; ++st) {
      int rowK = st * 16 + c15;
      bf16x8 kh0 = *(const bf16x8*)(&lds[KB + rowK * 64 + (g ^ swz) * 8]);
      bf16x8 kh1 = *(const bf16x8*)(&lds[KB + rowK * 64 + ((4 + g) ^ swz) * 8]);
      f32x4 ssv = (f32x4){0.f, 0.f, 0.f, 0.f};
      ssv = MFMA16(qh0, kh0, ssv);
      ssv = MFMA16(qh1, kh1, ssv);
      float ckv = CKb2[(size_t)(j0 + st * 16 + c15) * 8];
      #pragma unroll
      for (int q = 0; q < 4; ++q) {
        int eoff = c15 + 15 - 4 * g - q;     // in [0,30]
        int src = (lane & 48) | (eoff & 15);
        float v0 = __shfl(T[st][q], src);
        float v1 = __shfl(T[st + 1][q], src);
        ssv[q] += ckv + ((eoff < 16) ? v0 : v1);
      }
      S[st] = ssv;
    }
    // ---- online softmax (16-lane row groups) with defer-max (THR=8) ----
    float mx[4];
    #pragma unroll
    for (int q = 0; q < 4; ++q) mx[q] = fmaxf(S[0][q], S[1][q]);
    #pragma unroll
    for (int off = 8; off >= 1; off >>= 1)
      #pragma unroll
      for (int q = 0; q < 4; ++q) mx[q] = fmaxf(mx[q], __shfl_xor(mx[q], off));
    int need = 0;
    #pragma unroll
    for (int q = 0; q < 4; ++q) need |= (mx[q] > mrun[q] + 8.0f) ? 1 : 0;
    if (__any(need)) {
      #pragma unroll
      for (int q = 0; q < 4; ++q) {
        float mn = fmaxf(mrun[q], mx[q]);
        float al = __expf(mrun[q] - mn);
        mrun[q] = mn;
        lrun[q] *= al;
        #pragma unroll
        for (int d = 0; d < 12; ++d) acc[d][q] *= al;
      }
    }
    float pv16[2][4], sum[4];
    #pragma unroll
    for (int q = 0; q < 4; ++q) sum[q] = 0.f;
    #pragma unroll
    for (int st = 0; st < 2; ++st)
      #pragma unroll
      for (int q = 0; q < 4; ++q) {
        float p = __expf(S[st][q] - mrun[q]);
        sum[q] += p;
        pv16[st][q] = p;
      }
    #pragma unroll
    for (int off = 8; off >= 1; off >>= 1)
      #pragma unroll
      for (int q = 0; q < 4; ++q) sum[q] += __shfl_xor(sum[q], off);
    #pragma unroll
    for (int q = 0; q < 4; ++q) lrun[q] += sum[q];

    // Ps repack (wave-private rows; same-wave write->read)
    #pragma unroll
    for (int st = 0; st < 2; ++st)
      #pragma unroll
      for (int q = 0; q < 4; ++q)
        lds[22528 + (w * 16 + 4 * g + q) * 34 + st * 16 + c15] = f2bu(pv16[st][q]);

    __syncthreads();  // B: R/K reads done; KV prefetch drained

    if (c < 47) STAGE_R(1472 + j0 + 32 - it * 64);

    // ---- PV: P[16][32] @ V^T fragments ----
    bf16x8 pf = *(const bf16x8*)(&lds[22528 + (w * 16 + c15) * 34 + g * 8]);
    #pragma unroll
    for (int d = 0; d < 12; ++d) {
      int rowV = d * 16 + c15;
      bf16x8 vf = *(const bf16x8*)(&lds[VB + rowV * 32 + (g ^ vsz) * 8]);
      acc[d] = MFMA16(pf, vf, acc[d]);
    }
  }

  // ---- epilogue: out = acc / l -> bf16 hi/lo planes ----
  float rinv[4];
  #pragma unroll
  for (int q = 0; q < 4; ++q) rinv[q] = 1.0f / lrun[q];
  #pragma unroll
  for (int d = 0; d < 12; ++d) {
    int col = h * 192 + d * 16 + c15;
    #pragma unroll
    for (int q = 0; q < 4; ++q) {
      size_t row = (size_t)(b * SEQN + qrow0 + 4 * g + q);
      float v = acc[d][q] * rinv[q];
      unsigned short hh = f2bu(v);
      aoh[row * 1536 + col] = hh;
      aol[row * 1536 + col] = f2bu(v - b2f(hh));
    }
  }
  #undef STAGE_KV
  #undef STAGE_R
}

extern "C" void kernel_launch(void* const* d_in, const int* in_sizes, int n_in,
                              void* d_out, int out_size, void* d_ws, size_t ws_size,
                              hipStream_t stream) {
  (void)in_sizes; (void)n_in; (void)out_size; (void)ws_size;
  const float* x   = (const float*)d_in[0];
  const float* g1  = (const float*)d_in[1];
  const float* be1 = (const float*)d_in[2];
  const float* Wq  = (const float*)d_in[3];
  const float* Wk  = (const float*)d_in[4];
  const float* Wv  = (const float*)d_in[5];
  const float* Wo  = (const float*)d_in[6];
  const float* bo  = (const float*)d_in[7];
  const float* Wrk = (const float*)d_in[8];
  const float* cb  = (const float*)d_in[9];
  const float* pb  = (const float*)d_in[10];
  const float* g2  = (const float*)d_in[11];
  const float* be2 = (const float*)d_in[12];
  const float* W1  = (const float*)d_in[13];
  const float* b1  = (const float*)d_in[14];
  const float* W2  = (const float*)d_in[15];
  const float* b2  = (const float*)d_in[16];
  float* out = (float*)d_out;

  char* B = (char*)d_ws;
  float* pos          = (float*)(B + 0);                   //  2,359,296
  unsigned short* rkh = (unsigned short*)(B + 2359296);    //  3,145,728 (3072 rows)
  unsigned short* rkl = (unsigned short*)(B + 5505024);    //  3,145,728
  float* PRb          = (float*)(B + 8650752);             //     98,304
  float* CKb          = (float*)(B + 8749056);             //    196,608
  unsigned short* xnh = (unsigned short*)(B + 8945664);    // 18,874,368
  unsigned short* xnl = (unsigned short*)(B + 27820032);   // 18,874,368
  unsigned short* Wbh = (unsigned short*)(B + 46694400);   //  9,437,184
  unsigned short* Wbl = (unsigned short*)(B + 56131584);   //  9,437,184
  unsigned short* Qph = (unsigned short*)(B + 65568768);   //  6,291,456
  unsigned short* Qpl = (unsigned short*)(B + 71860224);   //  6,291,456
  unsigned short* Kph = (unsigned short*)(B + 78151680);   //  6,291,456
  unsigned short* Kpl = (unsigned short*)(B + 84443136);   //  6,291,456
  unsigned short* Vtp = (unsigned short*)(B + 90734592);   // 18,874,368
  float* x2           = (float*)(B + 65568768);            // 37,748,736 (after attn)
  unsigned short* aoh = (unsigned short*)(B + 109608960);  // 18,874,368
  unsigned short* aol = (unsigned short*)(B + 128483328);  // 18,874,368
  unsigned short* h1h = (unsigned short*)(B + 103317504);  // 37,748,736 (after Wo)
  unsigned short* h1l = (unsigned short*)(B + 141066240);  // 37,748,736 -> ends 178,814,976

  pos_embed_kernel<<<NDIST, 64, 0, stream>>>(pos);
  relk_kernel<<<NDIST, 512, 0, stream>>>(pos, Wrk, pb, rkh, rkl, PRb);
  ln_kernel<<<MROWS, 256, 0, stream>>>(x, g1, be1, xnh, xnl);
  // fused QKV weights (transposed, hi/lo); fold 0.125 scale into Wq
  convw_kernel<<<dim3(16, 48), 256, 0, stream>>>(Wq, Wbh, Wbl, 512, 1536, 1536, 0, 0.125f);
  convw_kernel<<<dim3(16, 48), 256, 0, stream>>>(Wk, Wbh, Wbl, 512, 1536, 1536, 512, 1.0f);
  convw_kernel<<<dim3(48, 48), 256, 0, stream>>>(Wv, Wbh, Wbl, 1536, 1536, 1536, 1024, 1.0f);
  mgemm_kernel<4><<<dim3(20, 48), 256, 0, stream>>>(
      xnh, xnl, Wbh, Wbl, nullptr, Qph, Qpl, Kph, Kpl, Vtp, nullptr, nullptr,
      MROWS, 2560, 1536);
  ck_kernel<<<MROWS * 2, 256, 0, stream>>>(Kph, Kpl, cb, CKb);
  attn_kernel<<<768, 256, 0, stream>>>(Qph, Kph, Vtp, rkh, PRb, CKb, aoh, aol);
  convw_kernel<<<dim3(48, 48), 256, 0, stream>>>(Wo, Wbh, Wbl, 1536, 1536, 1536, 0, 1.0f);
  mgemm_kernel<3><<<dim3(12, 48), 256, 0, stream>>>(
      aoh, aol, Wbh, Wbl, x2, nullptr, nullptr, nullptr, nullptr, nullptr, bo, x,
      MROWS, 1536, 1536);
  ln_kernel<<<MROWS, 256, 0, stream>>>(x2, g2, be2, xnh, xnl);
  convw_kernel<<<dim3(96, 48), 256, 0, stream>>>(W1, Wbh, Wbl, 3072, 1536, 1536, 0, 1.0f);
  mgemm_kernel<2><<<dim3(24, 48), 256, 0, stream>>>(
      xnh, xnl, Wbh, Wbl, nullptr, h1h, h1l, nullptr, nullptr, nullptr, b1, nullptr,
      MROWS, 3072, 1536);
  convw_kernel<<<dim3(48, 96), 256, 0, stream>>>(W2, Wbh, Wbl, 1536, 3072, 3072, 0, 1.0f);
  mgemm_kernel<3><<<dim3(12, 48), 256, 0, stream>>>(
      h1h, h1l, Wbh, Wbl, out, nullptr, nullptr, nullptr, nullptr, nullptr, b2, x2,
      MROWS, 1536, 3072);
}

// Round 9
// 565.222 us; speedup vs baseline: 6.7591x; 1.6717x over previous
//
#include <hip/hip_runtime.h>
#include <hip/hip_bf16.h>
#include <math.h>

#define SEQN 1536
#define NH 8
#define MROWS 6144      // BATCH*SEQ
#define NDIST 3071      // 2*SEQ-1

typedef __attribute__((ext_vector_type(8))) _Float16 f16x8;
typedef __attribute__((ext_vector_type(4))) _Float16 f16x4;
typedef __attribute__((ext_vector_type(4))) float f32x4;

#define MFMAH(a, b, c) __builtin_amdgcn_mfma_f32_16x16x32_f16(a, b, c, 0, 0, 0)

__device__ __forceinline__ void gl_lds16(const void* g, void* l) {
  __builtin_amdgcn_global_load_lds(
      (const __attribute__((address_space(1))) void*)g,
      (__attribute__((address_space(3))) void*)l, 16, 0, 0);
}

// ---------------- positional embedding table: pos[3071][192] ----------------
__global__ __launch_bounds__(64) void pos_embed_kernel(float* __restrict__ pos) {
  int row = blockIdx.x;
  int j = threadIdx.x;
  if (j >= 32) return;
  float dist = (float)(row - (SEQN - 1));
  float adist = fabsf(dist);
  float sgn = (dist > 0.f) ? 1.f : (dist < 0.f ? -1.f : 0.f);

  const float max_range = 10.58496250072116f;  // log2(1536)
  float hl = exp2f(3.0f + ((max_range - 3.0f) / 31.0f) * (float)j);
  float e_exp = expf(-0.6931471805599453f / hl * adist);

  float cw = exp2f((float)(j + 1)) - 1.0f;
  float e_cm = (cw > adist) ? 1.0f : 0.0f;

  float mean = 48.0f * (float)(j + 1);
  float tt = mean / 24.0f;
  float conc = tt * tt;
  float rate = mean / 576.0f;
  float log_unnorm = (conc - 1.0f) * logf(fmaxf(adist, 1e-20f)) - rate * adist;
  float log_norm = lgammaf(conc) - conc * logf(rate);
  float prob = expf(log_unnorm - log_norm) + 1e-8f;
  float mx = prob;
  #pragma unroll
  for (int off = 16; off >= 1; off >>= 1)
    mx = fmaxf(mx, __shfl_xor(mx, off, 32));
  float e_g = prob / mx;

  float* o = pos + (size_t)row * 192;
  o[j] = e_exp;        o[32 + j] = e_cm;        o[64 + j] = e_g;
  o[96 + j] = sgn * e_exp; o[128 + j] = sgn * e_cm; o[160 + j] = sgn * e_g;
}

// ------------- rel_k = pos @ Wrk -> f16 [3072 rows][512]; PR[h][d] -------------
__global__ __launch_bounds__(512) void relk_kernel(
    const float* __restrict__ pos, const float* __restrict__ Wrk,
    const float* __restrict__ pb, _Float16* __restrict__ rk, float* __restrict__ PR) {
  const int d = blockIdx.x;
  const int t = threadIdx.x;
  __shared__ float prow[192];
  if (t < 192) prow[t] = pos[(size_t)d * 192 + t];
  __syncthreads();
  float acc = 0.f;
  #pragma unroll 8
  for (int kk = 0; kk < 192; ++kk)
    acc = fmaf(prow[kk], Wrk[(size_t)kk * 512 + t], acc);
  rk[(size_t)d * 512 + t] = (_Float16)acc;
  float pv = pb[t] * acc;
  #pragma unroll
  for (int off = 32; off >= 1; off >>= 1) pv += __shfl_xor(pv, off);
  if ((t & 63) == 0) PR[(size_t)(t >> 6) * NDIST + d] = pv;
}

// ------------- CK[row][h] = cb_h . k[row,h,:] from f16 K plane -------------
__global__ __launch_bounds__(256) void ck_kernel(
    const _Float16* __restrict__ Kp, const float* __restrict__ cb,
    float* __restrict__ CK) {
  const int gid = blockIdx.x * 4 + (threadIdx.x >> 6);
  const int lane = threadIdx.x & 63;
  const int row = gid >> 3;
  const int h = gid & 7;
  float kv = (float)Kp[(size_t)row * 512 + h * 64 + lane];
  float pv = cb[h * 64 + lane] * kv;
  #pragma unroll
  for (int off = 32; off >= 1; off >>= 1) pv += __shfl_xor(pv, off);
  if (lane == 0) CK[(size_t)row * 8 + h] = pv;
}

// ------------- layernorm: fp32 in -> f16 plane out -------------
__global__ __launch_bounds__(256) void ln_kernel(
    const float* __restrict__ x, const float* __restrict__ g,
    const float* __restrict__ bta, _Float16* __restrict__ oh) {
  const int row = blockIdx.x;
  const int t = threadIdx.x;
  __shared__ float red[4];
  __shared__ float bc[2];
  const float4* xr = (const float4*)(x + (size_t)row * 1536);
  float4 v0 = xr[t];
  float4 v1 = make_float4(0.f, 0.f, 0.f, 0.f);
  if (t < 128) v1 = xr[256 + t];
  float s = v0.x + v0.y + v0.z + v0.w;
  if (t < 128) s += v1.x + v1.y + v1.z + v1.w;
  #pragma unroll
  for (int off = 32; off >= 1; off >>= 1) s += __shfl_xor(s, off);
  if ((t & 63) == 0) red[t >> 6] = s;
  __syncthreads();
  if (t == 0) bc[0] = (red[0] + red[1] + red[2] + red[3]) * (1.f / 1536.f);
  __syncthreads();
  const float mu = bc[0];
  float d, s2 = 0.f;
  d = v0.x - mu; s2 += d * d; d = v0.y - mu; s2 += d * d;
  d = v0.z - mu; s2 += d * d; d = v0.w - mu; s2 += d * d;
  if (t < 128) {
    d = v1.x - mu; s2 += d * d; d = v1.y - mu; s2 += d * d;
    d = v1.z - mu; s2 += d * d; d = v1.w - mu; s2 += d * d;
  }
  #pragma unroll
  for (int off = 32; off >= 1; off >>= 1) s2 += __shfl_xor(s2, off);
  if ((t & 63) == 0) red[t >> 6] = s2;
  __syncthreads();
  if (t == 0) bc[1] = (red[0] + red[1] + red[2] + red[3]) * (1.f / 1536.f);
  __syncthreads();
  const float inv = rsqrtf(bc[1] + 1e-5f);
  const float4* g4 = (const float4*)g;
  const float4* b4 = (const float4*)bta;
  float4 gg = g4[t], bb = b4[t];
  f16x4 hv;
  hv[0] = (_Float16)((v0.x - mu) * inv * gg.x + bb.x);
  hv[1] = (_Float16)((v0.y - mu) * inv * gg.y + bb.y);
  hv[2] = (_Float16)((v0.z - mu) * inv * gg.z + bb.z);
  hv[3] = (_Float16)((v0.w - mu) * inv * gg.w + bb.w);
  *(f16x4*)(oh + (size_t)row * 1536 + t * 4) = hv;
  if (t < 128) {
    gg = g4[256 + t]; bb = b4[256 + t];
    hv[0] = (_Float16)((v1.x - mu) * inv * gg.x + bb.x);
    hv[1] = (_Float16)((v1.y - mu) * inv * gg.y + bb.y);
    hv[2] = (_Float16)((v1.z - mu) * inv * gg.z + bb.z);
    hv[3] = (_Float16)((v1.w - mu) * inv * gg.w + bb.w);
    *(f16x4*)(oh + (size_t)row * 1536 + 1024 + t * 4) = hv;
  }
}

// ------------- weight convert + transpose: W[K][N] fp32 -> T[roff+N][KD] f16 -------------
__global__ __launch_bounds__(256) void convw_kernel(
    const float* __restrict__ W, _Float16* __restrict__ Th,
    int N, int K, int KD, int roff, float scale) {
  __shared__ float tile[32][33];
  const int n0 = blockIdx.x * 32, k0 = blockIdx.y * 32;
  const int t = threadIdx.x;
  const int cr = t >> 5;
  const int cc = t & 31;
  #pragma unroll
  for (int p = 0; p < 4; ++p) {
    int r = cr + p * 8;
    tile[r][cc] = W[(size_t)(k0 + r) * N + n0 + cc];
  }
  __syncthreads();
  #pragma unroll
  for (int p = 0; p < 4; ++p) {
    int r = cr + p * 8;                    // local n
    float v = tile[cc][r] * scale;         // W[k0+cc][n0+r]
    Th[(size_t)(roff + n0 + r) * KD + k0 + cc] = (_Float16)v;
  }
}

// ------------- fp16 MFMA GEMM, 128x128 tile, BK=32 (m97 structure) -------------
// EPI: 2 = bias+relu -> f16 plane; 3 = bias+residual -> fp32;
//      4 = QKV epilogue: Q/K f16 planes + V^T f16 plane
template <int EPI>
__global__ __launch_bounds__(256, 2) void mgemm_kernel(
    const _Float16* __restrict__ A, const _Float16* __restrict__ B,
    float* __restrict__ C, _Float16* __restrict__ Ch,
    _Float16* __restrict__ Kp, _Float16* __restrict__ Vt,
    const float* __restrict__ bias, const float* __restrict__ res,
    int M, int N, int K) {
  __shared__ _Float16 sm[8192];  // A[128][32] @0, B[128][32] @4096 (8KB each)
  const int t = threadIdx.x;
  const int lane = t & 63;
  const int w = t >> 6;
  const int wm = w >> 1, wn = w & 1;
  const int m0 = blockIdx.y * 128, n0 = blockIdx.x * 128;

  f32x4 acc[4][4];
  #pragma unroll
  for (int i = 0; i < 4; ++i)
    #pragma unroll
    for (int j = 0; j < 4; ++j) acc[i][j] = (f32x4){0.f, 0.f, 0.f, 0.f};

  const int r0 = w * 32 + (lane >> 2);
  const int ks = lane & 3;
  const int lr = lane & 15;
  const int ko = (lane >> 4) * 8;
  char* smb = (char*)&sm[0];

  for (int k0 = 0; k0 < K; k0 += 32) {
    #pragma unroll
    for (int j = 0; j < 2; ++j) {
      int r = r0 + j * 16;
      int lo = (w * 2 + j) * 1024;
      gl_lds16(A + (size_t)(m0 + r) * K + k0 + ks * 8, smb + lo);
      gl_lds16(B + (size_t)(n0 + r) * K + k0 + ks * 8, smb + 8192 + lo);
    }
    __syncthreads();
    f16x8 a[4], b[4];
    const _Float16* pa = sm + (wm * 64 + lr) * 32 + ko;
    const _Float16* pb2 = sm + 4096 + (wn * 64 + lr) * 32 + ko;
    #pragma unroll
    for (int i = 0; i < 4; ++i) {
      a[i] = *(const f16x8*)(pa + i * 512);
      b[i] = *(const f16x8*)(pb2 + i * 512);
    }
    #pragma unroll
    for (int i = 0; i < 4; ++i)
      #pragma unroll
      for (int j = 0; j < 4; ++j)
        acc[i][j] = MFMAH(a[i], b[j], acc[i][j]);
    __syncthreads();
  }

  const int lq = lane >> 4;
  #pragma unroll
  for (int i = 0; i < 4; ++i) {
    #pragma unroll
    for (int j = 0; j < 4; ++j) {
      const int c0 = n0 + wn * 64 + j * 16;   // tile col base (uniform)
      const int col = c0 + lr;
      const int rbase = m0 + wm * 64 + i * 16 + lq * 4;
      if (EPI == 3) {
        #pragma unroll
        for (int q = 0; q < 4; ++q) {
          size_t o = (size_t)(rbase + q) * N + col;
          C[o] = acc[i][j][q] + bias[col] + res[o];
        }
      } else if (EPI == 2) {
        #pragma unroll
        for (int q = 0; q < 4; ++q) {
          size_t o = (size_t)(rbase + q) * N + col;
          Ch[o] = (_Float16)fmaxf(acc[i][j][q] + bias[col], 0.f);
        }
      } else {  // EPI == 4: QKV split epilogue
        if (c0 < 512) {
          #pragma unroll
          for (int q = 0; q < 4; ++q)
            Ch[(size_t)(rbase + q) * 512 + col] = (_Float16)acc[i][j][q];
        } else if (c0 < 1024) {
          #pragma unroll
          for (int q = 0; q < 4; ++q)
            Kp[(size_t)(rbase + q) * 512 + (col - 512)] = (_Float16)acc[i][j][q];
        } else {
          int dv = col - 1024;
          int hd = dv / 192;
          int dvh = dv - hd * 192;
          int bb = rbase / 1536;
          int nloc = rbase - bb * 1536;
          f16x4 pk;
          pk[0] = (_Float16)acc[i][j][0];
          pk[1] = (_Float16)acc[i][j][1];
          pk[2] = (_Float16)acc[i][j][2];
          pk[3] = (_Float16)acc[i][j][3];
          *(f16x4*)(Vt + (((size_t)bb * 8 + hd) * 192 + dvh) * 1536 + nloc) = pk;
        }
      }
    }
  }
}

// ------------- MFMA flash attention (fp16): chunk 32, 3 blocks/CU -------------
// 256 threads / 4 waves; block = 64 Q rows; 48 chunks of 32 j.
// LDS (f16): K dbuf [2][32][64] @0; V^T dbuf [2][192][32] @4096;
//   R [96][64] @16384; Ps [64][34] @22528.  Total 24704 f16 = 49.4 KB.
// K/R: 8-slot XOR swizzle (slot ^= row&7); V: 4-slot swizzle (slot ^= (row>>1)&3);
// realized by pre-swizzled global source (LDS dest of global_load_lds linear).
__global__ __launch_bounds__(256, 3) void attn_kernel(
    const _Float16* __restrict__ Qp, const _Float16* __restrict__ Kp,
    const _Float16* __restrict__ Vt, const _Float16* __restrict__ rk,
    const float* __restrict__ PR, const float* __restrict__ CK,
    _Float16* __restrict__ ao) {
  __shared__ _Float16 lds[24704];
  const int id = blockIdx.x;
  const int xcd = id & 7, s = id >> 3;    // XCD-chunked (b,h) mapping
  const int bh = xcd * 4 + s / 24;
  const int it = s % 24;
  const int b = bh >> 3, h = bh & 7;
  const int t = threadIdx.x;
  const int w = t >> 6;
  const int lane = t & 63;
  const int c15 = lane & 15, g = lane >> 4;
  const int swz = c15 & 7;                // K/R read swizzle (row&7 == c15&7)
  const int vsz = (c15 >> 1) & 3;         // V read swizzle ((row>>1)&3)
  const int qrow0 = it * 64 + w * 16;     // wave's 16 Q rows
  const int rrow0 = 48 - w * 16;          // wave's R-row base in LDS band

  // staging lane geometry
  const int lr = lane >> 3, sl = lane & 7;
  const int ss = sl ^ lr;                           // K/R source slot
  const int ss2 = (lane & 3) ^ ((lane >> 3) & 3);   // V source slot

  // persistent Q fragment (A-operand: lane holds row c15, k = g*8..+8, 32+g*8..+8)
  f16x8 qh0, qh1;
  {
    size_t qo = ((size_t)(b * SEQN + qrow0 + c15)) * 512 + h * 64 + g * 8;
    qh0 = *(const f16x8*)(Qp + qo);
    qh1 = *(const f16x8*)(Qp + qo + 32);
  }
  const float* PRrow = PR + (size_t)h * NDIST;
  const float* CKb2 = CK + (size_t)b * SEQN * 8 + h;

  f32x4 acc[12];
  #pragma unroll
  for (int d = 0; d < 12; ++d) acc[d] = (f32x4){0.f, 0.f, 0.f, 0.f};
  float mrun[4], lrun[4];
  #pragma unroll
  for (int q = 0; q < 4; ++q) { mrun[q] = -1e30f; lrun[q] = 0.f; }

  #define STAGE_KV(J0, KB, VB)                                                   \
    do {                                                                         \
      size_t gk = ((size_t)(b * SEQN + (J0) + w * 8 + lr)) * 512 + h * 64 + ss * 8; \
      gl_lds16(Kp + gk, &lds[(KB) + w * 512]);                                   \
      _Pragma("unroll") for (int p = 0; p < 3; ++p) {                            \
        int rv = w * 48 + p * 16 + (lane >> 2);                                  \
        size_t gv = (((size_t)(b * 8 + h)) * 192 + rv) * SEQN + (J0) + ss2 * 8;  \
        gl_lds16(Vt + gv, &lds[(VB) + (w * 48 + p * 16) * 32]);                  \
      }                                                                          \
    } while (0)

  #define STAGE_R(DB)                                                            \
    do {                                                                         \
      _Pragma("unroll") for (int p = 0; p < 3; ++p) {                            \
        int rr = w * 24 + p * 8 + lr;                                            \
        size_t gr = ((size_t)((DB) + rr)) * 512 + h * 64 + ss * 8;               \
        gl_lds16(rk + gr, &lds[16384 + (w * 24 + p * 8) * 64]);                  \
      }                                                                          \
    } while (0)

  // prologue: stage chunk 0
  STAGE_KV(0, 0, 4096);
  STAGE_R(1472 - it * 64);

  for (int c = 0; c < 48; ++c) {
    const int j0 = c * 32;
    const int cur = c & 1;
    const int KB = cur * 2048;
    const int VB = 4096 + cur * 6144;
    __syncthreads();  // A: staged data for chunk c visible

    // prefetch next chunk's K/V into alternate buffers (drains at barrier B)
    if (c < 47) STAGE_KV(j0 + 32, (cur ^ 1) * 2048, 4096 + (cur ^ 1) * 6144);

    const int dbase = 1520 + j0 - qrow0;
    // ---- T[e] = q . relk[dbase+e] + PR[dbase+e], e in [0,48) ----
    f32x4 T[3];
    #pragma unroll
    for (int et = 0; et < 3; ++et) {
      int rowR = rrow0 + et * 16 + c15;
      f16x8 rh0 = *(const f16x8*)(&lds[16384 + rowR * 64 + (g ^ swz) * 8]);
      f16x8 rh1 = *(const f16x8*)(&lds[16384 + rowR * 64 + ((4 + g) ^ swz) * 8]);
      f32x4 tt = (f32x4){0.f, 0.f, 0.f, 0.f};
      tt = MFMAH(qh0, rh0, tt);
      tt = MFMAH(qh1, rh1, tt);
      float prv = PRrow[dbase + et * 16 + c15];
      #pragma unroll
      for (int q = 0; q < 4; ++q) tt[q] += prv;
      T[et] = tt;
    }
    // ---- S = Q @ K^T + CK + gather(T) ----
    f32x4 S[2];
    #pragma unroll
    for (int st = 0; st < 2; ++st) {
      int rowK = st * 16 + c15;
      f16x8 kh0 = *(const f16x8*)(&lds[KB + rowK * 64 + (g ^ swz) * 8]);
      f16x8 kh1 = *(const f16x8*)(&lds[KB + rowK * 64 + ((4 + g) ^ swz) * 8]);
      f32x4 ssv = (f32x4){0.f, 0.f, 0.f, 0.f};
      ssv = MFMAH(qh0, kh0, ssv);
      ssv = MFMAH(qh1, kh1, ssv);
      float ckv = CKb2[(size_t)(j0 + st * 16 + c15) * 8];
      #pragma unroll
      for (int q = 0; q < 4; ++q) {
        int eoff = c15 + 15 - 4 * g - q;     // in [0,30]
        int src = (lane & 48) | (eoff & 15);
        float v0 = __shfl(T[st][q], src);
        float v1 = __shfl(T[st + 1][q], src);
        ssv[q] += ckv + ((eoff < 16) ? v0 : v1);
      }
      S[st] = ssv;
    }
    // ---- online softmax (16-lane row groups) with defer-max (THR=8) ----
    float mx[4];
    #pragma unroll
    for (int q = 0; q < 4; ++q) mx[q] = fmaxf(S[0][q], S[1][q]);
    #pragma unroll
    for (int off = 8; off >= 1; off >>= 1)
      #pragma unroll
      for (int q = 0; q < 4; ++q) mx[q] = fmaxf(mx[q], __shfl_xor(mx[q], off));
    int need = 0;
    #pragma unroll
    for (int q = 0; q < 4; ++q) need |= (mx[q] > mrun[q] + 8.0f) ? 1 : 0;
    if (__any(need)) {
      #pragma unroll
      for (int q = 0; q < 4; ++q) {
        float mn = fmaxf(mrun[q], mx[q]);
        float al = __expf(mrun[q] - mn);
        mrun[q] = mn;
        lrun[q] *= al;
        #pragma unroll
        for (int d = 0; d < 12; ++d) acc[d][q] *= al;
      }
    }
    float pv16[2][4], sum[4];
    #pragma unroll
    for (int q = 0; q < 4; ++q) sum[q] = 0.f;
    #pragma unroll
    for (int st = 0; st < 2; ++st)
      #pragma unroll
      for (int q = 0; q < 4; ++q) {
        float p = __expf(S[st][q] - mrun[q]);
        sum[q] += p;
        pv16[st][q] = p;
      }
    #pragma unroll
    for (int off = 8; off >= 1; off >>= 1)
      #pragma unroll
      for (int q = 0; q < 4; ++q) sum[q] += __shfl_xor(sum[q], off);
    #pragma unroll
    for (int q = 0; q < 4; ++q) lrun[q] += sum[q];

    // Ps repack (wave-private rows; same-wave write->read)
    #pragma unroll
    for (int st = 0; st < 2; ++st)
      #pragma unroll
      for (int q = 0; q < 4; ++q)
        lds[22528 + (w * 16 + 4 * g + q) * 34 + st * 16 + c15] = (_Float16)pv16[st][q];

    __syncthreads();  // B: R/K reads done; KV prefetch drained

    if (c < 47) STAGE_R(1472 + j0 + 32 - it * 64);

    // ---- PV: P[16][32] @ V^T fragments ----
    f16x8 pf = *(const f16x8*)(&lds[22528 + (w * 16 + c15) * 34 + g * 8]);
    #pragma unroll
    for (int d = 0; d < 12; ++d) {
      int rowV = d * 16 + c15;
      f16x8 vf = *(const f16x8*)(&lds[VB + rowV * 32 + (g ^ vsz) * 8]);
      acc[d] = MFMAH(pf, vf, acc[d]);
    }
  }

  // ---- epilogue: out = acc / l -> f16 plane ----
  float rinv[4];
  #pragma unroll
  for (int q = 0; q < 4; ++q) rinv[q] = 1.0f / lrun[q];
  #pragma unroll
  for (int d = 0; d < 12; ++d) {
    int col = h * 192 + d * 16 + c15;
    #pragma unroll
    for (int q = 0; q < 4; ++q) {
      size_t row = (size_t)(b * SEQN + qrow0 + 4 * g + q);
      ao[row * 1536 + col] = (_Float16)(acc[d][q] * rinv[q]);
    }
  }
  #undef STAGE_KV
  #undef STAGE_R
}

extern "C" void kernel_launch(void* const* d_in, const int* in_sizes, int n_in,
                              void* d_out, int out_size, void* d_ws, size_t ws_size,
                              hipStream_t stream) {
  (void)in_sizes; (void)n_in; (void)out_size; (void)ws_size;
  const float* x   = (const float*)d_in[0];
  const float* g1  = (const float*)d_in[1];
  const float* be1 = (const float*)d_in[2];
  const float* Wq  = (const float*)d_in[3];
  const float* Wk  = (const float*)d_in[4];
  const float* Wv  = (const float*)d_in[5];
  const float* Wo  = (const float*)d_in[6];
  const float* bo  = (const float*)d_in[7];
  const float* Wrk = (const float*)d_in[8];
  const float* cb  = (const float*)d_in[9];
  const float* pb  = (const float*)d_in[10];
  const float* g2  = (const float*)d_in[11];
  const float* be2 = (const float*)d_in[12];
  const float* W1  = (const float*)d_in[13];
  const float* b1  = (const float*)d_in[14];
  const float* W2  = (const float*)d_in[15];
  const float* b2  = (const float*)d_in[16];
  float* out = (float*)d_out;

  char* B = (char*)d_ws;
  float* pos     = (float*)(B + 0);             //  2,359,296
  _Float16* rk   = (_Float16*)(B + 2359296);    //  3,145,728 (3072 rows x 512)
  float* PRb     = (float*)(B + 5505024);       //     98,304
  float* CKb     = (float*)(B + 5603328);       //    196,608
  _Float16* xn   = (_Float16*)(B + 5799936);    // 18,874,368
  _Float16* Wb   = (_Float16*)(B + 24674304);   //  9,437,184 (max weight plane)
  _Float16* Qp   = (_Float16*)(B + 34111488);   //  6,291,456
  _Float16* Kp   = (_Float16*)(B + 40402944);   //  6,291,456
  _Float16* Vtp  = (_Float16*)(B + 46694400);   // 18,874,368
  _Float16* ao   = (_Float16*)(B + 65568768);   // 18,874,368
  float* x2      = (float*)(B + 84443136);      // 37,748,736
  _Float16* h1   = (_Float16*)(B + 122191872);  // 37,748,736 -> ends 159,940,608

  pos_embed_kernel<<<NDIST, 64, 0, stream>>>(pos);
  relk_kernel<<<NDIST, 512, 0, stream>>>(pos, Wrk, pb, rk, PRb);
  ln_kernel<<<MROWS, 256, 0, stream>>>(x, g1, be1, xn);
  // fused QKV weights (transposed); fold 0.125 scale into Wq
  convw_kernel<<<dim3(16, 48), 256, 0, stream>>>(Wq, Wb, 512, 1536, 1536, 0, 0.125f);
  convw_kernel<<<dim3(16, 48), 256, 0, stream>>>(Wk, Wb, 512, 1536, 1536, 512, 1.0f);
  convw_kernel<<<dim3(48, 48), 256, 0, stream>>>(Wv, Wb, 1536, 1536, 1536, 1024, 1.0f);
  mgemm_kernel<4><<<dim3(20, 48), 256, 0, stream>>>(
      xn, Wb, nullptr, Qp, Kp, Vtp, nullptr, nullptr, MROWS, 2560, 1536);
  ck_kernel<<<MROWS * 2, 256, 0, stream>>>(Kp, cb, CKb);
  attn_kernel<<<768, 256, 0, stream>>>(Qp, Kp, Vtp, rk, PRb, CKb, ao);
  convw_kernel<<<dim3(48, 48), 256, 0, stream>>>(Wo, Wb, 1536, 1536, 1536, 0, 1.0f);
  mgemm_kernel<3><<<dim3(12, 48), 256, 0, stream>>>(
      ao, Wb, x2, nullptr, nullptr, nullptr, bo, x, MROWS, 1536, 1536);
  ln_kernel<<<MROWS, 256, 0, stream>>>(x2, g2, be2, xn);
  convw_kernel<<<dim3(96, 48), 256, 0, stream>>>(W1, Wb, 3072, 1536, 1536, 0, 1.0f);
  mgemm_kernel<2><<<dim3(24, 48), 256, 0, stream>>>(
      xn, Wb, nullptr, h1, nullptr, nullptr, b1, nullptr, MROWS, 3072, 1536);
  convw_kernel<<<dim3(48, 96), 256, 0, stream>>>(W2, Wb, 1536, 3072, 3072, 0, 1.0f);
  mgemm_kernel<3><<<dim3(12, 48), 256, 0, stream>>>(
      h1, Wb, out, nullptr, nullptr, nullptr, b2, x2, MROWS, 1536, 3072);
}

// Round 11
// 536.731 us; speedup vs baseline: 7.1179x; 1.0531x over previous
//
#include <hip/hip_runtime.h>
#include <hip/hip_bf16.h>
#include <math.h>

#define SEQN 1536
#define NH 8
#define MROWS 6144      // BATCH*SEQ
#define NDIST 3071      // 2*SEQ-1

typedef __attribute__((ext_vector_type(8))) _Float16 f16x8;
typedef __attribute__((ext_vector_type(4))) _Float16 f16x4;
typedef __attribute__((ext_vector_type(4))) float f32x4;

#define MFMAH(a, b, c) __builtin_amdgcn_mfma_f32_16x16x32_f16(a, b, c, 0, 0, 0)

__device__ __forceinline__ void gl_lds16(const void* g, void* l) {
  __builtin_amdgcn_global_load_lds(
      (const __attribute__((address_space(1))) void*)g,
      (__attribute__((address_space(3))) void*)l, 16, 0, 0);
}

// ---------------- positional embedding table: pos[3071][192] ----------------
__global__ __launch_bounds__(64) void pos_embed_kernel(float* __restrict__ pos) {
  int row = blockIdx.x;
  int j = threadIdx.x;
  if (j >= 32) return;
  float dist = (float)(row - (SEQN - 1));
  float adist = fabsf(dist);
  float sgn = (dist > 0.f) ? 1.f : (dist < 0.f ? -1.f : 0.f);

  const float max_range = 10.58496250072116f;  // log2(1536)
  float hl = exp2f(3.0f + ((max_range - 3.0f) / 31.0f) * (float)j);
  float e_exp = expf(-0.6931471805599453f / hl * adist);

  float cw = exp2f((float)(j + 1)) - 1.0f;
  float e_cm = (cw > adist) ? 1.0f : 0.0f;

  float mean = 48.0f * (float)(j + 1);
  float tt = mean / 24.0f;
  float conc = tt * tt;
  float rate = mean / 576.0f;
  float log_unnorm = (conc - 1.0f) * logf(fmaxf(adist, 1e-20f)) - rate * adist;
  float log_norm = lgammaf(conc) - conc * logf(rate);
  float prob = expf(log_unnorm - log_norm) + 1e-8f;
  float mx = prob;
  #pragma unroll
  for (int off = 16; off >= 1; off >>= 1)
    mx = fmaxf(mx, __shfl_xor(mx, off, 32));
  float e_g = prob / mx;

  float* o = pos + (size_t)row * 192;
  o[j] = e_exp;        o[32 + j] = e_cm;        o[64 + j] = e_g;
  o[96 + j] = sgn * e_exp; o[128 + j] = sgn * e_cm; o[160 + j] = sgn * e_g;
}

// ------------- rel_k = pos @ Wrk -> f16 [3072 rows][512]; PR[h][d] -------------
__global__ __launch_bounds__(512) void relk_kernel(
    const float* __restrict__ pos, const float* __restrict__ Wrk,
    const float* __restrict__ pb, _Float16* __restrict__ rk, float* __restrict__ PR) {
  const int d = blockIdx.x;
  const int t = threadIdx.x;
  __shared__ float prow[192];
  if (t < 192) prow[t] = pos[(size_t)d * 192 + t];
  __syncthreads();
  float acc = 0.f;
  #pragma unroll 8
  for (int kk = 0; kk < 192; ++kk)
    acc = fmaf(prow[kk], Wrk[(size_t)kk * 512 + t], acc);
  rk[(size_t)d * 512 + t] = (_Float16)acc;
  float pv = pb[t] * acc;
  #pragma unroll
  for (int off = 32; off >= 1; off >>= 1) pv += __shfl_xor(pv, off);
  if ((t & 63) == 0) PR[(size_t)(t >> 6) * NDIST + d] = pv;
}

// ------------- CK[row][h] = cb_h . k[row,h,:] from f16 K plane -------------
__global__ __launch_bounds__(256) void ck_kernel(
    const _Float16* __restrict__ Kp, const float* __restrict__ cb,
    float* __restrict__ CK) {
  const int gid = blockIdx.x * 4 + (threadIdx.x >> 6);
  const int lane = threadIdx.x & 63;
  const int row = gid >> 3;
  const int h = gid & 7;
  float kv = (float)Kp[(size_t)row * 512 + h * 64 + lane];
  float pv = cb[h * 64 + lane] * kv;
  #pragma unroll
  for (int off = 32; off >= 1; off >>= 1) pv += __shfl_xor(pv, off);
  if (lane == 0) CK[(size_t)row * 8 + h] = pv;
}

// ------------- layernorm: fp32 in -> f16 plane out -------------
__global__ __launch_bounds__(256) void ln_kernel(
    const float* __restrict__ x, const float* __restrict__ g,
    const float* __restrict__ bta, _Float16* __restrict__ oh) {
  const int row = blockIdx.x;
  const int t = threadIdx.x;
  __shared__ float red[4];
  __shared__ float bc[2];
  const float4* xr = (const float4*)(x + (size_t)row * 1536);
  float4 v0 = xr[t];
  float4 v1 = make_float4(0.f, 0.f, 0.f, 0.f);
  if (t < 128) v1 = xr[256 + t];
  float s = v0.x + v0.y + v0.z + v0.w;
  if (t < 128) s += v1.x + v1.y + v1.z + v1.w;
  #pragma unroll
  for (int off = 32; off >= 1; off >>= 1) s += __shfl_xor(s, off);
  if ((t & 63) == 0) red[t >> 6] = s;
  __syncthreads();
  if (t == 0) bc[0] = (red[0] + red[1] + red[2] + red[3]) * (1.f / 1536.f);
  __syncthreads();
  const float mu = bc[0];
  float d, s2 = 0.f;
  d = v0.x - mu; s2 += d * d; d = v0.y - mu; s2 += d * d;
  d = v0.z - mu; s2 += d * d; d = v0.w - mu; s2 += d * d;
  if (t < 128) {
    d = v1.x - mu; s2 += d * d; d = v1.y - mu; s2 += d * d;
    d = v1.z - mu; s2 += d * d; d = v1.w - mu; s2 += d * d;
  }
  #pragma unroll
  for (int off = 32; off >= 1; off >>= 1) s2 += __shfl_xor(s2, off);
  if ((t & 63) == 0) red[t >> 6] = s2;
  __syncthreads();
  if (t == 0) bc[1] = (red[0] + red[1] + red[2] + red[3]) * (1.f / 1536.f);
  __syncthreads();
  const float inv = rsqrtf(bc[1] + 1e-5f);
  const float4* g4 = (const float4*)g;
  const float4* b4 = (const float4*)bta;
  float4 gg = g4[t], bb = b4[t];
  f16x4 hv;
  hv[0] = (_Float16)((v0.x - mu) * inv * gg.x + bb.x);
  hv[1] = (_Float16)((v0.y - mu) * inv * gg.y + bb.y);
  hv[2] = (_Float16)((v0.z - mu) * inv * gg.z + bb.z);
  hv[3] = (_Float16)((v0.w - mu) * inv * gg.w + bb.w);
  *(f16x4*)(oh + (size_t)row * 1536 + t * 4) = hv;
  if (t < 128) {
    gg = g4[256 + t]; bb = b4[256 + t];
    hv[0] = (_Float16)((v1.x - mu) * inv * gg.x + bb.x);
    hv[1] = (_Float16)((v1.y - mu) * inv * gg.y + bb.y);
    hv[2] = (_Float16)((v1.z - mu) * inv * gg.z + bb.z);
    hv[3] = (_Float16)((v1.w - mu) * inv * gg.w + bb.w);
    *(f16x4*)(oh + (size_t)row * 1536 + 1024 + t * 4) = hv;
  }
}

// ------------- weight convert + transpose: W[K][N] fp32 -> T[roff+N][KD] f16 -------------
__global__ __launch_bounds__(256) void convw_kernel(
    const float* __restrict__ W, _Float16* __restrict__ Th,
    int N, int K, int KD, int roff, float scale) {
  __shared__ float tile[32][33];
  const int n0 = blockIdx.x * 32, k0 = blockIdx.y * 32;
  const int t = threadIdx.x;
  const int cr = t >> 5;
  const int cc = t & 31;
  #pragma unroll
  for (int p = 0; p < 4; ++p) {
    int r = cr + p * 8;
    tile[r][cc] = W[(size_t)(k0 + r) * N + n0 + cc];
  }
  __syncthreads();
  #pragma unroll
  for (int p = 0; p < 4; ++p) {
    int r = cr + p * 8;                    // local n
    float v = tile[cc][r] * scale;         // W[k0+cc][n0+r]
    Th[(size_t)(roff + n0 + r) * KD + k0 + cc] = (_Float16)v;
  }
}

// ------------- fp16 MFMA GEMM, 128x128 tile, BK=32 (m97 structure) -------------
// 1D grid, XCD y-slab swizzle: each XCD owns ny/8 consecutive row-tiles (A-panel
// slab stays L2-resident); within XCD y varies fastest (B panel reused slab-times).
// EPI: 2 = bias+relu -> f16 plane; 3 = bias+residual -> fp32;
//      4 = QKV epilogue: Q/K f16 planes + V^T f16 plane
template <int EPI>
__global__ __launch_bounds__(256, 4) void mgemm_kernel(
    const _Float16* __restrict__ A, const _Float16* __restrict__ B,
    float* __restrict__ C, _Float16* __restrict__ Ch,
    _Float16* __restrict__ Kp, _Float16* __restrict__ Vt,
    const float* __restrict__ bias, const float* __restrict__ res,
    int M, int N, int K) {
  __shared__ _Float16 sm[8192];  // A[128][32] @0, B[128][32] @4096 (8KB each)
  const int t = threadIdx.x;
  const int lane = t & 63;
  const int w = t >> 6;
  const int wm = w >> 1, wn = w & 1;
  const int slab = (M >> 7) >> 3;           // row-tiles per XCD (6 for M=6144)
  const int xcd = blockIdx.x & 7;
  const int r = blockIdx.x >> 3;
  const int yt = xcd * slab + (r % slab);
  const int xt = r / slab;
  const int m0 = yt * 128, n0 = xt * 128;

  f32x4 acc[4][4];
  #pragma unroll
  for (int i = 0; i < 4; ++i)
    #pragma unroll
    for (int j = 0; j < 4; ++j) acc[i][j] = (f32x4){0.f, 0.f, 0.f, 0.f};

  const int r0 = w * 32 + (lane >> 2);
  const int ks = lane & 3;
  const int lr = lane & 15;
  const int ko = (lane >> 4) * 8;
  char* smb = (char*)&sm[0];

  for (int k0 = 0; k0 < K; k0 += 32) {
    #pragma unroll
    for (int j = 0; j < 2; ++j) {
      int rr = r0 + j * 16;
      int lo = (w * 2 + j) * 1024;
      gl_lds16(A + (size_t)(m0 + rr) * K + k0 + ks * 8, smb + lo);
      gl_lds16(B + (size_t)(n0 + rr) * K + k0 + ks * 8, smb + 8192 + lo);
    }
    __syncthreads();
    f16x8 a[4], b[4];
    const _Float16* pa = sm + (wm * 64 + lr) * 32 + ko;
    const _Float16* pb2 = sm + 4096 + (wn * 64 + lr) * 32 + ko;
    #pragma unroll
    for (int i = 0; i < 4; ++i) {
      a[i] = *(const f16x8*)(pa + i * 512);
      b[i] = *(const f16x8*)(pb2 + i * 512);
    }
    #pragma unroll
    for (int i = 0; i < 4; ++i)
      #pragma unroll
      for (int j = 0; j < 4; ++j)
        acc[i][j] = MFMAH(a[i], b[j], acc[i][j]);
    __syncthreads();
  }

  const int lq = lane >> 4;
  #pragma unroll
  for (int i = 0; i < 4; ++i) {
    #pragma unroll
    for (int j = 0; j < 4; ++j) {
      const int c0 = n0 + wn * 64 + j * 16;   // tile col base (uniform)
      const int col = c0 + lr;
      const int rbase = m0 + wm * 64 + i * 16 + lq * 4;
      if (EPI == 3) {
        #pragma unroll
        for (int q = 0; q < 4; ++q) {
          size_t o = (size_t)(rbase + q) * N + col;
          C[o] = acc[i][j][q] + bias[col] + res[o];
        }
      } else if (EPI == 2) {
        #pragma unroll
        for (int q = 0; q < 4; ++q) {
          size_t o = (size_t)(rbase + q) * N + col;
          Ch[o] = (_Float16)fmaxf(acc[i][j][q] + bias[col], 0.f);
        }
      } else {  // EPI == 4: QKV split epilogue
        if (c0 < 512) {
          #pragma unroll
          for (int q = 0; q < 4; ++q)
            Ch[(size_t)(rbase + q) * 512 + col] = (_Float16)acc[i][j][q];
        } else if (c0 < 1024) {
          #pragma unroll
          for (int q = 0; q < 4; ++q)
            Kp[(size_t)(rbase + q) * 512 + (col - 512)] = (_Float16)acc[i][j][q];
        } else {
          int dv = col - 1024;
          int hd = dv / 192;
          int dvh = dv - hd * 192;
          int bb = rbase / 1536;
          int nloc = rbase - bb * 1536;
          f16x4 pk;
          pk[0] = (_Float16)acc[i][j][0];
          pk[1] = (_Float16)acc[i][j][1];
          pk[2] = (_Float16)acc[i][j][2];
          pk[3] = (_Float16)acc[i][j][3];
          *(f16x4*)(Vt + (((size_t)bb * 8 + hd) * 192 + dvh) * 1536 + nloc) = pk;
        }
      }
    }
  }
}

// ------------- MFMA flash attention (fp16): chunk 32, ring-R, 3 blocks/CU -------------
// 256 threads / 4 waves; block = 64 Q rows; 48 chunks of 32 j.
// LDS (f16): K dbuf [2][32][64] @0; V^T dbuf [2][192][32] @4096;
//   R ring [128][64] @16384 (advances 32 rows/chunk); Ps [64][34] @24576.
//   Total 26752 f16 = 53.5 KB -> 3 blocks/CU.
// K/R: 8-slot XOR swizzle (slot ^= row&7); V: 4-slot swizzle (slot ^= (row>>1)&3);
// realized by pre-swizzled global source (LDS dest of global_load_lds linear).
__global__ __launch_bounds__(256, 3) void attn_kernel(
    const _Float16* __restrict__ Qp, const _Float16* __restrict__ Kp,
    const _Float16* __restrict__ Vt, const _Float16* __restrict__ rk,
    const float* __restrict__ PR, const float* __restrict__ CK,
    _Float16* __restrict__ ao) {
  __shared__ _Float16 lds[26752];
  const int id = blockIdx.x;
  const int xcd = id & 7, s = id >> 3;    // XCD-chunked (b,h) mapping
  const int bh = xcd * 4 + s / 24;
  const int it = s % 24;
  const int b = bh >> 3, h = bh & 7;
  const int t = threadIdx.x;
  const int w = t >> 6;
  const int lane = t & 63;
  const int c15 = lane & 15, g = lane >> 4;
  const int swz = c15 & 7;                // K/R read swizzle (row&7 == c15&7)
  const int vsz = (c15 >> 1) & 3;         // V read swizzle ((row>>1)&3)
  const int qrow0 = it * 64 + w * 16;     // wave's 16 Q rows
  const int rrow0 = 48 - w * 16;          // wave's band offset within window
  const int R0 = 1472 - it * 64;          // absolute rel_k row of ring origin

  // staging lane geometry
  const int lr = lane >> 3, sl = lane & 7;
  const int ss = sl ^ lr;                           // K/R source slot
  const int ss2 = (lane & 3) ^ ((lane >> 3) & 3);   // V source slot

  // persistent Q fragment (A-operand: lane holds row c15, k = g*8..+8, 32+g*8..+8)
  f16x8 qh0, qh1;
  {
    size_t qo = ((size_t)(b * SEQN + qrow0 + c15)) * 512 + h * 64 + g * 8;
    qh0 = *(const f16x8*)(Qp + qo);
    qh1 = *(const f16x8*)(Qp + qo + 32);
  }
  const float* PRrow = PR + (size_t)h * NDIST;
  const float* CKb2 = CK + (size_t)b * SEQN * 8 + h;

  f32x4 acc[12];
  #pragma unroll
  for (int d = 0; d < 12; ++d) acc[d] = (f32x4){0.f, 0.f, 0.f, 0.f};
  float mrun[4], lrun[4];
  #pragma unroll
  for (int q = 0; q < 4; ++q) { mrun[q] = -1e30f; lrun[q] = 0.f; }

  #define STAGE_KV(J0, KB, VB)                                                   \
    do {                                                                         \
      size_t gk = ((size_t)(b * SEQN + (J0) + w * 8 + lr)) * 512 + h * 64 + ss * 8; \
      gl_lds16(Kp + gk, &lds[(KB) + w * 512]);                                   \
      _Pragma("unroll") for (int p = 0; p < 3; ++p) {                            \
        int rv = w * 48 + p * 16 + (lane >> 2);                                  \
        size_t gv = (((size_t)(b * 8 + h)) * 192 + rv) * SEQN + (J0) + ss2 * 8;  \
        gl_lds16(Vt + gv, &lds[(VB) + (w * 48 + p * 16) * 32]);                  \
      }                                                                          \
    } while (0)

  // prologue: full 128-row ring fill (rel rows 0..127)
  #define STAGE_R_PRO()                                                          \
    do {                                                                         \
      _Pragma("unroll") for (int p = 0; p < 4; ++p) {                            \
        int rr = w * 32 + p * 8 + lr;                                            \
        size_t gr = ((size_t)(R0 + rr)) * 512 + h * 64 + ss * 8;                 \
        gl_lds16(rk + gr, &lds[16384 + (w * 32 + p * 8) * 64]);                  \
      }                                                                          \
    } while (0)

  // incremental: stage 32 new rows rel [REL0, REL0+32) into ring
  #define STAGE_R_INC(REL0)                                                      \
    do {                                                                         \
      int rr = (REL0) + w * 8 + lr;                                              \
      size_t gr = ((size_t)(R0 + rr)) * 512 + h * 64 + ss * 8;                   \
      gl_lds16(rk + gr, &lds[16384 + ((((REL0) + w * 8) & 127)) * 64]);          \
    } while (0)

  // compute one T tile at band offset ETOFF (ring read + PR add)
  #define COMP_T(DST, ETOFF)                                                     \
    do {                                                                         \
      int relrow = (cc32 + rrow0 + (ETOFF) + c15) & 127;                         \
      f16x8 r0_ = *(const f16x8*)(&lds[16384 + relrow * 64 + (g ^ swz) * 8]);    \
      f16x8 r1_ = *(const f16x8*)(&lds[16384 + relrow * 64 + ((4 + g) ^ swz) * 8]); \
      f32x4 tt_ = (f32x4){0.f, 0.f, 0.f, 0.f};                                   \
      tt_ = MFMAH(qh0, r0_, tt_);                                                \
      tt_ = MFMAH(qh1, r1_, tt_);                                                \
      float prv_ = PRrow[dbase + (ETOFF) + c15];                                 \
      _Pragma("unroll") for (int q = 0; q < 4; ++q) tt_[q] += prv_;              \
      DST = tt_;                                                                 \
    } while (0)

  STAGE_KV(0, 0, 4096);
  STAGE_R_PRO();

  f32x4 T0, T1, T2;

  for (int c = 0; c < 48; ++c) {
    const int j0 = c * 32;
    const int cc32 = c * 32;
    const int cur = c & 1;
    const int KB = cur * 2048;
    const int VB = 4096 + cur * 6144;
    __syncthreads();  // A: staged data for chunk c visible

    // prefetch next chunk's K/V into alternate buffers (drains by next A)
    if (c < 47) STAGE_KV(j0 + 32, (cur ^ 1) * 2048, 4096 + (cur ^ 1) * 6144);

    const int dbase = 1520 + j0 - qrow0;
    // ---- T tiles: carry T0 from previous chunk's T2; compute T1, T2 ----
    __builtin_amdgcn_s_setprio(1);
    if (c == 0) {
      COMP_T(T0, 0);
    } else {
      T0 = T2;
    }
    COMP_T(T1, 16);
    COMP_T(T2, 32);
    // ---- S = Q @ K^T ----
    f32x4 S[2];
    #pragma unroll
    for (int st = 0; st < 2; ++st) {
      int rowK = st * 16 + c15;
      f16x8 kh0 = *(const f16x8*)(&lds[KB + rowK * 64 + (g ^ swz) * 8]);
      f16x8 kh1 = *(const f16x8*)(&lds[KB + rowK * 64 + ((4 + g) ^ swz) * 8]);
      f32x4 ssv = (f32x4){0.f, 0.f, 0.f, 0.f};
      ssv = MFMAH(qh0, kh0, ssv);
      ssv = MFMAH(qh1, kh1, ssv);
      S[st] = ssv;
    }
    __builtin_amdgcn_s_setprio(0);
    // ---- add CK + gathered rel logits (12 shuffles) ----
    float ck0 = CKb2[(size_t)(j0 + c15) * 8];
    float ck1 = CKb2[(size_t)(j0 + 16 + c15) * 8];
    #pragma unroll
    for (int q = 0; q < 4; ++q) {
      int eoff = c15 + 15 - 4 * g - q;     // in [0,30]
      int src = (lane & 48) | (eoff & 15);
      float t0v = __shfl(T0[q], src);
      float t1v = __shfl(T1[q], src);
      float t2v = __shfl(T2[q], src);
      bool lo = eoff < 16;
      S[0][q] += ck0 + (lo ? t0v : t1v);
      S[1][q] += ck1 + (lo ? t1v : t2v);
    }
    // ---- online softmax (16-lane row groups) with defer-max (THR=8) ----
    float mx[4];
    #pragma unroll
    for (int q = 0; q < 4; ++q) mx[q] = fmaxf(S[0][q], S[1][q]);
    #pragma unroll
    for (int off = 8; off >= 1; off >>= 1)
      #pragma unroll
      for (int q = 0; q < 4; ++q) mx[q] = fmaxf(mx[q], __shfl_xor(mx[q], off));
    int need = 0;
    #pragma unroll
    for (int q = 0; q < 4; ++q) need |= (mx[q] > mrun[q] + 8.0f) ? 1 : 0;
    if (__any(need)) {
      #pragma unroll
      for (int q = 0; q < 4; ++q) {
        float mn = fmaxf(mrun[q], mx[q]);
        float al = __expf(mrun[q] - mn);
        mrun[q] = mn;
        lrun[q] *= al;
        #pragma unroll
        for (int d = 0; d < 12; ++d) acc[d][q] *= al;
      }
    }
    float pv16[2][4], sum[4];
    #pragma unroll
    for (int q = 0; q < 4; ++q) sum[q] = 0.f;
    #pragma unroll
    for (int st = 0; st < 2; ++st)
      #pragma unroll
      for (int q = 0; q < 4; ++q) {
        float p = __expf(S[st][q] - mrun[q]);
        sum[q] += p;
        pv16[st][q] = p;
      }
    #pragma unroll
    for (int off = 8; off >= 1; off >>= 1)
      #pragma unroll
      for (int q = 0; q < 4; ++q) sum[q] += __shfl_xor(sum[q], off);
    #pragma unroll
    for (int q = 0; q < 4; ++q) lrun[q] += sum[q];

    // Ps repack (wave-private rows; same-wave write->read)
    #pragma unroll
    for (int st = 0; st < 2; ++st)
      #pragma unroll
      for (int q = 0; q < 4; ++q)
        lds[24576 + (w * 16 + 4 * g + q) * 34 + st * 16 + c15] = (_Float16)pv16[st][q];

    __syncthreads();  // B: R/K reads of chunk c done; KV prefetch drained

    // stage 32 new ring rows (for chunk c+1's band); prologue covered c=0,1
    if (c >= 1 && c < 47) STAGE_R_INC(cc32 + 96);

    // ---- PV: P[16][32] @ V^T fragments ----
    f16x8 pf = *(const f16x8*)(&lds[24576 + (w * 16 + c15) * 34 + g * 8]);
    __builtin_amdgcn_s_setprio(1);
    #pragma unroll
    for (int d = 0; d < 12; ++d) {
      int rowV = d * 16 + c15;
      f16x8 vf = *(const f16x8*)(&lds[VB + rowV * 32 + (g ^ vsz) * 8]);
      acc[d] = MFMAH(pf, vf, acc[d]);
    }
    __builtin_amdgcn_s_setprio(0);
  }

  // ---- epilogue: out = acc / l -> f16 plane ----
  float rinv[4];
  #pragma unroll
  for (int q = 0; q < 4; ++q) rinv[q] = 1.0f / lrun[q];
  #pragma unroll
  for (int d = 0; d < 12; ++d) {
    int col = h * 192 + d * 16 + c15;
    #pragma unroll
    for (int q = 0; q < 4; ++q) {
      size_t row = (size_t)(b * SEQN + qrow0 + 4 * g + q);
      ao[row * 1536 + col] = (_Float16)(acc[d][q] * rinv[q]);
    }
  }
  #undef STAGE_KV
  #undef STAGE_R_PRO
  #undef STAGE_R_INC
  #undef COMP_T
}

extern "C" void kernel_launch(void* const* d_in, const int* in_sizes, int n_in,
                              void* d_out, int out_size, void* d_ws, size_t ws_size,
                              hipStream_t stream) {
  (void)in_sizes; (void)n_in; (void)out_size; (void)ws_size;
  const float* x   = (const float*)d_in[0];
  const float* g1  = (const float*)d_in[1];
  const float* be1 = (const float*)d_in[2];
  const float* Wq  = (const float*)d_in[3];
  const float* Wk  = (const float*)d_in[4];
  const float* Wv  = (const float*)d_in[5];
  const float* Wo  = (const float*)d_in[6];
  const float* bo  = (const float*)d_in[7];
  const float* Wrk = (const float*)d_in[8];
  const float* cb  = (const float*)d_in[9];
  const float* pb  = (const float*)d_in[10];
  const float* g2  = (const float*)d_in[11];
  const float* be2 = (const float*)d_in[12];
  const float* W1  = (const float*)d_in[13];
  const float* b1  = (const float*)d_in[14];
  const float* W2  = (const float*)d_in[15];
  const float* b2  = (const float*)d_in[16];
  float* out = (float*)d_out;

  char* B = (char*)d_ws;
  float* pos     = (float*)(B + 0);             //  2,359,296
  _Float16* rk   = (_Float16*)(B + 2359296);    //  3,145,728 (3072 rows x 512)
  float* PRb     = (float*)(B + 5505024);       //     98,304
  float* CKb     = (float*)(B + 5603328);       //    196,608
  _Float16* xn   = (_Float16*)(B + 5799936);    // 18,874,368
  _Float16* Wb   = (_Float16*)(B + 24674304);   //  9,437,184 (max weight plane)
  _Float16* Qp   = (_Float16*)(B + 34111488);   //  6,291,456
  _Float16* Kp   = (_Float16*)(B + 40402944);   //  6,291,456
  _Float16* Vtp  = (_Float16*)(B + 46694400);   // 18,874,368
  _Float16* ao   = (_Float16*)(B + 65568768);   // 18,874,368
  float* x2      = (float*)(B + 84443136);      // 37,748,736
  _Float16* h1   = (_Float16*)(B + 122191872);  // 37,748,736 -> ends 159,940,608

  pos_embed_kernel<<<NDIST, 64, 0, stream>>>(pos);
  relk_kernel<<<NDIST, 512, 0, stream>>>(pos, Wrk, pb, rk, PRb);
  ln_kernel<<<MROWS, 256, 0, stream>>>(x, g1, be1, xn);
  // fused QKV weights (transposed); fold 0.125 scale into Wq
  convw_kernel<<<dim3(16, 48), 256, 0, stream>>>(Wq, Wb, 512, 1536, 1536, 0, 0.125f);
  convw_kernel<<<dim3(16, 48), 256, 0, stream>>>(Wk, Wb, 512, 1536, 1536, 512, 1.0f);
  convw_kernel<<<dim3(48, 48), 256, 0, stream>>>(Wv, Wb, 1536, 1536, 1536, 1024, 1.0f);
  mgemm_kernel<4><<<960, 256, 0, stream>>>(
      xn, Wb, nullptr, Qp, Kp, Vtp, nullptr, nullptr, MROWS, 2560, 1536);
  ck_kernel<<<MROWS * 2, 256, 0, stream>>>(Kp, cb, CKb);
  attn_kernel<<<768, 256, 0, stream>>>(Qp, Kp, Vtp, rk, PRb, CKb, ao);
  convw_kernel<<<dim3(48, 48), 256, 0, stream>>>(Wo, Wb, 1536, 1536, 1536, 0, 1.0f);
  mgemm_kernel<3><<<576, 256, 0, stream>>>(
      ao, Wb, x2, nullptr, nullptr, nullptr, bo, x, MROWS, 1536, 1536);
  ln_kernel<<<MROWS, 256, 0, stream>>>(x2, g2, be2, xn);
  convw_kernel<<<dim3(96, 48), 256, 0, stream>>>(W1, Wb, 3072, 1536, 1536, 0, 1.0f);
  mgemm_kernel<2><<<1152, 256, 0, stream>>>(
      xn, Wb, nullptr, h1, nullptr, nullptr, b1, nullptr, MROWS, 3072, 1536);
  convw_kernel<<<dim3(48, 96), 256, 0, stream>>>(W2, Wb, 1536, 3072, 3072, 0, 1.0f);
  mgemm_kernel<3><<<576, 256, 0, stream>>>(
      h1, Wb, out, nullptr, nullptr, nullptr, b2, x2, MROWS, 1536, 3072);
}

// Round 12
// 519.221 us; speedup vs baseline: 7.3579x; 1.0337x over previous
//
#include <hip/hip_runtime.h>
#include <hip/hip_bf16.h>
#include <math.h>

#define SEQN 1536
#define NH 8
#define MROWS 6144      // BATCH*SEQ
#define NDIST 3071      // 2*SEQ-1

typedef __attribute__((ext_vector_type(8))) _Float16 f16x8;
typedef __attribute__((ext_vector_type(4))) _Float16 f16x4;
typedef __attribute__((ext_vector_type(4))) float f32x4;

#define MFMAH(a, b, c) __builtin_amdgcn_mfma_f32_16x16x32_f16(a, b, c, 0, 0, 0)

__device__ __forceinline__ void gl_lds16(const void* g, void* l) {
  __builtin_amdgcn_global_load_lds(
      (const __attribute__((address_space(1))) void*)g,
      (__attribute__((address_space(3))) void*)l, 16, 0, 0);
}

// ---------------- positional embedding table: pos[3071][192] ----------------
__global__ __launch_bounds__(64) void pos_embed_kernel(float* __restrict__ pos) {
  int row = blockIdx.x;
  int j = threadIdx.x;
  if (j >= 32) return;
  float dist = (float)(row - (SEQN - 1));
  float adist = fabsf(dist);
  float sgn = (dist > 0.f) ? 1.f : (dist < 0.f ? -1.f : 0.f);

  const float max_range = 10.58496250072116f;  // log2(1536)
  float hl = exp2f(3.0f + ((max_range - 3.0f) / 31.0f) * (float)j);
  float e_exp = expf(-0.6931471805599453f / hl * adist);

  float cw = exp2f((float)(j + 1)) - 1.0f;
  float e_cm = (cw > adist) ? 1.0f : 0.0f;

  float mean = 48.0f * (float)(j + 1);
  float tt = mean / 24.0f;
  float conc = tt * tt;
  float rate = mean / 576.0f;
  float log_unnorm = (conc - 1.0f) * logf(fmaxf(adist, 1e-20f)) - rate * adist;
  float log_norm = lgammaf(conc) - conc * logf(rate);
  float prob = expf(log_unnorm - log_norm) + 1e-8f;
  float mx = prob;
  #pragma unroll
  for (int off = 16; off >= 1; off >>= 1)
    mx = fmaxf(mx, __shfl_xor(mx, off, 32));
  float e_g = prob / mx;

  float* o = pos + (size_t)row * 192;
  o[j] = e_exp;        o[32 + j] = e_cm;        o[64 + j] = e_g;
  o[96 + j] = sgn * e_exp; o[128 + j] = sgn * e_cm; o[160 + j] = sgn * e_g;
}

// ------------- rel_k = pos @ Wrk -> f16 [3072 rows][512]; PR[h][d] -------------
// Tiled: each block owns 16 d-rows; Wrk streamed once per block (192 blocks,
// 75 MB total L2 traffic vs 1.2 GB in the one-row-per-block version).
__global__ __launch_bounds__(512) void relk_kernel(
    const float* __restrict__ pos, const float* __restrict__ Wrk,
    const float* __restrict__ pb, _Float16* __restrict__ rk, float* __restrict__ PR) {
  __shared__ float prow[16][192];
  const int d0 = blockIdx.x * 16;
  const int t = threadIdx.x;
  #pragma unroll
  for (int p = 0; p < 6; ++p) {
    int idx = t + p * 512;
    int r = idx / 192, c = idx - r * 192;
    prow[r][c] = pos[(size_t)(d0 + r) * 192 + c];
  }
  __syncthreads();
  float acc[16];
  #pragma unroll
  for (int r = 0; r < 16; ++r) acc[r] = 0.f;
  #pragma unroll 4
  for (int kk = 0; kk < 192; ++kk) {
    float wv = Wrk[(size_t)kk * 512 + t];
    #pragma unroll
    for (int r = 0; r < 16; ++r) acc[r] = fmaf(prow[r][kk], wv, acc[r]);
  }
  #pragma unroll
  for (int r = 0; r < 16; ++r)
    rk[(size_t)(d0 + r) * 512 + t] = (_Float16)acc[r];
  float pbv = pb[t];
  #pragma unroll
  for (int r = 0; r < 16; ++r) {
    float pv = pbv * acc[r];
    #pragma unroll
    for (int off = 32; off >= 1; off >>= 1) pv += __shfl_xor(pv, off);
    if ((t & 63) == 0 && (d0 + r) < NDIST)
      PR[(size_t)(t >> 6) * NDIST + d0 + r] = pv;
  }
}

// ------------- CK[row][h] = cb_h . k[row,h,:] from f16 K plane -------------
__global__ __launch_bounds__(256) void ck_kernel(
    const _Float16* __restrict__ Kp, const float* __restrict__ cb,
    float* __restrict__ CK) {
  const int gid = blockIdx.x * 4 + (threadIdx.x >> 6);
  const int lane = threadIdx.x & 63;
  const int row = gid >> 3;
  const int h = gid & 7;
  float kv = (float)Kp[(size_t)row * 512 + h * 64 + lane];
  float pv = cb[h * 64 + lane] * kv;
  #pragma unroll
  for (int off = 32; off >= 1; off >>= 1) pv += __shfl_xor(pv, off);
  if (lane == 0) CK[(size_t)row * 8 + h] = pv;
}

// ------------- layernorm: fp32 in -> f16 plane out -------------
__global__ __launch_bounds__(256) void ln_kernel(
    const float* __restrict__ x, const float* __restrict__ g,
    const float* __restrict__ bta, _Float16* __restrict__ oh) {
  const int row = blockIdx.x;
  const int t = threadIdx.x;
  __shared__ float red[4];
  __shared__ float bc[2];
  const float4* xr = (const float4*)(x + (size_t)row * 1536);
  float4 v0 = xr[t];
  float4 v1 = make_float4(0.f, 0.f, 0.f, 0.f);
  if (t < 128) v1 = xr[256 + t];
  float s = v0.x + v0.y + v0.z + v0.w;
  if (t < 128) s += v1.x + v1.y + v1.z + v1.w;
  #pragma unroll
  for (int off = 32; off >= 1; off >>= 1) s += __shfl_xor(s, off);
  if ((t & 63) == 0) red[t >> 6] = s;
  __syncthreads();
  if (t == 0) bc[0] = (red[0] + red[1] + red[2] + red[3]) * (1.f / 1536.f);
  __syncthreads();
  const float mu = bc[0];
  float d, s2 = 0.f;
  d = v0.x - mu; s2 += d * d; d = v0.y - mu; s2 += d * d;
  d = v0.z - mu; s2 += d * d; d = v0.w - mu; s2 += d * d;
  if (t < 128) {
    d = v1.x - mu; s2 += d * d; d = v1.y - mu; s2 += d * d;
    d = v1.z - mu; s2 += d * d; d = v1.w - mu; s2 += d * d;
  }
  #pragma unroll
  for (int off = 32; off >= 1; off >>= 1) s2 += __shfl_xor(s2, off);
  if ((t & 63) == 0) red[t >> 6] = s2;
  __syncthreads();
  if (t == 0) bc[1] = (red[0] + red[1] + red[2] + red[3]) * (1.f / 1536.f);
  __syncthreads();
  const float inv = rsqrtf(bc[1] + 1e-5f);
  const float4* g4 = (const float4*)g;
  const float4* b4 = (const float4*)bta;
  float4 gg = g4[t], bb = b4[t];
  f16x4 hv;
  hv[0] = (_Float16)((v0.x - mu) * inv * gg.x + bb.x);
  hv[1] = (_Float16)((v0.y - mu) * inv * gg.y + bb.y);
  hv[2] = (_Float16)((v0.z - mu) * inv * gg.z + bb.z);
  hv[3] = (_Float16)((v0.w - mu) * inv * gg.w + bb.w);
  *(f16x4*)(oh + (size_t)row * 1536 + t * 4) = hv;
  if (t < 128) {
    gg = g4[256 + t]; bb = b4[256 + t];
    hv[0] = (_Float16)((v1.x - mu) * inv * gg.x + bb.x);
    hv[1] = (_Float16)((v1.y - mu) * inv * gg.y + bb.y);
    hv[2] = (_Float16)((v1.z - mu) * inv * gg.z + bb.z);
    hv[3] = (_Float16)((v1.w - mu) * inv * gg.w + bb.w);
    *(f16x4*)(oh + (size_t)row * 1536 + 1024 + t * 4) = hv;
  }
}

// ------------- weight convert + transpose: W[K][N] fp32 -> T[roff+N][KD] f16 -------------
__global__ __launch_bounds__(256) void convw_kernel(
    const float* __restrict__ W, _Float16* __restrict__ Th,
    int N, int K, int KD, int roff, float scale) {
  __shared__ float tile[32][33];
  const int n0 = blockIdx.x * 32, k0 = blockIdx.y * 32;
  const int t = threadIdx.x;
  const int cr = t >> 5;
  const int cc = t & 31;
  #pragma unroll
  for (int p = 0; p < 4; ++p) {
    int r = cr + p * 8;
    tile[r][cc] = W[(size_t)(k0 + r) * N + n0 + cc];
  }
  __syncthreads();
  #pragma unroll
  for (int p = 0; p < 4; ++p) {
    int r = cr + p * 8;                    // local n
    float v = tile[cc][r] * scale;         // W[k0+cc][n0+r]
    Th[(size_t)(roff + n0 + r) * KD + k0 + cc] = (_Float16)v;
  }
}

// ------------- fp16 MFMA GEMM, 128x128 tile, BK=32 (m97 structure) -------------
// 1D grid, XCD y-slab swizzle; 4-slot XOR LDS swizzle (slot ^= row&3) kills the
// 8-way ds_read_b128 bank conflict; realized via pre-swizzled global source
// (LDS dest of global_load_lds stays linear) + swizzled fragment reads.
// EPI: 2 = bias+relu -> f16 plane; 3 = bias+residual -> fp32;
//      4 = QKV epilogue: Q/K f16 planes + V^T f16 plane
template <int EPI>
__global__ __launch_bounds__(256, 4) void mgemm_kernel(
    const _Float16* __restrict__ A, const _Float16* __restrict__ B,
    float* __restrict__ C, _Float16* __restrict__ Ch,
    _Float16* __restrict__ Kp, _Float16* __restrict__ Vt,
    const float* __restrict__ bias, const float* __restrict__ res,
    int M, int N, int K) {
  __shared__ _Float16 sm[8192];  // A[128][32] @0, B[128][32] @4096 (8KB each)
  const int t = threadIdx.x;
  const int lane = t & 63;
  const int w = t >> 6;
  const int wm = w >> 1, wn = w & 1;
  const int slab = (M >> 7) >> 3;           // row-tiles per XCD (6 for M=6144)
  const int xcd = blockIdx.x & 7;
  const int r = blockIdx.x >> 3;
  const int yt = xcd * slab + (r % slab);
  const int xt = r / slab;
  const int m0 = yt * 128, n0 = xt * 128;

  f32x4 acc[4][4];
  #pragma unroll
  for (int i = 0; i < 4; ++i)
    #pragma unroll
    for (int j = 0; j < 4; ++j) acc[i][j] = (f32x4){0.f, 0.f, 0.f, 0.f};

  const int r0 = w * 32 + (lane >> 2);
  const int ssg = (lane & 3) ^ ((lane >> 2) & 3);   // pre-swizzled source slot
  const int lr = lane & 15;
  const int g = lane >> 4;
  const int kswz = (g ^ (lr & 3)) * 8;              // swizzled fragment k-offset
  char* smb = (char*)&sm[0];

  for (int k0 = 0; k0 < K; k0 += 32) {
    #pragma unroll
    for (int j = 0; j < 2; ++j) {
      int rr = r0 + j * 16;
      int lo = (w * 2 + j) * 1024;
      gl_lds16(A + (size_t)(m0 + rr) * K + k0 + ssg * 8, smb + lo);
      gl_lds16(B + (size_t)(n0 + rr) * K + k0 + ssg * 8, smb + 8192 + lo);
    }
    __syncthreads();
    f16x8 a[4], b[4];
    const _Float16* pa = sm + (wm * 64 + lr) * 32 + kswz;
    const _Float16* pb2 = sm + 4096 + (wn * 64 + lr) * 32 + kswz;
    #pragma unroll
    for (int i = 0; i < 4; ++i) {
      a[i] = *(const f16x8*)(pa + i * 512);
      b[i] = *(const f16x8*)(pb2 + i * 512);
    }
    #pragma unroll
    for (int i = 0; i < 4; ++i)
      #pragma unroll
      for (int j = 0; j < 4; ++j)
        acc[i][j] = MFMAH(a[i], b[j], acc[i][j]);
    __syncthreads();
  }

  const int lq = lane >> 4;
  #pragma unroll
  for (int i = 0; i < 4; ++i) {
    #pragma unroll
    for (int j = 0; j < 4; ++j) {
      const int c0 = n0 + wn * 64 + j * 16;   // tile col base (uniform)
      const int col = c0 + lr;
      const int rbase = m0 + wm * 64 + i * 16 + lq * 4;
      if (EPI == 3) {
        #pragma unroll
        for (int q = 0; q < 4; ++q) {
          size_t o = (size_t)(rbase + q) * N + col;
          C[o] = acc[i][j][q] + bias[col] + res[o];
        }
      } else if (EPI == 2) {
        #pragma unroll
        for (int q = 0; q < 4; ++q) {
          size_t o = (size_t)(rbase + q) * N + col;
          Ch[o] = (_Float16)fmaxf(acc[i][j][q] + bias[col], 0.f);
        }
      } else {  // EPI == 4: QKV split epilogue
        if (c0 < 512) {
          #pragma unroll
          for (int q = 0; q < 4; ++q)
            Ch[(size_t)(rbase + q) * 512 + col] = (_Float16)acc[i][j][q];
        } else if (c0 < 1024) {
          #pragma unroll
          for (int q = 0; q < 4; ++q)
            Kp[(size_t)(rbase + q) * 512 + (col - 512)] = (_Float16)acc[i][j][q];
        } else {
          int dv = col - 1024;
          int hd = dv / 192;
          int dvh = dv - hd * 192;
          int bb = rbase / 1536;
          int nloc = rbase - bb * 1536;
          f16x4 pk;
          pk[0] = (_Float16)acc[i][j][0];
          pk[1] = (_Float16)acc[i][j][1];
          pk[2] = (_Float16)acc[i][j][2];
          pk[3] = (_Float16)acc[i][j][3];
          *(f16x4*)(Vt + (((size_t)bb * 8 + hd) * 192 + dvh) * 1536 + nloc) = pk;
        }
      }
    }
  }
}

// ------------- MFMA flash attention (fp16): chunk 32, ring-R, 3 blocks/CU -------------
// 256 threads / 4 waves; block = 64 Q rows; 48 chunks of 32 j.
// LDS (f16): K dbuf [2][32][64] @0; V^T dbuf [2][192][32] @4096;
//   R ring [128][64] @16384 (advances 32 rows/chunk); Ps [64][34] @24576.
// K/R: 8-slot XOR swizzle; V: 4-slot swizzle; pre-swizzled global source.
__global__ __launch_bounds__(256, 3) void attn_kernel(
    const _Float16* __restrict__ Qp, const _Float16* __restrict__ Kp,
    const _Float16* __restrict__ Vt, const _Float16* __restrict__ rk,
    const float* __restrict__ PR, const float* __restrict__ CK,
    _Float16* __restrict__ ao) {
  __shared__ _Float16 lds[26752];
  const int id = blockIdx.x;
  const int xcd = id & 7, s = id >> 3;    // XCD-chunked (b,h) mapping
  const int bh = xcd * 4 + s / 24;
  const int it = s % 24;
  const int b = bh >> 3, h = bh & 7;
  const int t = threadIdx.x;
  const int w = t >> 6;
  const int lane = t & 63;
  const int c15 = lane & 15, g = lane >> 4;
  const int swz = c15 & 7;                // K/R read swizzle (row&7 == c15&7)
  const int vsz = (c15 >> 1) & 3;         // V read swizzle ((row>>1)&3)
  const int qrow0 = it * 64 + w * 16;     // wave's 16 Q rows
  const int rrow0 = 48 - w * 16;          // wave's band offset within window
  const int R0 = 1472 - it * 64;          // absolute rel_k row of ring origin

  // staging lane geometry
  const int lr = lane >> 3, sl = lane & 7;
  const int ss = sl ^ lr;                           // K/R source slot
  const int ss2 = (lane & 3) ^ ((lane >> 3) & 3);   // V source slot

  // persistent Q fragment (A-operand: lane holds row c15, k = g*8..+8, 32+g*8..+8)
  f16x8 qh0, qh1;
  {
    size_t qo = ((size_t)(b * SEQN + qrow0 + c15)) * 512 + h * 64 + g * 8;
    qh0 = *(const f16x8*)(Qp + qo);
    qh1 = *(const f16x8*)(Qp + qo + 32);
  }
  const float* PRrow = PR + (size_t)h * NDIST;
  const float* CKb2 = CK + (size_t)b * SEQN * 8 + h;

  f32x4 acc[12];
  #pragma unroll
  for (int d = 0; d < 12; ++d) acc[d] = (f32x4){0.f, 0.f, 0.f, 0.f};
  float mrun[4], lrun[4];
  #pragma unroll
  for (int q = 0; q < 4; ++q) { mrun[q] = -1e30f; lrun[q] = 0.f; }

  #define STAGE_KV(J0, KB, VB)                                                   \
    do {                                                                         \
      size_t gk = ((size_t)(b * SEQN + (J0) + w * 8 + lr)) * 512 + h * 64 + ss * 8; \
      gl_lds16(Kp + gk, &lds[(KB) + w * 512]);                                   \
      _Pragma("unroll") for (int p = 0; p < 3; ++p) {                            \
        int rv = w * 48 + p * 16 + (lane >> 2);                                  \
        size_t gv = (((size_t)(b * 8 + h)) * 192 + rv) * SEQN + (J0) + ss2 * 8;  \
        gl_lds16(Vt + gv, &lds[(VB) + (w * 48 + p * 16) * 32]);                  \
      }                                                                          \
    } while (0)

  // prologue: full 128-row ring fill (rel rows 0..127)
  #define STAGE_R_PRO()                                                          \
    do {                                                                         \
      _Pragma("unroll") for (int p = 0; p < 4; ++p) {                            \
        int rr = w * 32 + p * 8 + lr;                                            \
        size_t gr = ((size_t)(R0 + rr)) * 512 + h * 64 + ss * 8;                 \
        gl_lds16(rk + gr, &lds[16384 + (w * 32 + p * 8) * 64]);                  \
      }                                                                          \
    } while (0)

  // incremental: stage 32 new rows rel [REL0, REL0+32) into ring
  #define STAGE_R_INC(REL0)                                                      \
    do {                                                                         \
      int rr = (REL0) + w * 8 + lr;                                              \
      size_t gr = ((size_t)(R0 + rr)) * 512 + h * 64 + ss * 8;                   \
      gl_lds16(rk + gr, &lds[16384 + ((((REL0) + w * 8) & 127)) * 64]);          \
    } while (0)

  // compute one T tile at band offset ETOFF (ring read + PR add)
  #define COMP_T(DST, ETOFF)                                                     \
    do {                                                                         \
      int relrow = (cc32 + rrow0 + (ETOFF) + c15) & 127;                         \
      f16x8 r0_ = *(const f16x8*)(&lds[16384 + relrow * 64 + (g ^ swz) * 8]);    \
      f16x8 r1_ = *(const f16x8*)(&lds[16384 + relrow * 64 + ((4 + g) ^ swz) * 8]); \
      f32x4 tt_ = (f32x4){0.f, 0.f, 0.f, 0.f};                                   \
      tt_ = MFMAH(qh0, r0_, tt_);                                                \
      tt_ = MFMAH(qh1, r1_, tt_);                                                \
      float prv_ = PRrow[dbase + (ETOFF) + c15];                                 \
      _Pragma("unroll") for (int q = 0; q < 4; ++q) tt_[q] += prv_;              \
      DST = tt_;                                                                 \
    } while (0)

  STAGE_KV(0, 0, 4096);
  STAGE_R_PRO();

  f32x4 T0, T1, T2;

  for (int c = 0; c < 48; ++c) {
    const int j0 = c * 32;
    const int cc32 = c * 32;
    const int cur = c & 1;
    const int KB = cur * 2048;
    const int VB = 4096 + cur * 6144;
    __syncthreads();  // A: staged data for chunk c visible

    // prefetch next chunk's K/V into alternate buffers (drains by next A)
    if (c < 47) STAGE_KV(j0 + 32, (cur ^ 1) * 2048, 4096 + (cur ^ 1) * 6144);

    const int dbase = 1520 + j0 - qrow0;
    // ---- T tiles: carry T0 from previous chunk's T2; compute T1, T2 ----
    __builtin_amdgcn_s_setprio(1);
    if (c == 0) {
      COMP_T(T0, 0);
    } else {
      T0 = T2;
    }
    COMP_T(T1, 16);
    COMP_T(T2, 32);
    // ---- S = Q @ K^T ----
    f32x4 S[2];
    #pragma unroll
    for (int st = 0; st < 2; ++st) {
      int rowK = st * 16 + c15;
      f16x8 kh0 = *(const f16x8*)(&lds[KB + rowK * 64 + (g ^ swz) * 8]);
      f16x8 kh1 = *(const f16x8*)(&lds[KB + rowK * 64 + ((4 + g) ^ swz) * 8]);
      f32x4 ssv = (f32x4){0.f, 0.f, 0.f, 0.f};
      ssv = MFMAH(qh0, kh0, ssv);
      ssv = MFMAH(qh1, kh1, ssv);
      S[st] = ssv;
    }
    __builtin_amdgcn_s_setprio(0);
    // ---- add CK + gathered rel logits (12 shuffles) ----
    float ck0 = CKb2[(size_t)(j0 + c15) * 8];
    float ck1 = CKb2[(size_t)(j0 + 16 + c15) * 8];
    #pragma unroll
    for (int q = 0; q < 4; ++q) {
      int eoff = c15 + 15 - 4 * g - q;     // in [0,30]
      int src = (lane & 48) | (eoff & 15);
      float t0v = __shfl(T0[q], src);
      float t1v = __shfl(T1[q], src);
      float t2v = __shfl(T2[q], src);
      bool lo = eoff < 16;
      S[0][q] += ck0 + (lo ? t0v : t1v);
      S[1][q] += ck1 + (lo ? t1v : t2v);
    }
    // ---- online softmax with lazy defer-max (T13: __any test on raw S) ----
    int need = 0;
    #pragma unroll
    for (int st = 0; st < 2; ++st)
      #pragma unroll
      for (int q = 0; q < 4; ++q) need |= (S[st][q] > mrun[q] + 8.0f) ? 1 : 0;
    if (__any(need)) {
      float mx[4];
      #pragma unroll
      for (int q = 0; q < 4; ++q) mx[q] = fmaxf(S[0][q], S[1][q]);
      #pragma unroll
      for (int off = 8; off >= 1; off >>= 1)
        #pragma unroll
        for (int q = 0; q < 4; ++q) mx[q] = fmaxf(mx[q], __shfl_xor(mx[q], off));
      #pragma unroll
      for (int q = 0; q < 4; ++q) {
        float mn = fmaxf(mrun[q], mx[q]);
        float al = __expf(mrun[q] - mn);
        mrun[q] = mn;
        lrun[q] *= al;
        #pragma unroll
        for (int d = 0; d < 12; ++d) acc[d][q] *= al;
      }
    }
    float pv16[2][4], sum[4];
    #pragma unroll
    for (int q = 0; q < 4; ++q) sum[q] = 0.f;
    #pragma unroll
    for (int st = 0; st < 2; ++st)
      #pragma unroll
      for (int q = 0; q < 4; ++q) {
        float p = __expf(S[st][q] - mrun[q]);
        sum[q] += p;
        pv16[st][q] = p;
      }
    #pragma unroll
    for (int off = 8; off >= 1; off >>= 1)
      #pragma unroll
      for (int q = 0; q < 4; ++q) sum[q] += __shfl_xor(sum[q], off);
    #pragma unroll
    for (int q = 0; q < 4; ++q) lrun[q] += sum[q];

    // Ps repack (wave-private rows; same-wave write->read)
    #pragma unroll
    for (int st = 0; st < 2; ++st)
      #pragma unroll
      for (int q = 0; q < 4; ++q)
        lds[24576 + (w * 16 + 4 * g + q) * 34 + st * 16 + c15] = (_Float16)pv16[st][q];

    __syncthreads();  // B: R/K reads of chunk c done; KV prefetch drained

    // stage 32 new ring rows (for chunk c+1's band); prologue covered c=0,1
    if (c >= 1 && c < 47) STAGE_R_INC(cc32 + 96);

    // ---- PV: P[16][32] @ V^T fragments ----
    f16x8 pf = *(const f16x8*)(&lds[24576 + (w * 16 + c15) * 34 + g * 8]);
    __builtin_amdgcn_s_setprio(1);
    #pragma unroll
    for (int d = 0; d < 12; ++d) {
      int rowV = d * 16 + c15;
      f16x8 vf = *(const f16x8*)(&lds[VB + rowV * 32 + (g ^ vsz) * 8]);
      acc[d] = MFMAH(pf, vf, acc[d]);
    }
    __builtin_amdgcn_s_setprio(0);
  }

  // ---- epilogue: out = acc / l -> f16 plane ----
  float rinv[4];
  #pragma unroll
  for (int q = 0; q < 4; ++q) rinv[q] = 1.0f / lrun[q];
  #pragma unroll
  for (int d = 0; d < 12; ++d) {
    int col = h * 192 + d * 16 + c15;
    #pragma unroll
    for (int q = 0; q < 4; ++q) {
      size_t row = (size_t)(b * SEQN + qrow0 + 4 * g + q);
      ao[row * 1536 + col] = (_Float16)(acc[d][q] * rinv[q]);
    }
  }
  #undef STAGE_KV
  #undef STAGE_R_PRO
  #undef STAGE_R_INC
  #undef COMP_T
}

extern "C" void kernel_launch(void* const* d_in, const int* in_sizes, int n_in,
                              void* d_out, int out_size, void* d_ws, size_t ws_size,
                              hipStream_t stream) {
  (void)in_sizes; (void)n_in; (void)out_size; (void)ws_size;
  const float* x   = (const float*)d_in[0];
  const float* g1  = (const float*)d_in[1];
  const float* be1 = (const float*)d_in[2];
  const float* Wq  = (const float*)d_in[3];
  const float* Wk  = (const float*)d_in[4];
  const float* Wv  = (const float*)d_in[5];
  const float* Wo  = (const float*)d_in[6];
  const float* bo  = (const float*)d_in[7];
  const float* Wrk = (const float*)d_in[8];
  const float* cb  = (const float*)d_in[9];
  const float* pb  = (const float*)d_in[10];
  const float* g2  = (const float*)d_in[11];
  const float* be2 = (const float*)d_in[12];
  const float* W1  = (const float*)d_in[13];
  const float* b1  = (const float*)d_in[14];
  const float* W2  = (const float*)d_in[15];
  const float* b2  = (const float*)d_in[16];
  float* out = (float*)d_out;

  char* B = (char*)d_ws;
  float* pos     = (float*)(B + 0);             //  2,359,296
  _Float16* rk   = (_Float16*)(B + 2359296);    //  3,145,728 (3072 rows x 512)
  float* PRb     = (float*)(B + 5505024);       //     98,304
  float* CKb     = (float*)(B + 5603328);       //    196,608
  _Float16* xn   = (_Float16*)(B + 5799936);    // 18,874,368
  _Float16* Wb   = (_Float16*)(B + 24674304);   //  9,437,184 (max weight plane)
  _Float16* Qp   = (_Float16*)(B + 34111488);   //  6,291,456
  _Float16* Kp   = (_Float16*)(B + 40402944);   //  6,291,456
  _Float16* Vtp  = (_Float16*)(B + 46694400);   // 18,874,368
  _Float16* ao   = (_Float16*)(B + 65568768);   // 18,874,368
  float* x2      = (float*)(B + 84443136);      // 37,748,736
  _Float16* h1   = (_Float16*)(B + 122191872);  // 37,748,736 -> ends 159,940,608

  pos_embed_kernel<<<NDIST, 64, 0, stream>>>(pos);
  relk_kernel<<<192, 512, 0, stream>>>(pos, Wrk, pb, rk, PRb);
  ln_kernel<<<MROWS, 256, 0, stream>>>(x, g1, be1, xn);
  // fused QKV weights (transposed); fold 0.125 scale into Wq
  convw_kernel<<<dim3(16, 48), 256, 0, stream>>>(Wq, Wb, 512, 1536, 1536, 0, 0.125f);
  convw_kernel<<<dim3(16, 48), 256, 0, stream>>>(Wk, Wb, 512, 1536, 1536, 512, 1.0f);
  convw_kernel<<<dim3(48, 48), 256, 0, stream>>>(Wv, Wb, 1536, 1536, 1536, 1024, 1.0f);
  mgemm_kernel<4><<<960, 256, 0, stream>>>(
      xn, Wb, nullptr, Qp, Kp, Vtp, nullptr, nullptr, MROWS, 2560, 1536);
  ck_kernel<<<MROWS * 2, 256, 0, stream>>>(Kp, cb, CKb);
  attn_kernel<<<768, 256, 0, stream>>>(Qp, Kp, Vtp, rk, PRb, CKb, ao);
  convw_kernel<<<dim3(48, 48), 256, 0, stream>>>(Wo, Wb, 1536, 1536, 1536, 0, 1.0f);
  mgemm_kernel<3><<<576, 256, 0, stream>>>(
      ao, Wb, x2, nullptr, nullptr, nullptr, bo, x, MROWS, 1536, 1536);
  ln_kernel<<<MROWS, 256, 0, stream>>>(x2, g2, be2, xn);
  convw_kernel<<<dim3(96, 48), 256, 0, stream>>>(W1, Wb, 3072, 1536, 1536, 0, 1.0f);
  mgemm_kernel<2><<<1152, 256, 0, stream>>>(
      xn, Wb, nullptr, h1, nullptr, nullptr, b1, nullptr, MROWS, 3072, 1536);
  convw_kernel<<<dim3(48, 96), 256, 0, stream>>>(W2, Wb, 1536, 3072, 3072, 0, 1.0f);
  mgemm_kernel<3><<<576, 256, 0, stream>>>(
      h1, Wb, out, nullptr, nullptr, nullptr, b2, x2, MROWS, 1536, 3072);
}

// Round 13
// 463.021 us; speedup vs baseline: 8.2510x; 1.1214x over previous
//
#include <hip/hip_runtime.h>
#include <hip/hip_bf16.h>
#include <math.h>

#define SEQN 1536
#define NH 8
#define MROWS 6144      // BATCH*SEQ
#define NDIST 3071      // 2*SEQ-1

typedef __attribute__((ext_vector_type(8))) _Float16 f16x8;
typedef __attribute__((ext_vector_type(4))) _Float16 f16x4;
typedef __attribute__((ext_vector_type(4))) float f32x4;

#define MFMAH(a, b, c) __builtin_amdgcn_mfma_f32_16x16x32_f16(a, b, c, 0, 0, 0)

__device__ __forceinline__ void gl_lds16(const void* g, void* l) {
  __builtin_amdgcn_global_load_lds(
      (const __attribute__((address_space(1))) void*)g,
      (__attribute__((address_space(3))) void*)l, 16, 0, 0);
}

// ---------------- positional embedding table: pos[3071][192] ----------------
__global__ __launch_bounds__(64) void pos_embed_kernel(float* __restrict__ pos) {
  int row = blockIdx.x;
  int j = threadIdx.x;
  if (j >= 32) return;
  float dist = (float)(row - (SEQN - 1));
  float adist = fabsf(dist);
  float sgn = (dist > 0.f) ? 1.f : (dist < 0.f ? -1.f : 0.f);

  const float max_range = 10.58496250072116f;  // log2(1536)
  float hl = exp2f(3.0f + ((max_range - 3.0f) / 31.0f) * (float)j);
  float e_exp = expf(-0.6931471805599453f / hl * adist);

  float cw = exp2f((float)(j + 1)) - 1.0f;
  float e_cm = (cw > adist) ? 1.0f : 0.0f;

  float mean = 48.0f * (float)(j + 1);
  float tt = mean / 24.0f;
  float conc = tt * tt;
  float rate = mean / 576.0f;
  float log_unnorm = (conc - 1.0f) * logf(fmaxf(adist, 1e-20f)) - rate * adist;
  float log_norm = lgammaf(conc) - conc * logf(rate);
  float prob = expf(log_unnorm - log_norm) + 1e-8f;
  float mx = prob;
  #pragma unroll
  for (int off = 16; off >= 1; off >>= 1)
    mx = fmaxf(mx, __shfl_xor(mx, off, 32));
  float e_g = prob / mx;

  float* o = pos + (size_t)row * 192;
  o[j] = e_exp;        o[32 + j] = e_cm;        o[64 + j] = e_g;
  o[96 + j] = sgn * e_exp; o[128 + j] = sgn * e_cm; o[160 + j] = sgn * e_g;
}

// ------------- rel_k = pos @ Wrk -> f16 [3072 rows][512]; PR[h][d] -------------
// Tiled: each block owns 16 d-rows; Wrk streamed once per block (192 blocks).
__global__ __launch_bounds__(512) void relk_kernel(
    const float* __restrict__ pos, const float* __restrict__ Wrk,
    const float* __restrict__ pb, _Float16* __restrict__ rk, float* __restrict__ PR) {
  __shared__ float prow[16][192];
  const int d0 = blockIdx.x * 16;
  const int t = threadIdx.x;
  #pragma unroll
  for (int p = 0; p < 6; ++p) {
    int idx = t + p * 512;
    int r = idx / 192, c = idx - r * 192;
    prow[r][c] = pos[(size_t)(d0 + r) * 192 + c];
  }
  __syncthreads();
  float acc[16];
  #pragma unroll
  for (int r = 0; r < 16; ++r) acc[r] = 0.f;
  #pragma unroll 4
  for (int kk = 0; kk < 192; ++kk) {
    float wv = Wrk[(size_t)kk * 512 + t];
    #pragma unroll
    for (int r = 0; r < 16; ++r) acc[r] = fmaf(prow[r][kk], wv, acc[r]);
  }
  #pragma unroll
  for (int r = 0; r < 16; ++r)
    rk[(size_t)(d0 + r) * 512 + t] = (_Float16)acc[r];
  float pbv = pb[t];
  #pragma unroll
  for (int r = 0; r < 16; ++r) {
    float pv = pbv * acc[r];
    #pragma unroll
    for (int off = 32; off >= 1; off >>= 1) pv += __shfl_xor(pv, off);
    if ((t & 63) == 0 && (d0 + r) < NDIST)
      PR[(size_t)(t >> 6) * NDIST + d0 + r] = pv;
  }
}

// ------------- CK[row][h] = cb_h . k[row,h,:] from f16 K plane -------------
__global__ __launch_bounds__(256) void ck_kernel(
    const _Float16* __restrict__ Kp, const float* __restrict__ cb,
    float* __restrict__ CK) {
  const int gid = blockIdx.x * 4 + (threadIdx.x >> 6);
  const int lane = threadIdx.x & 63;
  const int row = gid >> 3;
  const int h = gid & 7;
  float kv = (float)Kp[(size_t)row * 512 + h * 64 + lane];
  float pv = cb[h * 64 + lane] * kv;
  #pragma unroll
  for (int off = 32; off >= 1; off >>= 1) pv += __shfl_xor(pv, off);
  if (lane == 0) CK[(size_t)row * 8 + h] = pv;
}

// ------------- layernorm: fp32 in -> f16 plane out -------------
__global__ __launch_bounds__(256) void ln_kernel(
    const float* __restrict__ x, const float* __restrict__ g,
    const float* __restrict__ bta, _Float16* __restrict__ oh) {
  const int row = blockIdx.x;
  const int t = threadIdx.x;
  __shared__ float red[4];
  __shared__ float bc[2];
  const float4* xr = (const float4*)(x + (size_t)row * 1536);
  float4 v0 = xr[t];
  float4 v1 = make_float4(0.f, 0.f, 0.f, 0.f);
  if (t < 128) v1 = xr[256 + t];
  float s = v0.x + v0.y + v0.z + v0.w;
  if (t < 128) s += v1.x + v1.y + v1.z + v1.w;
  #pragma unroll
  for (int off = 32; off >= 1; off >>= 1) s += __shfl_xor(s, off);
  if ((t & 63) == 0) red[t >> 6] = s;
  __syncthreads();
  if (t == 0) bc[0] = (red[0] + red[1] + red[2] + red[3]) * (1.f / 1536.f);
  __syncthreads();
  const float mu = bc[0];
  float d, s2 = 0.f;
  d = v0.x - mu; s2 += d * d; d = v0.y - mu; s2 += d * d;
  d = v0.z - mu; s2 += d * d; d = v0.w - mu; s2 += d * d;
  if (t < 128) {
    d = v1.x - mu; s2 += d * d; d = v1.y - mu; s2 += d * d;
    d = v1.z - mu; s2 += d * d; d = v1.w - mu; s2 += d * d;
  }
  #pragma unroll
  for (int off = 32; off >= 1; off >>= 1) s2 += __shfl_xor(s2, off);
  if ((t & 63) == 0) red[t >> 6] = s2;
  __syncthreads();
  if (t == 0) bc[1] = (red[0] + red[1] + red[2] + red[3]) * (1.f / 1536.f);
  __syncthreads();
  const float inv = rsqrtf(bc[1] + 1e-5f);
  const float4* g4 = (const float4*)g;
  const float4* b4 = (const float4*)bta;
  float4 gg = g4[t], bb = b4[t];
  f16x4 hv;
  hv[0] = (_Float16)((v0.x - mu) * inv * gg.x + bb.x);
  hv[1] = (_Float16)((v0.y - mu) * inv * gg.y + bb.y);
  hv[2] = (_Float16)((v0.z - mu) * inv * gg.z + bb.z);
  hv[3] = (_Float16)((v0.w - mu) * inv * gg.w + bb.w);
  *(f16x4*)(oh + (size_t)row * 1536 + t * 4) = hv;
  if (t < 128) {
    gg = g4[256 + t]; bb = b4[256 + t];
    hv[0] = (_Float16)((v1.x - mu) * inv * gg.x + bb.x);
    hv[1] = (_Float16)((v1.y - mu) * inv * gg.y + bb.y);
    hv[2] = (_Float16)((v1.z - mu) * inv * gg.z + bb.z);
    hv[3] = (_Float16)((v1.w - mu) * inv * gg.w + bb.w);
    *(f16x4*)(oh + (size_t)row * 1536 + 1024 + t * 4) = hv;
  }
}

// ------------- weight convert + transpose: W[K][N] fp32 -> T[roff+N][KD] f16 -------------
__global__ __launch_bounds__(256) void convw_kernel(
    const float* __restrict__ W, _Float16* __restrict__ Th,
    int N, int K, int KD, int roff, float scale) {
  __shared__ float tile[32][33];
  const int n0 = blockIdx.x * 32, k0 = blockIdx.y * 32;
  const int t = threadIdx.x;
  const int cr = t >> 5;
  const int cc = t & 31;
  #pragma unroll
  for (int p = 0; p < 4; ++p) {
    int r = cr + p * 8;
    tile[r][cc] = W[(size_t)(k0 + r) * N + n0 + cc];
  }
  __syncthreads();
  #pragma unroll
  for (int p = 0; p < 4; ++p) {
    int r = cr + p * 8;                    // local n
    float v = tile[cc][r] * scale;         // W[k0+cc][n0+r]
    Th[(size_t)(roff + n0 + r) * KD + k0 + cc] = (_Float16)v;
  }
}

// ------------- fp16 MFMA GEMM, 128xBN tile, BK=64 -------------
// 1D grid, XCD y-slab swizzle; 8-slot XOR LDS swizzle (slot ^= row&7) via
// pre-swizzled global source (LDS dest of global_load_lds stays linear) +
// swizzled fragment reads. BK=64 halves barrier count (32 MFMA per pair).
// BNJ = j-tiles per wave: 4 -> BN=128, 3 -> BN=96 (exact 768-block fill at N=1536).
// EPI: 2 = bias+relu -> f16 plane; 3 = bias+residual -> fp32;
//      4 = QKV epilogue: Q/K f16 planes + V^T f16 plane
template <int EPI, int BNJ>
__global__ __launch_bounds__(256, 4) void mgemm_kernel(
    const _Float16* __restrict__ A, const _Float16* __restrict__ B,
    float* __restrict__ C, _Float16* __restrict__ Ch,
    _Float16* __restrict__ Kp, _Float16* __restrict__ Vt,
    const float* __restrict__ bias, const float* __restrict__ res,
    int M, int N, int K) {
  constexpr int BN = BNJ * 32;                 // 128 or 96
  __shared__ _Float16 sm[8192 + BN * 64];      // A[128][64] @0, B[BN][64] @8192
  const int t = threadIdx.x;
  const int lane = t & 63;
  const int w = t >> 6;
  const int wm = w >> 1, wn = w & 1;
  const int slab = (M >> 7) >> 3;              // row-tiles per XCD (6 for M=6144)
  const int xcd = blockIdx.x & 7;
  const int r = blockIdx.x >> 3;
  const int yt = xcd * slab + (r % slab);
  const int xt = r / slab;
  const int m0 = yt * 128, n0 = xt * BN;

  f32x4 acc[4][BNJ];
  #pragma unroll
  for (int i = 0; i < 4; ++i)
    #pragma unroll
    for (int j = 0; j < BNJ; ++j) acc[i][j] = (f32x4){0.f, 0.f, 0.f, 0.f};

  // staging geometry: chunk id = row*8 + sl (8 slots x 16B per 64-f16 row);
  // thread t covers (srow + p*32, sl = t&7); source slot pre-swizzled, p-invariant.
  const int srow = t >> 3;
  const int ssl = t & 7;
  const int ss = ssl ^ (srow & 7);
  const int lr = lane & 15;
  const int g = lane >> 4;
  const int kb = lr & 7;                       // fragment-row swizzle key

  for (int k0 = 0; k0 < K; k0 += 64) {
    #pragma unroll
    for (int p = 0; p < 4; ++p) {
      int row = srow + p * 32;
      gl_lds16(A + (size_t)(m0 + row) * K + k0 + ss * 8, &sm[row * 64 + ssl * 8]);
    }
    #pragma unroll
    for (int p = 0; p < BN / 32; ++p) {
      int row = srow + p * 32;
      gl_lds16(B + (size_t)(n0 + row) * K + k0 + ss * 8,
               &sm[8192 + row * 64 + ssl * 8]);
    }
    __syncthreads();
    #pragma unroll
    for (int h2 = 0; h2 < 2; ++h2) {
      const int ksl = ((h2 * 4 + g) ^ kb) * 8;
      f16x8 a[4], b[BNJ];
      #pragma unroll
      for (int i = 0; i < 4; ++i)
        a[i] = *(const f16x8*)(&sm[(wm * 64 + i * 16 + lr) * 64 + ksl]);
      #pragma unroll
      for (int j = 0; j < BNJ; ++j)
        b[j] = *(const f16x8*)(&sm[8192 + (wn * BNJ * 16 + j * 16 + lr) * 64 + ksl]);
      #pragma unroll
      for (int i = 0; i < 4; ++i)
        #pragma unroll
        for (int j = 0; j < BNJ; ++j)
          acc[i][j] = MFMAH(a[i], b[j], acc[i][j]);
    }
    __syncthreads();
  }

  const int lq = lane >> 4;
  #pragma unroll
  for (int i = 0; i < 4; ++i) {
    #pragma unroll
    for (int j = 0; j < BNJ; ++j) {
      const int c0 = n0 + wn * BNJ * 16 + j * 16;   // tile col base (uniform)
      const int col = c0 + lr;
      const int rbase = m0 + wm * 64 + i * 16 + lq * 4;
      if (EPI == 3) {
        #pragma unroll
        for (int q = 0; q < 4; ++q) {
          size_t o = (size_t)(rbase + q) * N + col;
          C[o] = acc[i][j][q] + bias[col] + res[o];
        }
      } else if (EPI == 2) {
        #pragma unroll
        for (int q = 0; q < 4; ++q) {
          size_t o = (size_t)(rbase + q) * N + col;
          Ch[o] = (_Float16)fmaxf(acc[i][j][q] + bias[col], 0.f);
        }
      } else {  // EPI == 4: QKV split epilogue
        if (c0 < 512) {
          #pragma unroll
          for (int q = 0; q < 4; ++q)
            Ch[(size_t)(rbase + q) * 512 + col] = (_Float16)acc[i][j][q];
        } else if (c0 < 1024) {
          #pragma unroll
          for (int q = 0; q < 4; ++q)
            Kp[(size_t)(rbase + q) * 512 + (col - 512)] = (_Float16)acc[i][j][q];
        } else {
          int dv = col - 1024;
          int hd = dv / 192;
          int dvh = dv - hd * 192;
          int bb = rbase / 1536;
          int nloc = rbase - bb * 1536;
          f16x4 pk;
          pk[0] = (_Float16)acc[i][j][0];
          pk[1] = (_Float16)acc[i][j][1];
          pk[2] = (_Float16)acc[i][j][2];
          pk[3] = (_Float16)acc[i][j][3];
          *(f16x4*)(Vt + (((size_t)bb * 8 + hd) * 192 + dvh) * 1536 + nloc) = pk;
        }
      }
    }
  }
}

// ------------- MFMA flash attention (fp16): chunk 32, ring-R, 3 blocks/CU -------------
// 256 threads / 4 waves; block = 64 Q rows; 48 chunks of 32 j.
// LDS (f16): K dbuf [2][32][64] @0; V^T dbuf [2][192][32] @4096;
//   R ring [128][64] @16384 (advances 32 rows/chunk); Ps [64][34] @24576.
// K/R: 8-slot XOR swizzle; V: 4-slot swizzle; pre-swizzled global source.
__global__ __launch_bounds__(256, 3) void attn_kernel(
    const _Float16* __restrict__ Qp, const _Float16* __restrict__ Kp,
    const _Float16* __restrict__ Vt, const _Float16* __restrict__ rk,
    const float* __restrict__ PR, const float* __restrict__ CK,
    _Float16* __restrict__ ao) {
  __shared__ _Float16 lds[26752];
  const int id = blockIdx.x;
  const int xcd = id & 7, s = id >> 3;    // XCD-chunked (b,h) mapping
  const int bh = xcd * 4 + s / 24;
  const int it = s % 24;
  const int b = bh >> 3, h = bh & 7;
  const int t = threadIdx.x;
  const int w = t >> 6;
  const int lane = t & 63;
  const int c15 = lane & 15, g = lane >> 4;
  const int swz = c15 & 7;                // K/R read swizzle (row&7 == c15&7)
  const int vsz = (c15 >> 1) & 3;         // V read swizzle ((row>>1)&3)
  const int qrow0 = it * 64 + w * 16;     // wave's 16 Q rows
  const int rrow0 = 48 - w * 16;          // wave's band offset within window
  const int R0 = 1472 - it * 64;          // absolute rel_k row of ring origin

  // staging lane geometry
  const int lr = lane >> 3, sl = lane & 7;
  const int ss = sl ^ lr;                           // K/R source slot
  const int ss2 = (lane & 3) ^ ((lane >> 3) & 3);   // V source slot

  // persistent Q fragment (A-operand: lane holds row c15, k = g*8..+8, 32+g*8..+8)
  f16x8 qh0, qh1;
  {
    size_t qo = ((size_t)(b * SEQN + qrow0 + c15)) * 512 + h * 64 + g * 8;
    qh0 = *(const f16x8*)(Qp + qo);
    qh1 = *(const f16x8*)(Qp + qo + 32);
  }
  const float* PRrow = PR + (size_t)h * NDIST;
  const float* CKb2 = CK + (size_t)b * SEQN * 8 + h;

  f32x4 acc[12];
  #pragma unroll
  for (int d = 0; d < 12; ++d) acc[d] = (f32x4){0.f, 0.f, 0.f, 0.f};
  float mrun[4], lrun[4];
  #pragma unroll
  for (int q = 0; q < 4; ++q) { mrun[q] = -1e30f; lrun[q] = 0.f; }

  #define STAGE_KV(J0, KB, VB)                                                   \
    do {                                                                         \
      size_t gk = ((size_t)(b * SEQN + (J0) + w * 8 + lr)) * 512 + h * 64 + ss * 8; \
      gl_lds16(Kp + gk, &lds[(KB) + w * 512]);                                   \
      _Pragma("unroll") for (int p = 0; p < 3; ++p) {                            \
        int rv = w * 48 + p * 16 + (lane >> 2);                                  \
        size_t gv = (((size_t)(b * 8 + h)) * 192 + rv) * SEQN + (J0) + ss2 * 8;  \
        gl_lds16(Vt + gv, &lds[(VB) + (w * 48 + p * 16) * 32]);                  \
      }                                                                          \
    } while (0)

  // prologue: full 128-row ring fill (rel rows 0..127)
  #define STAGE_R_PRO()                                                          \
    do {                                                                         \
      _Pragma("unroll") for (int p = 0; p < 4; ++p) {                            \
        int rr = w * 32 + p * 8 + lr;                                            \
        size_t gr = ((size_t)(R0 + rr)) * 512 + h * 64 + ss * 8;                 \
        gl_lds16(rk + gr, &lds[16384 + (w * 32 + p * 8) * 64]);                  \
      }                                                                          \
    } while (0)

  // incremental: stage 32 new rows rel [REL0, REL0+32) into ring
  #define STAGE_R_INC(REL0)                                                      \
    do {                                                                         \
      int rr = (REL0) + w * 8 + lr;                                              \
      size_t gr = ((size_t)(R0 + rr)) * 512 + h * 64 + ss * 8;                   \
      gl_lds16(rk + gr, &lds[16384 + ((((REL0) + w * 8) & 127)) * 64]);          \
    } while (0)

  // compute one T tile at band offset ETOFF (ring read + PR add)
  #define COMP_T(DST, ETOFF)                                                     \
    do {                                                                         \
      int relrow = (cc32 + rrow0 + (ETOFF) + c15) & 127;                         \
      f16x8 r0_ = *(const f16x8*)(&lds[16384 + relrow * 64 + (g ^ swz) * 8]);    \
      f16x8 r1_ = *(const f16x8*)(&lds[16384 + relrow * 64 + ((4 + g) ^ swz) * 8]); \
      f32x4 tt_ = (f32x4){0.f, 0.f, 0.f, 0.f};                                   \
      tt_ = MFMAH(qh0, r0_, tt_);                                                \
      tt_ = MFMAH(qh1, r1_, tt_);                                                \
      float prv_ = PRrow[dbase + (ETOFF) + c15];                                 \
      _Pragma("unroll") for (int q = 0; q < 4; ++q) tt_[q] += prv_;              \
      DST = tt_;                                                                 \
    } while (0)

  STAGE_KV(0, 0, 4096);
  STAGE_R_PRO();

  f32x4 T0, T1, T2;

  for (int c = 0; c < 48; ++c) {
    const int j0 = c * 32;
    const int cc32 = c * 32;
    const int cur = c & 1;
    const int KB = cur * 2048;
    const int VB = 4096 + cur * 6144;
    __syncthreads();  // A: staged data for chunk c visible

    // prefetch next chunk's K/V into alternate buffers (drains by next A)
    if (c < 47) STAGE_KV(j0 + 32, (cur ^ 1) * 2048, 4096 + (cur ^ 1) * 6144);

    const int dbase = 1520 + j0 - qrow0;
    // ---- T tiles: carry T0 from previous chunk's T2; compute T1, T2 ----
    __builtin_amdgcn_s_setprio(1);
    if (c == 0) {
      COMP_T(T0, 0);
    } else {
      T0 = T2;
    }
    COMP_T(T1, 16);
    COMP_T(T2, 32);
    // ---- S = Q @ K^T ----
    f32x4 S[2];
    #pragma unroll
    for (int st = 0; st < 2; ++st) {
      int rowK = st * 16 + c15;
      f16x8 kh0 = *(const f16x8*)(&lds[KB + rowK * 64 + (g ^ swz) * 8]);
      f16x8 kh1 = *(const f16x8*)(&lds[KB + rowK * 64 + ((4 + g) ^ swz) * 8]);
      f32x4 ssv = (f32x4){0.f, 0.f, 0.f, 0.f};
      ssv = MFMAH(qh0, kh0, ssv);
      ssv = MFMAH(qh1, kh1, ssv);
      S[st] = ssv;
    }
    __builtin_amdgcn_s_setprio(0);
    // ---- add CK + gathered rel logits (12 shuffles) ----
    float ck0 = CKb2[(size_t)(j0 + c15) * 8];
    float ck1 = CKb2[(size_t)(j0 + 16 + c15) * 8];
    #pragma unroll
    for (int q = 0; q < 4; ++q) {
      int eoff = c15 + 15 - 4 * g - q;     // in [0,30]
      int src = (lane & 48) | (eoff & 15);
      float t0v = __shfl(T0[q], src);
      float t1v = __shfl(T1[q], src);
      float t2v = __shfl(T2[q], src);
      bool lo = eoff < 16;
      S[0][q] += ck0 + (lo ? t0v : t1v);
      S[1][q] += ck1 + (lo ? t1v : t2v);
    }
    // ---- online softmax with lazy defer-max (T13: __any test on raw S) ----
    int need = 0;
    #pragma unroll
    for (int st = 0; st < 2; ++st)
      #pragma unroll
      for (int q = 0; q < 4; ++q) need |= (S[st][q] > mrun[q] + 8.0f) ? 1 : 0;
    if (__any(need)) {
      float mx[4];
      #pragma unroll
      for (int q = 0; q < 4; ++q) mx[q] = fmaxf(S[0][q], S[1][q]);
      #pragma unroll
      for (int off = 8; off >= 1; off >>= 1)
        #pragma unroll
        for (int q = 0; q < 4; ++q) mx[q] = fmaxf(mx[q], __shfl_xor(mx[q], off));
      #pragma unroll
      for (int q = 0; q < 4; ++q) {
        float mn = fmaxf(mrun[q], mx[q]);
        float al = __expf(mrun[q] - mn);
        mrun[q] = mn;
        lrun[q] *= al;
        #pragma unroll
        for (int d = 0; d < 12; ++d) acc[d][q] *= al;
      }
    }
    float pv16[2][4], sum[4];
    #pragma unroll
    for (int q = 0; q < 4; ++q) sum[q] = 0.f;
    #pragma unroll
    for (int st = 0; st < 2; ++st)
      #pragma unroll
      for (int q = 0; q < 4; ++q) {
        float p = __expf(S[st][q] - mrun[q]);
        sum[q] += p;
        pv16[st][q] = p;
      }
    #pragma unroll
    for (int off = 8; off >= 1; off >>= 1)
      #pragma unroll
      for (int q = 0; q < 4; ++q) sum[q] += __shfl_xor(sum[q], off);
    #pragma unroll
    for (int q = 0; q < 4; ++q) lrun[q] += sum[q];

    // Ps repack (wave-private rows; same-wave write->read)
    #pragma unroll
    for (int st = 0; st < 2; ++st)
      #pragma unroll
      for (int q = 0; q < 4; ++q)
        lds[24576 + (w * 16 + 4 * g + q) * 34 + st * 16 + c15] = (_Float16)pv16[st][q];

    __syncthreads();  // B: R/K reads of chunk c done; KV prefetch drained

    // stage 32 new ring rows (for chunk c+1's band); prologue covered c=0,1
    if (c >= 1 && c < 47) STAGE_R_INC(cc32 + 96);

    // ---- PV: P[16][32] @ V^T fragments ----
    f16x8 pf = *(const f16x8*)(&lds[24576 + (w * 16 + c15) * 34 + g * 8]);
    __builtin_amdgcn_s_setprio(1);
    #pragma unroll
    for (int d = 0; d < 12; ++d) {
      int rowV = d * 16 + c15;
      f16x8 vf = *(const f16x8*)(&lds[VB + rowV * 32 + (g ^ vsz) * 8]);
      acc[d] = MFMAH(pf, vf, acc[d]);
    }
    __builtin_amdgcn_s_setprio(0);
  }

  // ---- epilogue: out = acc / l -> f16 plane ----
  float rinv[4];
  #pragma unroll
  for (int q = 0; q < 4; ++q) rinv[q] = 1.0f / lrun[q];
  #pragma unroll
  for (int d = 0; d < 12; ++d) {
    int col = h * 192 + d * 16 + c15;
    #pragma unroll
    for (int q = 0; q < 4; ++q) {
      size_t row = (size_t)(b * SEQN + qrow0 + 4 * g + q);
      ao[row * 1536 + col] = (_Float16)(acc[d][q] * rinv[q]);
    }
  }
  #undef STAGE_KV
  #undef STAGE_R_PRO
  #undef STAGE_R_INC
  #undef COMP_T
}

extern "C" void kernel_launch(void* const* d_in, const int* in_sizes, int n_in,
                              void* d_out, int out_size, void* d_ws, size_t ws_size,
                              hipStream_t stream) {
  (void)in_sizes; (void)n_in; (void)out_size; (void)ws_size;
  const float* x   = (const float*)d_in[0];
  const float* g1  = (const float*)d_in[1];
  const float* be1 = (const float*)d_in[2];
  const float* Wq  = (const float*)d_in[3];
  const float* Wk  = (const float*)d_in[4];
  const float* Wv  = (const float*)d_in[5];
  const float* Wo  = (const float*)d_in[6];
  const float* bo  = (const float*)d_in[7];
  const float* Wrk = (const float*)d_in[8];
  const float* cb  = (const float*)d_in[9];
  const float* pb  = (const float*)d_in[10];
  const float* g2  = (const float*)d_in[11];
  const float* be2 = (const float*)d_in[12];
  const float* W1  = (const float*)d_in[13];
  const float* b1  = (const float*)d_in[14];
  const float* W2  = (const float*)d_in[15];
  const float* b2  = (const float*)d_in[16];
  float* out = (float*)d_out;

  char* B = (char*)d_ws;
  float* pos     = (float*)(B + 0);             //  2,359,296
  _Float16* rk   = (_Float16*)(B + 2359296);    //  3,145,728 (3072 rows x 512)
  float* PRb     = (float*)(B + 5505024);       //     98,304
  float* CKb     = (float*)(B + 5603328);       //    196,608
  _Float16* xn   = (_Float16*)(B + 5799936);    // 18,874,368
  _Float16* Wb   = (_Float16*)(B + 24674304);   //  9,437,184 (max weight plane)
  _Float16* Qp   = (_Float16*)(B + 34111488);   //  6,291,456
  _Float16* Kp   = (_Float16*)(B + 40402944);   //  6,291,456
  _Float16* Vtp  = (_Float16*)(B + 46694400);   // 18,874,368
  _Float16* ao   = (_Float16*)(B + 65568768);   // 18,874,368
  float* x2      = (float*)(B + 84443136);      // 37,748,736
  _Float16* h1   = (_Float16*)(B + 122191872);  // 37,748,736 -> ends 159,940,608

  pos_embed_kernel<<<NDIST, 64, 0, stream>>>(pos);
  relk_kernel<<<192, 512, 0, stream>>>(pos, Wrk, pb, rk, PRb);
  ln_kernel<<<MROWS, 256, 0, stream>>>(x, g1, be1, xn);
  // fused QKV weights (transposed); fold 0.125 scale into Wq
  convw_kernel<<<dim3(16, 48), 256, 0, stream>>>(Wq, Wb, 512, 1536, 1536, 0, 0.125f);
  convw_kernel<<<dim3(16, 48), 256, 0, stream>>>(Wk, Wb, 512, 1536, 1536, 512, 1.0f);
  convw_kernel<<<dim3(48, 48), 256, 0, stream>>>(Wv, Wb, 1536, 1536, 1536, 1024, 1.0f);
  mgemm_kernel<4, 4><<<960, 256, 0, stream>>>(
      xn, Wb, nullptr, Qp, Kp, Vtp, nullptr, nullptr, MROWS, 2560, 1536);
  ck_kernel<<<MROWS * 2, 256, 0, stream>>>(Kp, cb, CKb);
  attn_kernel<<<768, 256, 0, stream>>>(Qp, Kp, Vtp, rk, PRb, CKb, ao);
  convw_kernel<<<dim3(48, 48), 256, 0, stream>>>(Wo, Wb, 1536, 1536, 1536, 0, 1.0f);
  mgemm_kernel<3, 3><<<768, 256, 0, stream>>>(
      ao, Wb, x2, nullptr, nullptr, nullptr, bo, x, MROWS, 1536, 1536);
  ln_kernel<<<MROWS, 256, 0, stream>>>(x2, g2, be2, xn);
  convw_kernel<<<dim3(96, 48), 256, 0, stream>>>(W1, Wb, 3072, 1536, 1536, 0, 1.0f);
  mgemm_kernel<2, 4><<<1152, 256, 0, stream>>>(
      xn, Wb, nullptr, h1, nullptr, nullptr, b1, nullptr, MROWS, 3072, 1536);
  convw_kernel<<<dim3(48, 96), 256, 0, stream>>>(W2, Wb, 1536, 3072, 3072, 0, 1.0f);
  mgemm_kernel<3, 3><<<768, 256, 0, stream>>>(
      h1, Wb, out, nullptr, nullptr, nullptr, b2, x2, MROWS, 1536, 3072);
}

// Round 14
// 427.050 us; speedup vs baseline: 8.9460x; 1.0842x over previous
//
#include <hip/hip_runtime.h>
#include <hip/hip_bf16.h>
#include <math.h>

#define SEQN 1536
#define NH 8
#define MROWS 6144      // BATCH*SEQ
#define NDIST 3071      // 2*SEQ-1

typedef __attribute__((ext_vector_type(8))) _Float16 f16x8;
typedef __attribute__((ext_vector_type(4))) _Float16 f16x4;
typedef __attribute__((ext_vector_type(4))) float f32x4;

#define MFMAH(a, b, c) __builtin_amdgcn_mfma_f32_16x16x32_f16(a, b, c, 0, 0, 0)

__device__ __forceinline__ void gl_lds16(const void* g, void* l) {
  __builtin_amdgcn_global_load_lds(
      (const __attribute__((address_space(1))) void*)g,
      (__attribute__((address_space(3))) void*)l, 16, 0, 0);
}

// ---------------- positional embedding table: pos[3071][192] ----------------
__global__ __launch_bounds__(64) void pos_embed_kernel(float* __restrict__ pos) {
  int row = blockIdx.x;
  int j = threadIdx.x;
  if (j >= 32) return;
  float dist = (float)(row - (SEQN - 1));
  float adist = fabsf(dist);
  float sgn = (dist > 0.f) ? 1.f : (dist < 0.f ? -1.f : 0.f);

  const float max_range = 10.58496250072116f;  // log2(1536)
  float hl = exp2f(3.0f + ((max_range - 3.0f) / 31.0f) * (float)j);
  float e_exp = expf(-0.6931471805599453f / hl * adist);

  float cw = exp2f((float)(j + 1)) - 1.0f;
  float e_cm = (cw > adist) ? 1.0f : 0.0f;

  float mean = 48.0f * (float)(j + 1);
  float tt = mean / 24.0f;
  float conc = tt * tt;
  float rate = mean / 576.0f;
  float log_unnorm = (conc - 1.0f) * logf(fmaxf(adist, 1e-20f)) - rate * adist;
  float log_norm = lgammaf(conc) - conc * logf(rate);
  float prob = expf(log_unnorm - log_norm) + 1e-8f;
  float mx = prob;
  #pragma unroll
  for (int off = 16; off >= 1; off >>= 1)
    mx = fmaxf(mx, __shfl_xor(mx, off, 32));
  float e_g = prob / mx;

  float* o = pos + (size_t)row * 192;
  o[j] = e_exp;        o[32 + j] = e_cm;        o[64 + j] = e_g;
  o[96 + j] = sgn * e_exp; o[128 + j] = sgn * e_cm; o[160 + j] = sgn * e_g;
}

// ------------- rel_k = pos @ Wrk -> f16 [3072 rows][512]; PR[h][d] -------------
// Tiled: each block owns 16 d-rows; Wrk streamed once per block (192 blocks).
__global__ __launch_bounds__(512) void relk_kernel(
    const float* __restrict__ pos, const float* __restrict__ Wrk,
    const float* __restrict__ pb, _Float16* __restrict__ rk, float* __restrict__ PR) {
  __shared__ float prow[16][192];
  const int d0 = blockIdx.x * 16;
  const int t = threadIdx.x;
  #pragma unroll
  for (int p = 0; p < 6; ++p) {
    int idx = t + p * 512;
    int r = idx / 192, c = idx - r * 192;
    prow[r][c] = pos[(size_t)(d0 + r) * 192 + c];
  }
  __syncthreads();
  float acc[16];
  #pragma unroll
  for (int r = 0; r < 16; ++r) acc[r] = 0.f;
  #pragma unroll 4
  for (int kk = 0; kk < 192; ++kk) {
    float wv = Wrk[(size_t)kk * 512 + t];
    #pragma unroll
    for (int r = 0; r < 16; ++r) acc[r] = fmaf(prow[r][kk], wv, acc[r]);
  }
  #pragma unroll
  for (int r = 0; r < 16; ++r)
    rk[(size_t)(d0 + r) * 512 + t] = (_Float16)acc[r];
  float pbv = pb[t];
  #pragma unroll
  for (int r = 0; r < 16; ++r) {
    float pv = pbv * acc[r];
    #pragma unroll
    for (int off = 32; off >= 1; off >>= 1) pv += __shfl_xor(pv, off);
    if ((t & 63) == 0 && (d0 + r) < NDIST)
      PR[(size_t)(t >> 6) * NDIST + d0 + r] = pv;
  }
}

// ------------- CK[row][h] = cb_h . k[row,h,:] from f16 K plane -------------
__global__ __launch_bounds__(256) void ck_kernel(
    const _Float16* __restrict__ Kp, const float* __restrict__ cb,
    float* __restrict__ CK) {
  const int gid = blockIdx.x * 4 + (threadIdx.x >> 6);
  const int lane = threadIdx.x & 63;
  const int row = gid >> 3;
  const int h = gid & 7;
  float kv = (float)Kp[(size_t)row * 512 + h * 64 + lane];
  float pv = cb[h * 64 + lane] * kv;
  #pragma unroll
  for (int off = 32; off >= 1; off >>= 1) pv += __shfl_xor(pv, off);
  if (lane == 0) CK[(size_t)row * 8 + h] = pv;
}

// ------------- layernorm: fp32 in -> f16 plane out -------------
__global__ __launch_bounds__(256) void ln_kernel(
    const float* __restrict__ x, const float* __restrict__ g,
    const float* __restrict__ bta, _Float16* __restrict__ oh) {
  const int row = blockIdx.x;
  const int t = threadIdx.x;
  __shared__ float red[4];
  __shared__ float bc[2];
  const float4* xr = (const float4*)(x + (size_t)row * 1536);
  float4 v0 = xr[t];
  float4 v1 = make_float4(0.f, 0.f, 0.f, 0.f);
  if (t < 128) v1 = xr[256 + t];
  float s = v0.x + v0.y + v0.z + v0.w;
  if (t < 128) s += v1.x + v1.y + v1.z + v1.w;
  #pragma unroll
  for (int off = 32; off >= 1; off >>= 1) s += __shfl_xor(s, off);
  if ((t & 63) == 0) red[t >> 6] = s;
  __syncthreads();
  if (t == 0) bc[0] = (red[0] + red[1] + red[2] + red[3]) * (1.f / 1536.f);
  __syncthreads();
  const float mu = bc[0];
  float d, s2 = 0.f;
  d = v0.x - mu; s2 += d * d; d = v0.y - mu; s2 += d * d;
  d = v0.z - mu; s2 += d * d; d = v0.w - mu; s2 += d * d;
  if (t < 128) {
    d = v1.x - mu; s2 += d * d; d = v1.y - mu; s2 += d * d;
    d = v1.z - mu; s2 += d * d; d = v1.w - mu; s2 += d * d;
  }
  #pragma unroll
  for (int off = 32; off >= 1; off >>= 1) s2 += __shfl_xor(s2, off);
  if ((t & 63) == 0) red[t >> 6] = s2;
  __syncthreads();
  if (t == 0) bc[1] = (red[0] + red[1] + red[2] + red[3]) * (1.f / 1536.f);
  __syncthreads();
  const float inv = rsqrtf(bc[1] + 1e-5f);
  const float4* g4 = (const float4*)g;
  const float4* b4 = (const float4*)bta;
  float4 gg = g4[t], bb = b4[t];
  f16x4 hv;
  hv[0] = (_Float16)((v0.x - mu) * inv * gg.x + bb.x);
  hv[1] = (_Float16)((v0.y - mu) * inv * gg.y + bb.y);
  hv[2] = (_Float16)((v0.z - mu) * inv * gg.z + bb.z);
  hv[3] = (_Float16)((v0.w - mu) * inv * gg.w + bb.w);
  *(f16x4*)(oh + (size_t)row * 1536 + t * 4) = hv;
  if (t < 128) {
    gg = g4[256 + t]; bb = b4[256 + t];
    hv[0] = (_Float16)((v1.x - mu) * inv * gg.x + bb.x);
    hv[1] = (_Float16)((v1.y - mu) * inv * gg.y + bb.y);
    hv[2] = (_Float16)((v1.z - mu) * inv * gg.z + bb.z);
    hv[3] = (_Float16)((v1.w - mu) * inv * gg.w + bb.w);
    *(f16x4*)(oh + (size_t)row * 1536 + 1024 + t * 4) = hv;
  }
}

// ------------- weight convert + transpose: W[K][N] fp32 -> T[roff+N][KD] f16 -------------
__global__ __launch_bounds__(256) void convw_kernel(
    const float* __restrict__ W, _Float16* __restrict__ Th,
    int N, int K, int KD, int roff, float scale) {
  __shared__ float tile[32][33];
  const int n0 = blockIdx.x * 32, k0 = blockIdx.y * 32;
  const int t = threadIdx.x;
  const int cr = t >> 5;
  const int cc = t & 31;
  #pragma unroll
  for (int p = 0; p < 4; ++p) {
    int r = cr + p * 8;
    tile[r][cc] = W[(size_t)(k0 + r) * N + n0 + cc];
  }
  __syncthreads();
  #pragma unroll
  for (int p = 0; p < 4; ++p) {
    int r = cr + p * 8;                    // local n
    float v = tile[cc][r] * scale;         // W[k0+cc][n0+r]
    Th[(size_t)(roff + n0 + r) * KD + k0 + cc] = (_Float16)v;
  }
}

// ------------- fp16 MFMA GEMM, 128xBN tile, BK=64 -------------
// 1D grid, XCD y-slab swizzle; 8-slot XOR LDS swizzle via pre-swizzled global
// source + swizzled fragment reads. BNJ j-tiles/wave: 3->BN=96, 4->128, 6->192.
// MW = min waves per EU for launch_bounds (occupancy/VGPR tradeoff).
// EPI: 2 = bias+relu -> f16 plane; 3 = bias+residual -> fp32;
//      4 = QKV epilogue: Q/K f16 planes + V^T f16 plane
template <int EPI, int BNJ, int MW>
__global__ __launch_bounds__(256, MW) void mgemm_kernel(
    const _Float16* __restrict__ A, const _Float16* __restrict__ B,
    float* __restrict__ C, _Float16* __restrict__ Ch,
    _Float16* __restrict__ Kp, _Float16* __restrict__ Vt,
    const float* __restrict__ bias, const float* __restrict__ res,
    int M, int N, int K) {
  constexpr int BN = BNJ * 32;                 // 96 / 128 / 192
  __shared__ _Float16 sm[8192 + BN * 64];      // A[128][64] @0, B[BN][64] @8192
  const int t = threadIdx.x;
  const int lane = t & 63;
  const int w = t >> 6;
  const int wm = w >> 1, wn = w & 1;
  const int slab = (M >> 7) >> 3;              // row-tiles per XCD (6 for M=6144)
  const int xcd = blockIdx.x & 7;
  const int r = blockIdx.x >> 3;
  const int yt = xcd * slab + (r % slab);
  const int xt = r / slab;
  const int m0 = yt * 128, n0 = xt * BN;

  f32x4 acc[4][BNJ];
  #pragma unroll
  for (int i = 0; i < 4; ++i)
    #pragma unroll
    for (int j = 0; j < BNJ; ++j) acc[i][j] = (f32x4){0.f, 0.f, 0.f, 0.f};

  const int srow = t >> 3;
  const int ssl = t & 7;
  const int ss = ssl ^ (srow & 7);
  const int lr = lane & 15;
  const int g = lane >> 4;
  const int kb = lr & 7;                       // fragment-row swizzle key

  for (int k0 = 0; k0 < K; k0 += 64) {
    #pragma unroll
    for (int p = 0; p < 4; ++p) {
      int row = srow + p * 32;
      gl_lds16(A + (size_t)(m0 + row) * K + k0 + ss * 8, &sm[row * 64 + ssl * 8]);
    }
    #pragma unroll
    for (int p = 0; p < BN / 32; ++p) {
      int row = srow + p * 32;
      gl_lds16(B + (size_t)(n0 + row) * K + k0 + ss * 8,
               &sm[8192 + row * 64 + ssl * 8]);
    }
    __syncthreads();
    #pragma unroll
    for (int h2 = 0; h2 < 2; ++h2) {
      const int ksl = ((h2 * 4 + g) ^ kb) * 8;
      f16x8 a[4], b[BNJ];
      #pragma unroll
      for (int i = 0; i < 4; ++i)
        a[i] = *(const f16x8*)(&sm[(wm * 64 + i * 16 + lr) * 64 + ksl]);
      #pragma unroll
      for (int j = 0; j < BNJ; ++j)
        b[j] = *(const f16x8*)(&sm[8192 + (wn * BNJ * 16 + j * 16 + lr) * 64 + ksl]);
      #pragma unroll
      for (int i = 0; i < 4; ++i)
        #pragma unroll
        for (int j = 0; j < BNJ; ++j)
          acc[i][j] = MFMAH(a[i], b[j], acc[i][j]);
    }
    __syncthreads();
  }

  const int lq = lane >> 4;
  #pragma unroll
  for (int i = 0; i < 4; ++i) {
    #pragma unroll
    for (int j = 0; j < BNJ; ++j) {
      const int c0 = n0 + wn * BNJ * 16 + j * 16;   // tile col base (uniform)
      const int col = c0 + lr;
      const int rbase = m0 + wm * 64 + i * 16 + lq * 4;
      if (EPI == 3) {
        #pragma unroll
        for (int q = 0; q < 4; ++q) {
          size_t o = (size_t)(rbase + q) * N + col;
          C[o] = acc[i][j][q] + bias[col] + res[o];
        }
      } else if (EPI == 2) {
        #pragma unroll
        for (int q = 0; q < 4; ++q) {
          size_t o = (size_t)(rbase + q) * N + col;
          Ch[o] = (_Float16)fmaxf(acc[i][j][q] + bias[col], 0.f);
        }
      } else {  // EPI == 4: QKV split epilogue
        if (c0 < 512) {
          #pragma unroll
          for (int q = 0; q < 4; ++q)
            Ch[(size_t)(rbase + q) * 512 + col] = (_Float16)acc[i][j][q];
        } else if (c0 < 1024) {
          #pragma unroll
          for (int q = 0; q < 4; ++q)
            Kp[(size_t)(rbase + q) * 512 + (col - 512)] = (_Float16)acc[i][j][q];
        } else {
          int dv = col - 1024;
          int hd = dv / 192;
          int dvh = dv - hd * 192;
          int bb = rbase / 1536;
          int nloc = rbase - bb * 1536;
          f16x4 pk;
          pk[0] = (_Float16)acc[i][j][0];
          pk[1] = (_Float16)acc[i][j][1];
          pk[2] = (_Float16)acc[i][j][2];
          pk[3] = (_Float16)acc[i][j][3];
          *(f16x4*)(Vt + (((size_t)bb * 8 + hd) * 192 + dvh) * 1536 + nloc) = pk;
        }
      }
    }
  }
}

// ------------- MFMA flash attention (fp16): chunk 32, ring-R, 1 barrier/chunk -------------
// 256 threads / 4 waves; block = 64 Q rows; 48 chunks of 32 j.
// LDS (f16): K dbuf [2][32][64] @0; V^T dbuf [2][192][32] @4096;
//   R ring [128][64] @16384 (advances 32 rows/chunk); Ps [64][34] @24576.
// Single barrier per chunk: ring INC writes exactly the 32-slot complement of
// the current chunk's 96-slot read band (WAR vs chunk c-1 protected by A(c));
// all prefetches drain at the vmcnt(0) before A(c+1). Row-sums via ones-MFMA
// into acc[12] (replaces the shuffle-tree denominator reduce).
__global__ __launch_bounds__(256, 3) void attn_kernel(
    const _Float16* __restrict__ Qp, const _Float16* __restrict__ Kp,
    const _Float16* __restrict__ Vt, const _Float16* __restrict__ rk,
    const float* __restrict__ PR, const float* __restrict__ CK,
    _Float16* __restrict__ ao) {
  __shared__ _Float16 lds[26752];
  const int id = blockIdx.x;
  const int xcd = id & 7, s = id >> 3;    // XCD-chunked (b,h) mapping
  const int bh = xcd * 4 + s / 24;
  const int it = s % 24;
  const int b = bh >> 3, h = bh & 7;
  const int t = threadIdx.x;
  const int w = t >> 6;
  const int lane = t & 63;
  const int c15 = lane & 15, g = lane >> 4;
  const int swz = c15 & 7;                // K/R read swizzle (row&7 == c15&7)
  const int vsz = (c15 >> 1) & 3;         // V read swizzle ((row>>1)&3)
  const int qrow0 = it * 64 + w * 16;     // wave's 16 Q rows
  const int rrow0 = 48 - w * 16;          // wave's band offset within window
  const int R0 = 1472 - it * 64;          // absolute rel_k row of ring origin

  // staging lane geometry
  const int lr = lane >> 3, sl = lane & 7;
  const int ss = sl ^ lr;                           // K/R source slot
  const int ss2 = (lane & 3) ^ ((lane >> 3) & 3);   // V source slot

  // persistent Q fragment (A-operand: lane holds row c15, k = g*8..+8, 32+g*8..+8)
  f16x8 qh0, qh1;
  {
    size_t qo = ((size_t)(b * SEQN + qrow0 + c15)) * 512 + h * 64 + g * 8;
    qh0 = *(const f16x8*)(Qp + qo);
    qh1 = *(const f16x8*)(Qp + qo + 32);
  }
  f16x8 ones;
  #pragma unroll
  for (int i = 0; i < 8; ++i) ones[i] = (_Float16)1.0f;
  const float* PRrow = PR + (size_t)h * NDIST;
  const float* CKb2 = CK + (size_t)b * SEQN * 8 + h;

  f32x4 acc[13];                          // [12] = row-sum (softmax denominator)
  #pragma unroll
  for (int d = 0; d < 13; ++d) acc[d] = (f32x4){0.f, 0.f, 0.f, 0.f};
  float mrun[4];
  #pragma unroll
  for (int q = 0; q < 4; ++q) mrun[q] = -1e30f;

  #define STAGE_KV(J0, KB, VB)                                                   \
    do {                                                                         \
      size_t gk = ((size_t)(b * SEQN + (J0) + w * 8 + lr)) * 512 + h * 64 + ss * 8; \
      gl_lds16(Kp + gk, &lds[(KB) + w * 512]);                                   \
      _Pragma("unroll") for (int p = 0; p < 3; ++p) {                            \
        int rv = w * 48 + p * 16 + (lane >> 2);                                  \
        size_t gv = (((size_t)(b * 8 + h)) * 192 + rv) * SEQN + (J0) + ss2 * 8;  \
        gl_lds16(Vt + gv, &lds[(VB) + (w * 48 + p * 16) * 32]);                  \
      }                                                                          \
    } while (0)

  // prologue: full 128-row ring fill (rel rows 0..127)
  #define STAGE_R_PRO()                                                          \
    do {                                                                         \
      _Pragma("unroll") for (int p = 0; p < 4; ++p) {                            \
        int rr = w * 32 + p * 8 + lr;                                            \
        size_t gr = ((size_t)(R0 + rr)) * 512 + h * 64 + ss * 8;                 \
        gl_lds16(rk + gr, &lds[16384 + (w * 32 + p * 8) * 64]);                  \
      }                                                                          \
    } while (0)

  // incremental: stage 32 new rows rel [REL0, REL0+32) into ring
  #define STAGE_R_INC(REL0)                                                      \
    do {                                                                         \
      int rr = (REL0) + w * 8 + lr;                                              \
      size_t gr = ((size_t)(R0 + rr)) * 512 + h * 64 + ss * 8;                   \
      gl_lds16(rk + gr, &lds[16384 + ((((REL0) + w * 8) & 127)) * 64]);          \
    } while (0)

  // compute one T tile at band offset ETOFF (ring read + PR add)
  #define COMP_T(DST, ETOFF)                                                     \
    do {                                                                         \
      int relrow = (cc32 + rrow0 + (ETOFF) + c15) & 127;                         \
      f16x8 r0_ = *(const f16x8*)(&lds[16384 + relrow * 64 + (g ^ swz) * 8]);    \
      f16x8 r1_ = *(const f16x8*)(&lds[16384 + relrow * 64 + ((4 + g) ^ swz) * 8]); \
      f32x4 tt_ = (f32x4){0.f, 0.f, 0.f, 0.f};                                   \
      tt_ = MFMAH(qh0, r0_, tt_);                                                \
      tt_ = MFMAH(qh1, r1_, tt_);                                                \
      float prv_ = PRrow[dbase + (ETOFF) + c15];                                 \
      _Pragma("unroll") for (int q = 0; q < 4; ++q) tt_[q] += prv_;              \
      DST = tt_;                                                                 \
    } while (0)

  STAGE_KV(0, 0, 4096);
  STAGE_R_PRO();

  f32x4 T0, T1, T2;

  for (int c = 0; c < 48; ++c) {
    const int j0 = c * 32;
    const int cc32 = c * 32;
    const int cur = c & 1;
    const int KB = cur * 2048;
    const int VB = 4096 + cur * 6144;
    __syncthreads();  // A: staged data for chunk c visible; prior reads complete

    // prefetch next chunk's K/V + ring rows (all drain by next A)
    if (c < 47) {
      STAGE_KV(j0 + 32, (cur ^ 1) * 2048, 4096 + (cur ^ 1) * 6144);
      if (c >= 1) STAGE_R_INC(cc32 + 96);
    }

    const int dbase = 1520 + j0 - qrow0;
    // ---- T tiles: carry T0 from previous chunk's T2; compute T1, T2 ----
    __builtin_amdgcn_s_setprio(1);
    if (c == 0) {
      COMP_T(T0, 0);
    } else {
      T0 = T2;
    }
    COMP_T(T1, 16);
    COMP_T(T2, 32);
    // ---- S = Q @ K^T ----
    f32x4 S[2];
    #pragma unroll
    for (int st = 0; st < 2; ++st) {
      int rowK = st * 16 + c15;
      f16x8 kh0 = *(const f16x8*)(&lds[KB + rowK * 64 + (g ^ swz) * 8]);
      f16x8 kh1 = *(const f16x8*)(&lds[KB + rowK * 64 + ((4 + g) ^ swz) * 8]);
      f32x4 ssv = (f32x4){0.f, 0.f, 0.f, 0.f};
      ssv = MFMAH(qh0, kh0, ssv);
      ssv = MFMAH(qh1, kh1, ssv);
      S[st] = ssv;
    }
    __builtin_amdgcn_s_setprio(0);
    // ---- add CK + gathered rel logits (12 shuffles) ----
    float ck0 = CKb2[(size_t)(j0 + c15) * 8];
    float ck1 = CKb2[(size_t)(j0 + 16 + c15) * 8];
    #pragma unroll
    for (int q = 0; q < 4; ++q) {
      int eoff = c15 + 15 - 4 * g - q;     // in [0,30]
      int src = (lane & 48) | (eoff & 15);
      float t0v = __shfl(T0[q], src);
      float t1v = __shfl(T1[q], src);
      float t2v = __shfl(T2[q], src);
      bool lo = eoff < 16;
      S[0][q] += ck0 + (lo ? t0v : t1v);
      S[1][q] += ck1 + (lo ? t1v : t2v);
    }
    // ---- online softmax with lazy defer-max (T13: __any test on raw S) ----
    int need = 0;
    #pragma unroll
    for (int st = 0; st < 2; ++st)
      #pragma unroll
      for (int q = 0; q < 4; ++q) need |= (S[st][q] > mrun[q] + 8.0f) ? 1 : 0;
    if (__any(need)) {
      float mx[4];
      #pragma unroll
      for (int q = 0; q < 4; ++q) mx[q] = fmaxf(S[0][q], S[1][q]);
      #pragma unroll
      for (int off = 8; off >= 1; off >>= 1)
        #pragma unroll
        for (int q = 0; q < 4; ++q) mx[q] = fmaxf(mx[q], __shfl_xor(mx[q], off));
      #pragma unroll
      for (int q = 0; q < 4; ++q) {
        float mn = fmaxf(mrun[q], mx[q]);
        float al = __expf(mrun[q] - mn);
        mrun[q] = mn;
        #pragma unroll
        for (int d = 0; d < 13; ++d) acc[d][q] *= al;
      }
    }
    // ---- P = exp(S - m); Ps repack (wave-private; same-wave write->read) ----
    #pragma unroll
    for (int st = 0; st < 2; ++st)
      #pragma unroll
      for (int q = 0; q < 4; ++q)
        lds[24576 + (w * 16 + 4 * g + q) * 34 + st * 16 + c15] =
            (_Float16)__expf(S[st][q] - mrun[q]);

    // ---- PV: P[16][32] @ V^T fragments; ones-MFMA accumulates row sums ----
    f16x8 pf = *(const f16x8*)(&lds[24576 + (w * 16 + c15) * 34 + g * 8]);
    __builtin_amdgcn_s_setprio(1);
    #pragma unroll
    for (int d = 0; d < 12; ++d) {
      int rowV = d * 16 + c15;
      f16x8 vf = *(const f16x8*)(&lds[VB + rowV * 32 + (g ^ vsz) * 8]);
      acc[d] = MFMAH(pf, vf, acc[d]);
    }
    acc[12] = MFMAH(pf, ones, acc[12]);
    __builtin_amdgcn_s_setprio(0);
  }

  // ---- epilogue: out = acc / rowsum -> f16 plane ----
  float rinv[4];
  #pragma unroll
  for (int q = 0; q < 4; ++q) rinv[q] = 1.0f / acc[12][q];
  #pragma unroll
  for (int d = 0; d < 12; ++d) {
    int col = h * 192 + d * 16 + c15;
    #pragma unroll
    for (int q = 0; q < 4; ++q) {
      size_t row = (size_t)(b * SEQN + qrow0 + 4 * g + q);
      ao[row * 1536 + col] = (_Float16)(acc[d][q] * rinv[q]);
    }
  }
  #undef STAGE_KV
  #undef STAGE_R_PRO
  #undef STAGE_R_INC
  #undef COMP_T
}

extern "C" void kernel_launch(void* const* d_in, const int* in_sizes, int n_in,
                              void* d_out, int out_size, void* d_ws, size_t ws_size,
                              hipStream_t stream) {
  (void)in_sizes; (void)n_in; (void)out_size; (void)ws_size;
  const float* x   = (const float*)d_in[0];
  const float* g1  = (const float*)d_in[1];
  const float* be1 = (const float*)d_in[2];
  const float* Wq  = (const float*)d_in[3];
  const float* Wk  = (const float*)d_in[4];
  const float* Wv  = (const float*)d_in[5];
  const float* Wo  = (const float*)d_in[6];
  const float* bo  = (const float*)d_in[7];
  const float* Wrk = (const float*)d_in[8];
  const float* cb  = (const float*)d_in[9];
  const float* pb  = (const float*)d_in[10];
  const float* g2  = (const float*)d_in[11];
  const float* be2 = (const float*)d_in[12];
  const float* W1  = (const float*)d_in[13];
  const float* b1  = (const float*)d_in[14];
  const float* W2  = (const float*)d_in[15];
  const float* b2  = (const float*)d_in[16];
  float* out = (float*)d_out;

  char* B = (char*)d_ws;
  float* pos     = (float*)(B + 0);             //  2,359,296
  _Float16* rk   = (_Float16*)(B + 2359296);    //  3,145,728 (3072 rows x 512)
  float* PRb     = (float*)(B + 5505024);       //     98,304
  float* CKb     = (float*)(B + 5603328);       //    196,608
  _Float16* xn   = (_Float16*)(B + 5799936);    // 18,874,368
  _Float16* Wb   = (_Float16*)(B + 24674304);   //  9,437,184 (max weight plane)
  _Float16* Qp   = (_Float16*)(B + 34111488);   //  6,291,456
  _Float16* Kp   = (_Float16*)(B + 40402944);   //  6,291,456
  _Float16* Vtp  = (_Float16*)(B + 46694400);   // 18,874,368
  _Float16* ao   = (_Float16*)(B + 65568768);   // 18,874,368
  float* x2      = (float*)(B + 84443136);      // 37,748,736
  _Float16* h1   = (_Float16*)(B + 122191872);  // 37,748,736 -> ends 159,940,608

  pos_embed_kernel<<<NDIST, 64, 0, stream>>>(pos);
  relk_kernel<<<192, 512, 0, stream>>>(pos, Wrk, pb, rk, PRb);
  ln_kernel<<<MROWS, 256, 0, stream>>>(x, g1, be1, xn);
  // fused QKV weights (transposed); fold 0.125 scale into Wq
  convw_kernel<<<dim3(16, 48), 256, 0, stream>>>(Wq, Wb, 512, 1536, 1536, 0, 0.125f);
  convw_kernel<<<dim3(16, 48), 256, 0, stream>>>(Wk, Wb, 512, 1536, 1536, 512, 1.0f);
  convw_kernel<<<dim3(48, 48), 256, 0, stream>>>(Wv, Wb, 1536, 1536, 1536, 1024, 1.0f);
  mgemm_kernel<4, 4, 4><<<960, 256, 0, stream>>>(
      xn, Wb, nullptr, Qp, Kp, Vtp, nullptr, nullptr, MROWS, 2560, 1536);
  ck_kernel<<<MROWS * 2, 256, 0, stream>>>(Kp, cb, CKb);
  attn_kernel<<<768, 256, 0, stream>>>(Qp, Kp, Vtp, rk, PRb, CKb, ao);
  convw_kernel<<<dim3(48, 48), 256, 0, stream>>>(Wo, Wb, 1536, 1536, 1536, 0, 1.0f);
  mgemm_kernel<3, 3, 4><<<768, 256, 0, stream>>>(
      ao, Wb, x2, nullptr, nullptr, nullptr, bo, x, MROWS, 1536, 1536);
  ln_kernel<<<MROWS, 256, 0, stream>>>(x2, g2, be2, xn);
  convw_kernel<<<dim3(96, 48), 256, 0, stream>>>(W1, Wb, 3072, 1536, 1536, 0, 1.0f);
  mgemm_kernel<2, 6, 3><<<768, 256, 0, stream>>>(
      xn, Wb, nullptr, h1, nullptr, nullptr, b1, nullptr, MROWS, 3072, 1536);
  convw_kernel<<<dim3(48, 96), 256, 0, stream>>>(W2, Wb, 1536, 3072, 3072, 0, 1.0f);
  mgemm_kernel<3, 3, 4><<<768, 256, 0, stream>>>(
      h1, Wb, out, nullptr, nullptr, nullptr, b2, x2, MROWS, 1536, 3072);
}

// Round 15
// 420.230 us; speedup vs baseline: 9.0912x; 1.0162x over previous
//
#include <hip/hip_runtime.h>
#include <hip/hip_bf16.h>
#include <math.h>

#define SEQN 1536
#define NH 8
#define MROWS 6144      // BATCH*SEQ
#define NDIST 3071      // 2*SEQ-1

typedef __attribute__((ext_vector_type(8))) _Float16 f16x8;
typedef __attribute__((ext_vector_type(4))) _Float16 f16x4;
typedef __attribute__((ext_vector_type(4))) float f32x4;

#define MFMAH(a, b, c) __builtin_amdgcn_mfma_f32_16x16x32_f16(a, b, c, 0, 0, 0)

__device__ __forceinline__ void gl_lds16(const void* g, void* l) {
  __builtin_amdgcn_global_load_lds(
      (const __attribute__((address_space(1))) void*)g,
      (__attribute__((address_space(3))) void*)l, 16, 0, 0);
}

// ---------------- positional embedding table: pos[3071][192] ----------------
__global__ __launch_bounds__(64) void pos_embed_kernel(float* __restrict__ pos) {
  int row = blockIdx.x;
  int j = threadIdx.x;
  if (j >= 32) return;
  float dist = (float)(row - (SEQN - 1));
  float adist = fabsf(dist);
  float sgn = (dist > 0.f) ? 1.f : (dist < 0.f ? -1.f : 0.f);

  const float max_range = 10.58496250072116f;  // log2(1536)
  float hl = exp2f(3.0f + ((max_range - 3.0f) / 31.0f) * (float)j);
  float e_exp = expf(-0.6931471805599453f / hl * adist);

  float cw = exp2f((float)(j + 1)) - 1.0f;
  float e_cm = (cw > adist) ? 1.0f : 0.0f;

  float mean = 48.0f * (float)(j + 1);
  float tt = mean / 24.0f;
  float conc = tt * tt;
  float rate = mean / 576.0f;
  float log_unnorm = (conc - 1.0f) * logf(fmaxf(adist, 1e-20f)) - rate * adist;
  float log_norm = lgammaf(conc) - conc * logf(rate);
  float prob = expf(log_unnorm - log_norm) + 1e-8f;
  float mx = prob;
  #pragma unroll
  for (int off = 16; off >= 1; off >>= 1)
    mx = fmaxf(mx, __shfl_xor(mx, off, 32));
  float e_g = prob / mx;

  float* o = pos + (size_t)row * 192;
  o[j] = e_exp;        o[32 + j] = e_cm;        o[64 + j] = e_g;
  o[96 + j] = sgn * e_exp; o[128 + j] = sgn * e_cm; o[160 + j] = sgn * e_g;
}

// ------------- rel_k = pos @ Wrk -> f16 [3072 rows][512]; PR[h][d] -------------
// Tiled: each block owns 16 d-rows; Wrk streamed once per block (192 blocks).
__global__ __launch_bounds__(512) void relk_kernel(
    const float* __restrict__ pos, const float* __restrict__ Wrk,
    const float* __restrict__ pb, _Float16* __restrict__ rk, float* __restrict__ PR) {
  __shared__ float prow[16][192];
  const int d0 = blockIdx.x * 16;
  const int t = threadIdx.x;
  #pragma unroll
  for (int p = 0; p < 6; ++p) {
    int idx = t + p * 512;
    int r = idx / 192, c = idx - r * 192;
    prow[r][c] = pos[(size_t)(d0 + r) * 192 + c];
  }
  __syncthreads();
  float acc[16];
  #pragma unroll
  for (int r = 0; r < 16; ++r) acc[r] = 0.f;
  #pragma unroll 4
  for (int kk = 0; kk < 192; ++kk) {
    float wv = Wrk[(size_t)kk * 512 + t];
    #pragma unroll
    for (int r = 0; r < 16; ++r) acc[r] = fmaf(prow[r][kk], wv, acc[r]);
  }
  #pragma unroll
  for (int r = 0; r < 16; ++r)
    rk[(size_t)(d0 + r) * 512 + t] = (_Float16)acc[r];
  float pbv = pb[t];
  #pragma unroll
  for (int r = 0; r < 16; ++r) {
    float pv = pbv * acc[r];
    #pragma unroll
    for (int off = 32; off >= 1; off >>= 1) pv += __shfl_xor(pv, off);
    if ((t & 63) == 0 && (d0 + r) < NDIST)
      PR[(size_t)(t >> 6) * NDIST + d0 + r] = pv;
  }
}

// ------------- layernorm: fp32 in -> f16 plane out -------------
__global__ __launch_bounds__(256) void ln_kernel(
    const float* __restrict__ x, const float* __restrict__ g,
    const float* __restrict__ bta, _Float16* __restrict__ oh) {
  const int row = blockIdx.x;
  const int t = threadIdx.x;
  __shared__ float red[4];
  __shared__ float bc[2];
  const float4* xr = (const float4*)(x + (size_t)row * 1536);
  float4 v0 = xr[t];
  float4 v1 = make_float4(0.f, 0.f, 0.f, 0.f);
  if (t < 128) v1 = xr[256 + t];
  float s = v0.x + v0.y + v0.z + v0.w;
  if (t < 128) s += v1.x + v1.y + v1.z + v1.w;
  #pragma unroll
  for (int off = 32; off >= 1; off >>= 1) s += __shfl_xor(s, off);
  if ((t & 63) == 0) red[t >> 6] = s;
  __syncthreads();
  if (t == 0) bc[0] = (red[0] + red[1] + red[2] + red[3]) * (1.f / 1536.f);
  __syncthreads();
  const float mu = bc[0];
  float d, s2 = 0.f;
  d = v0.x - mu; s2 += d * d; d = v0.y - mu; s2 += d * d;
  d = v0.z - mu; s2 += d * d; d = v0.w - mu; s2 += d * d;
  if (t < 128) {
    d = v1.x - mu; s2 += d * d; d = v1.y - mu; s2 += d * d;
    d = v1.z - mu; s2 += d * d; d = v1.w - mu; s2 += d * d;
  }
  #pragma unroll
  for (int off = 32; off >= 1; off >>= 1) s2 += __shfl_xor(s2, off);
  if ((t & 63) == 0) red[t >> 6] = s2;
  __syncthreads();
  if (t == 0) bc[1] = (red[0] + red[1] + red[2] + red[3]) * (1.f / 1536.f);
  __syncthreads();
  const float inv = rsqrtf(bc[1] + 1e-5f);
  const float4* g4 = (const float4*)g;
  const float4* b4 = (const float4*)bta;
  float4 gg = g4[t], bb = b4[t];
  f16x4 hv;
  hv[0] = (_Float16)((v0.x - mu) * inv * gg.x + bb.x);
  hv[1] = (_Float16)((v0.y - mu) * inv * gg.y + bb.y);
  hv[2] = (_Float16)((v0.z - mu) * inv * gg.z + bb.z);
  hv[3] = (_Float16)((v0.w - mu) * inv * gg.w + bb.w);
  *(f16x4*)(oh + (size_t)row * 1536 + t * 4) = hv;
  if (t < 128) {
    gg = g4[256 + t]; bb = b4[256 + t];
    hv[0] = (_Float16)((v1.x - mu) * inv * gg.x + bb.x);
    hv[1] = (_Float16)((v1.y - mu) * inv * gg.y + bb.y);
    hv[2] = (_Float16)((v1.z - mu) * inv * gg.z + bb.z);
    hv[3] = (_Float16)((v1.w - mu) * inv * gg.w + bb.w);
    *(f16x4*)(oh + (size_t)row * 1536 + 1024 + t * 4) = hv;
  }
}

// ------------- weight convert + transpose: W[K][N] fp32 -> T[roff+N][KD] f16 -------------
__global__ __launch_bounds__(256) void convw_kernel(
    const float* __restrict__ W, _Float16* __restrict__ Th,
    int N, int K, int KD, int roff, float scale) {
  __shared__ float tile[32][33];
  const int n0 = blockIdx.x * 32, k0 = blockIdx.y * 32;
  const int t = threadIdx.x;
  const int cr = t >> 5;
  const int cc = t & 31;
  #pragma unroll
  for (int p = 0; p < 4; ++p) {
    int r = cr + p * 8;
    tile[r][cc] = W[(size_t)(k0 + r) * N + n0 + cc];
  }
  __syncthreads();
  #pragma unroll
  for (int p = 0; p < 4; ++p) {
    int r = cr + p * 8;                    // local n
    float v = tile[cc][r] * scale;         // W[k0+cc][n0+r]
    Th[(size_t)(roff + n0 + r) * KD + k0 + cc] = (_Float16)v;
  }
}

// ------------- fp16 MFMA GEMM, 128xBN tile, BK=64 -------------
// 1D grid, XCD y-slab swizzle; 8-slot XOR LDS swizzle via pre-swizzled global
// source + swizzled fragment reads. BNJ j-tiles/wave: 3->BN=96, 4->128, 6->192.
// EPI: 2 = bias+relu -> f16 plane; 3 = bias+residual -> fp32;
//      4 = QKV epilogue: Q/K f16 planes + V^T f16 plane + fused CK reduce
//          (bias param carries cb = rel_content_bias when EPI==4)
template <int EPI, int BNJ, int MW>
__global__ __launch_bounds__(256, MW) void mgemm_kernel(
    const _Float16* __restrict__ A, const _Float16* __restrict__ B,
    float* __restrict__ C, _Float16* __restrict__ Ch,
    _Float16* __restrict__ Kp, _Float16* __restrict__ Vt, float* __restrict__ CKo,
    const float* __restrict__ bias, const float* __restrict__ res,
    int M, int N, int K) {
  constexpr int BN = BNJ * 32;                 // 96 / 128 / 192
  __shared__ _Float16 sm[8192 + BN * 64];      // A[128][64] @0, B[BN][64] @8192
  const int t = threadIdx.x;
  const int lane = t & 63;
  const int w = t >> 6;
  const int wm = w >> 1, wn = w & 1;
  const int slab = (M >> 7) >> 3;              // row-tiles per XCD (6 for M=6144)
  const int xcd = blockIdx.x & 7;
  const int r = blockIdx.x >> 3;
  const int yt = xcd * slab + (r % slab);
  const int xt = r / slab;
  const int m0 = yt * 128, n0 = xt * BN;

  f32x4 acc[4][BNJ];
  #pragma unroll
  for (int i = 0; i < 4; ++i)
    #pragma unroll
    for (int j = 0; j < BNJ; ++j) acc[i][j] = (f32x4){0.f, 0.f, 0.f, 0.f};

  const int srow = t >> 3;
  const int ssl = t & 7;
  const int ss = ssl ^ (srow & 7);
  const int lr = lane & 15;
  const int g = lane >> 4;
  const int kb = lr & 7;                       // fragment-row swizzle key

  for (int k0 = 0; k0 < K; k0 += 64) {
    #pragma unroll
    for (int p = 0; p < 4; ++p) {
      int row = srow + p * 32;
      gl_lds16(A + (size_t)(m0 + row) * K + k0 + ss * 8, &sm[row * 64 + ssl * 8]);
    }
    #pragma unroll
    for (int p = 0; p < BN / 32; ++p) {
      int row = srow + p * 32;
      gl_lds16(B + (size_t)(n0 + row) * K + k0 + ss * 8,
               &sm[8192 + row * 64 + ssl * 8]);
    }
    __syncthreads();
    #pragma unroll
    for (int h2 = 0; h2 < 2; ++h2) {
      const int ksl = ((h2 * 4 + g) ^ kb) * 8;
      f16x8 a[4], b[BNJ];
      #pragma unroll
      for (int i = 0; i < 4; ++i)
        a[i] = *(const f16x8*)(&sm[(wm * 64 + i * 16 + lr) * 64 + ksl]);
      #pragma unroll
      for (int j = 0; j < BNJ; ++j)
        b[j] = *(const f16x8*)(&sm[8192 + (wn * BNJ * 16 + j * 16 + lr) * 64 + ksl]);
      #pragma unroll
      for (int i = 0; i < 4; ++i)
        #pragma unroll
        for (int j = 0; j < BNJ; ++j)
          acc[i][j] = MFMAH(a[i], b[j], acc[i][j]);
    }
    __syncthreads();
  }

  const int lq = lane >> 4;
  #pragma unroll
  for (int i = 0; i < 4; ++i) {
    #pragma unroll
    for (int j = 0; j < BNJ; ++j) {
      const int c0 = n0 + wn * BNJ * 16 + j * 16;   // tile col base (uniform)
      const int col = c0 + lr;
      const int rbase = m0 + wm * 64 + i * 16 + lq * 4;
      if (EPI == 3) {
        #pragma unroll
        for (int q = 0; q < 4; ++q) {
          size_t o = (size_t)(rbase + q) * N + col;
          C[o] = acc[i][j][q] + bias[col] + res[o];
        }
      } else if (EPI == 2) {
        #pragma unroll
        for (int q = 0; q < 4; ++q) {
          size_t o = (size_t)(rbase + q) * N + col;
          Ch[o] = (_Float16)fmaxf(acc[i][j][q] + bias[col], 0.f);
        }
      } else {  // EPI == 4: QKV split epilogue
        if (c0 < 512) {
          #pragma unroll
          for (int q = 0; q < 4; ++q)
            Ch[(size_t)(rbase + q) * 512 + col] = (_Float16)acc[i][j][q];
        } else if (c0 < 1024) {
          #pragma unroll
          for (int q = 0; q < 4; ++q)
            Kp[(size_t)(rbase + q) * 512 + (col - 512)] = (_Float16)acc[i][j][q];
        } else {
          int dv = col - 1024;
          int hd = dv / 192;
          int dvh = dv - hd * 192;
          int bb = rbase / 1536;
          int nloc = rbase - bb * 1536;
          f16x4 pk;
          pk[0] = (_Float16)acc[i][j][0];
          pk[1] = (_Float16)acc[i][j][1];
          pk[2] = (_Float16)acc[i][j][2];
          pk[3] = (_Float16)acc[i][j][3];
          *(f16x4*)(Vt + (((size_t)bb * 8 + hd) * 192 + dvh) * 1536 + nloc) = pk;
        }
      }
    }
  }

  // fused CK reduce (EPI==4, K-region waves only; wave holds one full head)
  if (EPI == 4) {
    const int cw0 = n0 + wn * 64;               // wave col base (BNJ==4)
    if (cw0 >= 512 && cw0 < 1024) {
      const int hh = (cw0 - 512) >> 6;
      float cbv[4];
      #pragma unroll
      for (int j = 0; j < 4; ++j) cbv[j] = bias[cw0 - 512 + j * 16 + lr];
      #pragma unroll
      for (int i = 0; i < 4; ++i)
        #pragma unroll
        for (int q = 0; q < 4; ++q) {
          float v = acc[i][0][q] * cbv[0] + acc[i][1][q] * cbv[1] +
                    acc[i][2][q] * cbv[2] + acc[i][3][q] * cbv[3];
          #pragma unroll
          for (int off = 8; off >= 1; off >>= 1) v += __shfl_xor(v, off);
          if (lr == 0)
            CKo[(size_t)(m0 + wm * 64 + i * 16 + lq * 4 + q) * 8 + hh] = v;
        }
    }
  }
}

// ------------- MFMA flash attention (fp16): chunk 32, ring-R, 1 barrier/chunk -------------
// 256 threads / 4 waves; block = 64 Q rows; 48 chunks of 32 j, UNROLLED x2 so
// buffer parity is compile-time (LDS addrs = hoisted lane base + immediate) and
// global staging uses incremented pointers. Row-sums via ones-MFMA into acc[12].
__global__ __launch_bounds__(256, 3) void attn_kernel(
    const _Float16* __restrict__ Qp, const _Float16* __restrict__ Kp,
    const _Float16* __restrict__ Vt, const _Float16* __restrict__ rk,
    const float* __restrict__ PR, const float* __restrict__ CK,
    _Float16* __restrict__ ao) {
  __shared__ _Float16 lds[26752];
  const int id = blockIdx.x;
  const int xcd = id & 7, s = id >> 3;    // XCD-chunked (b,h) mapping
  const int bh = xcd * 4 + s / 24;
  const int it = s % 24;
  const int b = bh >> 3, h = bh & 7;
  const int t = threadIdx.x;
  const int w = t >> 6;
  const int lane = t & 63;
  const int c15 = lane & 15, g = lane >> 4;
  const int swz = c15 & 7;                // K/R read swizzle (row&7 == c15&7)
  const int vsz = (c15 >> 1) & 3;         // V read swizzle ((row>>1)&3)
  const int qrow0 = it * 64 + w * 16;     // wave's 16 Q rows
  const int rrow0 = 48 - w * 16;          // wave's band offset within window
  const int R0 = 1472 - it * 64;          // absolute rel_k row of ring origin

  // staging lane geometry
  const int lr = lane >> 3, sl = lane & 7;
  const int ss = sl ^ lr;                           // K/R source slot
  const int ss2 = (lane & 3) ^ ((lane >> 3) & 3);   // V source slot

  // persistent Q fragment
  f16x8 qh0, qh1;
  {
    size_t qo = ((size_t)(b * SEQN + qrow0 + c15)) * 512 + h * 64 + g * 8;
    qh0 = *(const f16x8*)(Qp + qo);
    qh1 = *(const f16x8*)(Qp + qo + 32);
  }
  f16x8 ones;
  #pragma unroll
  for (int i = 0; i < 8; ++i) ones[i] = (_Float16)1.0f;

  // hoisted lane-dependent LDS bases (element indices)
  const int klA = c15 * 64 + ((g ^ swz)) * 8;        // K/R tile read, lo half
  const int klB = c15 * 64 + (((4 + g) ^ swz)) * 8;  // K/R tile read, hi half
  const int vl  = c15 * 32 + ((g ^ vsz)) * 8;        // V tile read
  const int pwr = 24576 + (w * 16 + 4 * g) * 34 + c15;   // Ps write base
  const int pfr = 24576 + (w * 16 + c15) * 34 + g * 8;   // Ps read base

  // walking global pointers (advance per chunk)
  const _Float16* kg = Kp + ((size_t)(b * SEQN) + 32 + w * 8 + lr) * 512 + h * 64 + ss * 8;
  const _Float16* vg = Vt + (((size_t)(b * 8 + h)) * 192 + w * 48 + (lane >> 2)) * SEQN + 32 + ss2 * 8;
  const _Float16* rg = rk + ((size_t)(R0 + 96) + w * 8 + lr) * 512 + h * 64 + ss * 8;
  const float* prg = PR + (size_t)h * NDIST + 1520 - qrow0 + c15;
  const float* ckg = CK + (size_t)b * SEQN * 8 + h + c15 * 8;

  f32x4 acc[13];                          // [12] = row-sum (softmax denominator)
  #pragma unroll
  for (int d = 0; d < 13; ++d) acc[d] = (f32x4){0.f, 0.f, 0.f, 0.f};
  float mrun[4];
  #pragma unroll
  for (int q = 0; q < 4; ++q) mrun[q] = -1e30f;

  // prologue staging: chunk 0 K/V + full 128-row ring fill
  {
    size_t gk = ((size_t)(b * SEQN) + w * 8 + lr) * 512 + h * 64 + ss * 8;
    gl_lds16(Kp + gk, &lds[w * 512]);
    #pragma unroll
    for (int p = 0; p < 3; ++p) {
      size_t gv = (((size_t)(b * 8 + h)) * 192 + w * 48 + p * 16 + (lane >> 2)) * SEQN + ss2 * 8;
      gl_lds16(Vt + gv, &lds[4096 + (w * 48 + p * 16) * 32]);
    }
    #pragma unroll
    for (int p = 0; p < 4; ++p) {
      int rr = w * 32 + p * 8 + lr;
      size_t gr = ((size_t)(R0 + rr)) * 512 + h * 64 + ss * 8;
      gl_lds16(rk + gr, &lds[16384 + (w * 32 + p * 8) * 64]);
    }
  }

  f32x4 T0, T1, T2;

  // one chunk; P = buffer parity (compile-time constant at each expansion)
  #define COMP_T(DST, ETOFF)                                                    \
    do {                                                                        \
      int relrow = (cc32 + rrow0 + (ETOFF) + c15) & 127;                        \
      f16x8 r0_ = *(const f16x8*)(&lds[16384 + relrow * 64 + ((g ^ swz)) * 8]); \
      f16x8 r1_ = *(const f16x8*)(&lds[16384 + relrow * 64 + (((4 + g) ^ swz)) * 8]); \
      f32x4 tt_ = (f32x4){0.f, 0.f, 0.f, 0.f};                                  \
      tt_ = MFMAH(qh0, r0_, tt_);                                               \
      tt_ = MFMAH(qh1, r1_, tt_);                                               \
      float prv_ = prg[(ETOFF)];                                                \
      _Pragma("unroll") for (int q = 0; q < 4; ++q) tt_[q] += prv_;             \
      DST = tt_;                                                                \
    } while (0)

  #define CHUNK_BODY(CIDX, P)                                                   \
  {                                                                             \
    const int c = (CIDX);                                                       \
    const int cc32 = c * 32;                                                    \
    constexpr int KB = (P) * 2048;                                              \
    constexpr int VB = 4096 + (P) * 6144;                                       \
    constexpr int KBn = (1 - (P)) * 2048;                                       \
    constexpr int VBn = 4096 + (1 - (P)) * 6144;                                \
    __syncthreads(); /* A: staged data for chunk c visible; prior reads done */ \
    if (c < 47) {                                                               \
      gl_lds16(kg, &lds[KBn + w * 512]);                                        \
      gl_lds16(vg, &lds[VBn + (w * 48) * 32]);                                  \
      gl_lds16(vg + (size_t)16 * SEQN, &lds[VBn + (w * 48 + 16) * 32]);         \
      gl_lds16(vg + (size_t)32 * SEQN, &lds[VBn + (w * 48 + 32) * 32]);         \
      if (c >= 1) {                                                             \
        int dr = ((cc32 + 96 + w * 8) & 127) * 64;                              \
        gl_lds16(rg, &lds[16384 + dr]);                                         \
      }                                                                         \
    }                                                                           \
    __builtin_amdgcn_s_setprio(1);                                              \
    if (c == 0) { COMP_T(T0, 0); } else { T0 = T2; }                            \
    COMP_T(T1, 16);                                                             \
    COMP_T(T2, 32);                                                             \
    f32x4 S[2];                                                                 \
    _Pragma("unroll") for (int st = 0; st < 2; ++st) {                          \
      f16x8 kh0 = *(const f16x8*)(&lds[KB + st * 1024 + klA]);                  \
      f16x8 kh1 = *(const f16x8*)(&lds[KB + st * 1024 + klB]);                  \
      f32x4 ssv = (f32x4){0.f, 0.f, 0.f, 0.f};                                  \
      ssv = MFMAH(qh0, kh0, ssv);                                               \
      ssv = MFMAH(qh1, kh1, ssv);                                               \
      S[st] = ssv;                                                              \
    }                                                                           \
    __builtin_amdgcn_s_setprio(0);                                              \
    float ck0 = ckg[0];                                                         \
    float ck1 = ckg[128];                                                       \
    _Pragma("unroll") for (int q = 0; q < 4; ++q) {                             \
      int eoff = c15 + 15 - 4 * g - q;                                          \
      int src = (lane & 48) | (eoff & 15);                                      \
      float t0v = __shfl(T0[q], src);                                           \
      float t1v = __shfl(T1[q], src);                                           \
      float t2v = __shfl(T2[q], src);                                           \
      bool lo = eoff < 16;                                                      \
      S[0][q] += ck0 + (lo ? t0v : t1v);                                        \
      S[1][q] += ck1 + (lo ? t1v : t2v);                                        \
    }                                                                           \
    int need = 0;                                                               \
    _Pragma("unroll") for (int st = 0; st < 2; ++st)                            \
      _Pragma("unroll") for (int q = 0; q < 4; ++q)                             \
        need |= (S[st][q] > mrun[q] + 8.0f) ? 1 : 0;                            \
    if (__any(need)) {                                                          \
      float mx[4];                                                              \
      _Pragma("unroll") for (int q = 0; q < 4; ++q)                             \
        mx[q] = fmaxf(S[0][q], S[1][q]);                                        \
      _Pragma("unroll") for (int off = 8; off >= 1; off >>= 1)                  \
        _Pragma("unroll") for (int q = 0; q < 4; ++q)                           \
          mx[q] = fmaxf(mx[q], __shfl_xor(mx[q], off));                         \
      _Pragma("unroll") for (int q = 0; q < 4; ++q) {                           \
        float mn = fmaxf(mrun[q], mx[q]);                                       \
        float al = __expf(mrun[q] - mn);                                        \
        mrun[q] = mn;                                                           \
        _Pragma("unroll") for (int d = 0; d < 13; ++d) acc[d][q] *= al;         \
      }                                                                         \
    }                                                                           \
    _Pragma("unroll") for (int st = 0; st < 2; ++st)                            \
      _Pragma("unroll") for (int q = 0; q < 4; ++q)                             \
        lds[pwr + q * 34 + st * 16] = (_Float16)__expf(S[st][q] - mrun[q]);     \
    f16x8 pf = *(const f16x8*)(&lds[pfr]);                                      \
    __builtin_amdgcn_s_setprio(1);                                              \
    _Pragma("unroll") for (int d = 0; d < 12; ++d) {                            \
      f16x8 vf = *(const f16x8*)(&lds[VB + d * 512 + vl]);                      \
      acc[d] = MFMAH(pf, vf, acc[d]);                                           \
    }                                                                           \
    acc[12] = MFMAH(pf, ones, acc[12]);                                         \
    __builtin_amdgcn_s_setprio(0);                                              \
    kg += 32 * 512;                                                             \
    vg += 32;                                                                   \
    rg += 32 * 512;                                                             \
    prg += 32;                                                                  \
    ckg += 256;                                                                 \
  }

  for (int cc = 0; cc < 48; cc += 2) {
    CHUNK_BODY(cc, 0);
    CHUNK_BODY(cc + 1, 1);
  }
  #undef CHUNK_BODY
  #undef COMP_T

  // ---- epilogue: out = acc / rowsum -> f16 plane ----
  float rinv[4];
  #pragma unroll
  for (int q = 0; q < 4; ++q) rinv[q] = 1.0f / acc[12][q];
  #pragma unroll
  for (int d = 0; d < 12; ++d) {
    int col = h * 192 + d * 16 + c15;
    #pragma unroll
    for (int q = 0; q < 4; ++q) {
      size_t row = (size_t)(b * SEQN + qrow0 + 4 * g + q);
      ao[row * 1536 + col] = (_Float16)(acc[d][q] * rinv[q]);
    }
  }
}

extern "C" void kernel_launch(void* const* d_in, const int* in_sizes, int n_in,
                              void* d_out, int out_size, void* d_ws, size_t ws_size,
                              hipStream_t stream) {
  (void)in_sizes; (void)n_in; (void)out_size; (void)ws_size;
  const float* x   = (const float*)d_in[0];
  const float* g1  = (const float*)d_in[1];
  const float* be1 = (const float*)d_in[2];
  const float* Wq  = (const float*)d_in[3];
  const float* Wk  = (const float*)d_in[4];
  const float* Wv  = (const float*)d_in[5];
  const float* Wo  = (const float*)d_in[6];
  const float* bo  = (const float*)d_in[7];
  const float* Wrk = (const float*)d_in[8];
  const float* cb  = (const float*)d_in[9];
  const float* pb  = (const float*)d_in[10];
  const float* g2  = (const float*)d_in[11];
  const float* be2 = (const float*)d_in[12];
  const float* W1  = (const float*)d_in[13];
  const float* b1  = (const float*)d_in[14];
  const float* W2  = (const float*)d_in[15];
  const float* b2  = (const float*)d_in[16];
  float* out = (float*)d_out;

  char* B = (char*)d_ws;
  float* pos     = (float*)(B + 0);             //  2,359,296
  _Float16* rk   = (_Float16*)(B + 2359296);    //  3,145,728 (3072 rows x 512)
  float* PRb     = (float*)(B + 5505024);       //     98,304
  float* CKb     = (float*)(B + 5603328);       //    196,608
  _Float16* xn   = (_Float16*)(B + 5799936);    // 18,874,368
  _Float16* Wb   = (_Float16*)(B + 24674304);   //  9,437,184 (max weight plane)
  _Float16* Qp   = (_Float16*)(B + 34111488);   //  6,291,456
  _Float16* Kp   = (_Float16*)(B + 40402944);   //  6,291,456
  _Float16* Vtp  = (_Float16*)(B + 46694400);   // 18,874,368
  _Float16* ao   = (_Float16*)(B + 65568768);   // 18,874,368
  float* x2      = (float*)(B + 84443136);      // 37,748,736
  _Float16* h1   = (_Float16*)(B + 122191872);  // 37,748,736 -> ends 159,940,608

  pos_embed_kernel<<<NDIST, 64, 0, stream>>>(pos);
  relk_kernel<<<192, 512, 0, stream>>>(pos, Wrk, pb, rk, PRb);
  ln_kernel<<<MROWS, 256, 0, stream>>>(x, g1, be1, xn);
  // fused QKV weights (transposed); fold 0.125 scale into Wq
  convw_kernel<<<dim3(16, 48), 256, 0, stream>>>(Wq, Wb, 512, 1536, 1536, 0, 0.125f);
  convw_kernel<<<dim3(16, 48), 256, 0, stream>>>(Wk, Wb, 512, 1536, 1536, 512, 1.0f);
  convw_kernel<<<dim3(48, 48), 256, 0, stream>>>(Wv, Wb, 1536, 1536, 1536, 1024, 1.0f);
  mgemm_kernel<4, 4, 4><<<960, 256, 0, stream>>>(
      xn, Wb, nullptr, Qp, Kp, Vtp, CKb, cb, nullptr, MROWS, 2560, 1536);
  attn_kernel<<<768, 256, 0, stream>>>(Qp, Kp, Vtp, rk, PRb, CKb, ao);
  convw_kernel<<<dim3(48, 48), 256, 0, stream>>>(Wo, Wb, 1536, 1536, 1536, 0, 1.0f);
  mgemm_kernel<3, 3, 4><<<768, 256, 0, stream>>>(
      ao, Wb, x2, nullptr, nullptr, nullptr, nullptr, bo, x, MROWS, 1536, 1536);
  ln_kernel<<<MROWS, 256, 0, stream>>>(x2, g2, be2, xn);
  convw_kernel<<<dim3(96, 48), 256, 0, stream>>>(W1, Wb, 3072, 1536, 1536, 0, 1.0f);
  mgemm_kernel<2, 6, 3><<<768, 256, 0, stream>>>(
      xn, Wb, nullptr, h1, nullptr, nullptr, nullptr, b1, nullptr, MROWS, 3072, 1536);
  convw_kernel<<<dim3(48, 96), 256, 0, stream>>>(W2, Wb, 1536, 3072, 3072, 0, 1.0f);
  mgemm_kernel<3, 3, 4><<<768, 256, 0, stream>>>(
      h1, Wb, out, nullptr, nullptr, nullptr, nullptr, b2, x2, MROWS, 1536, 3072);
}